// Round 2
// baseline (4666.576 us; speedup 1.0000x reference)
//
#include <hip/hip_runtime.h>

#define N_NODES 2500
#define N_EDGES 50000
#define C 128
#define MC 19
#define NL 4
#define NB 600
#define GW 20
#define THSTR 132

__device__ __forceinline__ float silu(float v){ return v / (1.f + expf(-v)); }
__device__ __forceinline__ int l_of_m(int m){
  return (m==0)?0 : (m<4)?1 : (m<9)?2 : (m<14)?3 : 4;
}

// ---------------- CSR build ----------------
__global__ void k_count(const int* tgt, int* deg){
  int e = blockIdx.x*256 + threadIdx.x;
  if (e < N_EDGES) atomicAdd(&deg[tgt[e]], 1);
}

__global__ void k_scan(const int* deg, int* rowptr){
  int lane = threadIdx.x;               // 64 threads
  const int CH = (N_NODES + 63)/64;     // 40
  int base = lane*CH;
  int s = 0;
  for (int i=0;i<CH;i++){ int idx=base+i; if (idx<N_NODES) s += deg[idx]; }
  int inc = s;
  for (int d=1; d<64; d<<=1){
    int v = __shfl_up(inc, d, 64);
    if (lane >= d) inc += v;
  }
  int run = inc - s;                    // exclusive prefix
  for (int i=0;i<CH;i++){
    int idx = base+i;
    if (idx < N_NODES){ rowptr[idx] = run; run += deg[idx]; }
  }
  if (lane == 63) rowptr[N_NODES] = run;
}

__global__ void k_fill(const int* tgt, const int* rowptr, int* cursor, int* elist){
  int e = blockIdx.x*256 + threadIdx.x;
  if (e < N_EDGES){
    int n = tgt[e];
    int pos = atomicAdd(&cursor[n], 1);
    elist[rowptr[n] + pos] = e;
  }
}

// ---------------- edge features ----------------
// efeat = silu(silu(smear @ We1) @ We2); smear truncated to +-GW taps (exp(-50) tail)
__global__ __launch_bounds__(256) void k_efeat(const float* dist, const float* We1, const float* We2, float* efeat){
  __shared__ float gbuf[2][2*GW+1];
  __shared__ float t1[2][C];
  int t = threadIdx.x;
  int sub = t >> 7; int c = t & 127;
  int e = blockIdx.x*2 + sub;
  float d = dist[e];
  const float delta = 12.0f/599.0f;
  const float coeff = -0.5f/((2.0f*delta)*(2.0f*delta));
  int jc = (int)floorf(d/delta + 0.5f);
  int j0 = jc - GW; if (j0 < 0) j0 = 0;
  int j1 = jc + GW; if (j1 > NB-1) j1 = NB-1;
  int cnt = j1 - j0 + 1;
  if (c < cnt){
    float off = (float)(j0 + c) * delta;
    float dd = d - off;
    gbuf[sub][c] = expf(coeff*dd*dd);
  }
  __syncthreads();
  float acc = 0.f;
  for (int w=0; w<cnt; ++w)
    acc += gbuf[sub][w] * We1[(j0+w)*C + c];
  t1[sub][c] = silu(acc);
  __syncthreads();
  float acc2 = 0.f;
  for (int cc=0; cc<C; ++cc)
    acc2 += t1[sub][cc] * We2[cc*C + c];
  efeat[e*C + c] = silu(acc2);
}

__global__ void k_efsum(const float* efeat, const int* rowptr, const int* elist, float* efsum){
  int n = blockIdx.x; int t = threadIdx.x; // 128 threads
  float acc = 0.f;
  int beg = rowptr[n], end = rowptr[n+1];
  for (int i=beg;i<end;i++)
    acc += efeat[elist[i]*C + t];
  efsum[n*C + t] = acc;
}

// x[n,m,c] = emb(m==0) + (efsum @ Wdeg)/AVG_DEGREE   (segment-sum pushed through the linear map)
__global__ __launch_bounds__(256) void k_deginit(const float* efsum, const float* Wdeg, const float* emb,
                                                 const int* anum, float* x){
  __shared__ float ef[C];
  int n = blockIdx.x; int t = threadIdx.x;
  if (t < C) ef[t] = efsum[n*C+t];
  __syncthreads();
  int an = anum[n];
  const float inv_avg = 1.0f/23.395238876342773f;
  for (int o = t; o < MC*C; o += 256){
    float acc = 0.f;
    for (int cc=0; cc<C; ++cc) acc += ef[cc]*Wdeg[cc*(MC*C) + o];
    float val = acc * inv_avg;
    if (o < C) val += emb[an*C + o];
    x[(size_t)n*MC*C + o] = val;
  }
}

// ---------------- rms norm (per-l) ----------------
__global__ __launch_bounds__(256) void k_rmsnorm(const float* x, const float* scale, float* xn){
  __shared__ float ssum[5];
  int n = blockIdx.x; int t = threadIdx.x;
  int g = t>>7, c = t&127;
  if (t < 5) ssum[t] = 0.f;
  __syncthreads();
  float vals[10];
  float pl[5] = {0,0,0,0,0};
  #pragma unroll
  for (int i=0;i<10;i++){
    int m = g + 2*i;
    if (m < MC){
      float v = x[(size_t)n*MC*C + m*C + c];
      vals[i] = v;
      pl[l_of_m(m)] += v*v;
    }
  }
  #pragma unroll
  for (int l=0;l<5;l++){
    float r = pl[l];
    for (int d=32; d>0; d>>=1) r += __shfl_down(r, d, 64);
    if ((t&63)==0) atomicAdd(&ssum[l], r);
  }
  __syncthreads();
  float inv[5];
  const float dens[5] = {128.f, 384.f, 640.f, 896.f, 1152.f};
  #pragma unroll
  for (int l=0;l<5;l++) inv[l] = 1.0f/sqrtf(ssum[l]/dens[l] + 1e-8f);
  #pragma unroll
  for (int i=0;i<10;i++){
    int m = g + 2*i;
    if (m < MC){
      int l = l_of_m(m);
      xn[(size_t)n*MC*C + m*C + c] = vals[i] * inv[l] * scale[l*C + c];
    }
  }
}

// ---------------- attention pieces ----------------
__global__ __launch_bounds__(256) void k_qk(const float* xn, const float* Wq, const float* Wk, float* qb, float* kb){
  __shared__ float s[C];
  int n = blockIdx.x; int t = threadIdx.x;
  if (t < C) s[t] = xn[(size_t)n*MC*C + t];   // m=0 row
  __syncthreads();
  for (int o=t; o<512; o+=256){
    float aq=0.f, ak=0.f;
    for (int cc=0; cc<C; ++cc){
      float sv = s[cc];
      aq += sv*Wq[cc*512+o];
      ak += sv*Wk[cc*512+o];
    }
    qb[n*512+o] = aq;
    kb[n*512+o] = ak;
  }
}

__global__ __launch_bounds__(256) void k_logits(const float* qb, const float* kb, const float* alpha,
                                                const int* srcarr, const int* tgtarr, float* logits){
  int wid = threadIdx.x >> 6; int lane = threadIdx.x & 63;
  int e = blockIdx.x*4 + wid;
  if (e >= N_EDGES) return;
  int s = srcarr[e], tg = tgtarr[e];
  #pragma unroll
  for (int h=0; h<8; ++h){
    float qv = qb[tg*512 + h*64 + lane] + kb[s*512 + h*64 + lane];
    float v = silu(qv) * alpha[h*64 + lane];
    for (int d=32; d>0; d>>=1) v += __shfl_down(v, d, 64);
    if (lane == 0) logits[e*8 + h] = v * 0.125f;
  }
}

__global__ void k_softmax(const float* logits, const int* rowptr, const int* elist, float* attnb){
  int tid = blockIdx.x*256 + threadIdx.x;
  if (tid >= N_NODES*8) return;
  int n = tid >> 3; int h = tid & 7;
  int beg = rowptr[n], end = rowptr[n+1];
  float mx = -1e30f;
  for (int i=beg;i<end;i++) mx = fmaxf(mx, logits[elist[i]*8+h]);
  float sum = 0.f;
  for (int i=beg;i<end;i++) sum += expf(logits[elist[i]*8+h] - mx);
  float inv = 1.0f/(sum + 1e-9f);
  for (int i=beg;i<end;i++){
    int e = elist[i];
    attnb[e*8+h] = expf(logits[e*8+h]-mx)*inv;
  }
}

__global__ __launch_bounds__(256) void k_rad(const float* efeat, const float* Wrad, float* radb){
  int wid = threadIdx.x>>6; int lane = threadIdx.x&63;
  int e = blockIdx.x*4 + wid;
  if (e >= N_EDGES) return;
  if (lane < MC){
    float acc = 0.f;
    for (int cc=0; cc<C; ++cc) acc += efeat[e*C+cc]*Wrad[cc*MC + lane];
    radb[e*MC+lane] = silu(acc);
  }
}

// ---------------- fused message build:  msum[n,m,d] = sum_c T[n,m,h(d),c]*Wv[c,d]
// T[n,m,h,c] = sum_{e in in(n)} attn[e,h]*rad[e,m]*xn[src_e,m,c]  kept in registers (76/thread)
__global__ __launch_bounds__(256) void k_e1(const float* xn, const float* radb, const float* attnb,
        const float* Wv, const int* rowptr, const int* elist, const int* srcarr, float* msum){
  __shared__ float y[MC*C];            // 9728 B
  __shared__ float Th[MC*4*THSTR];     // 40128 B (padded stride kills bank conflicts)
  int n = blockIdx.x;
  int t = threadIdx.x; int g = t>>7; int c = t&127;
  float Treg[76];                      // (m,h) with h parity == g : h = 2j+g
  #pragma unroll
  for (int i=0;i<76;i++) Treg[i]=0.f;
  int beg = rowptr[n], end = rowptr[n+1];
  for (int idx=beg; idx<end; ++idx){
    int e = elist[idx];
    int s = srcarr[e];
    for (int q=t; q<MC*C; q+=256)
      y[q] = xn[(size_t)s*MC*C + q] * radb[e*MC + (q>>7)];
    float a0 = attnb[e*8+g], a1 = attnb[e*8+2+g], a2 = attnb[e*8+4+g], a3 = attnb[e*8+6+g];
    __syncthreads();
    #pragma unroll
    for (int m=0;m<MC;m++){
      float ym = y[m*C+c];
      Treg[m*4+0] += a0*ym;
      Treg[m*4+1] += a1*ym;
      Treg[m*4+2] += a2*ym;
      Treg[m*4+3] += a3*ym;
    }
    __syncthreads();
  }
  // contract with Wv in two h-halves (keeps LDS < 64 KB)
  for (int pass=0; pass<2; ++pass){
    #pragma unroll
    for (int m=0;m<MC;m++){
      #pragma unroll
      for (int jj=0;jj<2;jj++){
        // global h = 2*(2*pass+jj)+g ; local h within half = 2*jj+g
        Th[(m*4 + 2*jj + g)*THSTR + c] = Treg[m*4 + 2*pass + jj];
      }
    }
    __syncthreads();
    int dl = t & 63;                 // local d ; global d = pass*64+dl
    int sg = t >> 6;                 // 0..3 -> m stripes
    int dglob = pass*64 + dl;
    int hloc = dl >> 4;              // local head 0..3
    float acc[5];
    #pragma unroll
    for (int i=0;i<5;i++) acc[i]=0.f;
    for (int cc=0; cc<C; ++cc){
      float wv = Wv[cc*C + dglob];
      #pragma unroll
      for (int i=0;i<5;i++){
        int m = sg + 4*i;
        if (m < MC) acc[i] += Th[(m*4 + hloc)*THSTR + cc]*wv;
      }
    }
    #pragma unroll
    for (int i=0;i<5;i++){
      int m = sg + 4*i;
      if (m < MC) msum[(size_t)n*MC*C + m*C + dglob] = acc[i];
    }
    __syncthreads();
  }
}

// x[n] += msum[n] @ Wo   (segment-sum pushed through Wo)
__global__ __launch_bounds__(256) void k_e2(const float* msum, const float* Wo, float* x){
  __shared__ float ms[MC*C];
  int n = blockIdx.x; int t = threadIdx.x; int g = t>>7; int c = t&127;
  for (int q=t; q<MC*C; q+=256) ms[q] = msum[(size_t)n*MC*C+q];
  __syncthreads();
  float acc[10];
  #pragma unroll
  for (int i=0;i<10;i++) acc[i]=0.f;
  for (int d=0; d<C; ++d){
    float wo = Wo[d*C+c];
    #pragma unroll
    for (int i=0;i<10;i++){
      int m = g + 2*i;
      if (m < MC) acc[i] += ms[m*C+d]*wo;
    }
  }
  #pragma unroll
  for (int i=0;i<10;i++){
    int m = g + 2*i;
    if (m < MC){
      size_t off = (size_t)n*MC*C + m*C + c;
      x[off] += acc[i];
    }
  }
}

// ---------------- gated FFN ----------------
__global__ __launch_bounds__(256) void k_ffn(const float* xn, const float* W1, const float* W2, float* x){
  __shared__ float xs[MC*C];
  __shared__ float hb[MC*C];
  __shared__ float gate[C];
  int n = blockIdx.x; int t = threadIdx.x; int g = t>>7; int c = t&127;
  for (int q=t; q<MC*C; q+=256) xs[q] = xn[(size_t)n*MC*C+q];
  __syncthreads();
  {
    float acc[10];
    #pragma unroll
    for (int i=0;i<10;i++) acc[i]=0.f;
    for (int cc=0; cc<C; ++cc){
      float w = W1[cc*C+c];
      #pragma unroll
      for (int i=0;i<10;i++){
        int m = g+2*i;
        if (m<MC) acc[i] += xs[m*C+cc]*w;
      }
    }
    #pragma unroll
    for (int i=0;i<10;i++){
      int m = g+2*i;
      if (m<MC) hb[m*C+c] = acc[i];
    }
  }
  __syncthreads();
  if (t < C){ float v = hb[t]; gate[t] = silu(v); }
  __syncthreads();
  for (int q=t; q<MC*C; q+=256) hb[q] *= gate[q & 127];
  __syncthreads();
  {
    float acc[10];
    #pragma unroll
    for (int i=0;i<10;i++) acc[i]=0.f;
    for (int f=0; f<C; ++f){
      float w = W2[f*C+c];
      #pragma unroll
      for (int i=0;i<10;i++){
        int m = g+2*i;
        if (m<MC) acc[i] += hb[m*C+f]*w;
      }
    }
    #pragma unroll
    for (int i=0;i<10;i++){
      int m = g+2*i;
      if (m<MC){
        size_t off = (size_t)n*MC*C + m*C + c;
        x[off] += acc[i];
      }
    }
  }
}

// ---------------- final head (only l=0 row matters) ----------------
__global__ __launch_bounds__(128) void k_final(const float* x, const float* nsf, const float* Wef1,
        const float* Wef2, const int* batch, float* out){
  __shared__ float sl[C];
  __shared__ float red[2];
  __shared__ float red2[2];
  int n = blockIdx.x; int t = threadIdx.x;
  float v = x[(size_t)n*MC*C + t];
  float sq = v*v;
  for (int d=32; d>0; d>>=1) sq += __shfl_down(sq, d, 64);
  if ((t&63)==0) red[t>>6] = sq;
  __syncthreads();
  float ms = (red[0]+red[1]) * (1.0f/128.f);
  float inv = 1.0f/sqrtf(ms + 1e-8f);
  sl[t] = v*inv*nsf[t];
  __syncthreads();
  float acc = 0.f;
  for (int cc=0; cc<C; ++cc) acc += sl[cc]*Wef1[cc*C + t];
  float val = acc*silu(acc)*Wef2[t];
  for (int d=32; d>0; d>>=1) val += __shfl_down(val, d, 64);
  if ((t&63)==0) red2[t>>6] = val;
  __syncthreads();
  if (t==0){
    float ne = red2[0]+red2[1];
    atomicAdd(&out[batch[n]], ne * (1.0f/77.81317f));
  }
}

extern "C" void kernel_launch(void* const* d_in, const int* in_sizes, int n_in,
                              void* d_out, int out_size, void* d_ws, size_t ws_size,
                              hipStream_t stream){
  (void)in_sizes; (void)n_in; (void)ws_size;
  const int*   anum  = (const int*)d_in[0];
  const int*   eidx  = (const int*)d_in[1];
  const float* dist  = (const float*)d_in[2];
  const int*   batch = (const int*)d_in[3];
  const float* emb   = (const float*)d_in[4];
  const float* We1   = (const float*)d_in[5];
  const float* We2   = (const float*)d_in[6];
  const float* Wdeg  = (const float*)d_in[7];
  const float* ns1   = (const float*)d_in[8];
  const float* ns2   = (const float*)d_in[9];
  const float* Wq    = (const float*)d_in[10];
  const float* Wk    = (const float*)d_in[11];
  const float* alpha = (const float*)d_in[12];
  const float* Wv    = (const float*)d_in[13];
  const float* Wrad  = (const float*)d_in[14];
  const float* Wo    = (const float*)d_in[15];
  const float* W1    = (const float*)d_in[16];
  const float* W2    = (const float*)d_in[17];
  const float* nsf   = (const float*)d_in[18];
  const float* Wef1  = (const float*)d_in[19];
  const float* Wef2  = (const float*)d_in[20];
  float* out = (float*)d_out;

  const int* srcarr = eidx;
  const int* tgtarr = eidx + N_EDGES;

  char* wsb = (char*)d_ws;
  float* efeat = (float*)wsb;  wsb += (size_t)N_EDGES*C*4;
  float* efsum = (float*)wsb;  wsb += (size_t)N_NODES*C*4;
  float* x     = (float*)wsb;  wsb += (size_t)N_NODES*MC*C*4;
  float* xn    = (float*)wsb;  wsb += (size_t)N_NODES*MC*C*4;
  float* msum  = (float*)wsb;  wsb += (size_t)N_NODES*MC*C*4;
  float* qb    = (float*)wsb;  wsb += (size_t)N_NODES*512*4;
  float* kb    = (float*)wsb;  wsb += (size_t)N_NODES*512*4;
  float* logit = (float*)wsb;  wsb += (size_t)N_EDGES*8*4;
  float* attnb = (float*)wsb;  wsb += (size_t)N_EDGES*8*4;
  float* radb  = (float*)wsb;  wsb += (size_t)N_EDGES*MC*4;
  int* deg     = (int*)wsb;    wsb += (size_t)N_NODES*4;
  int* rowptr  = (int*)wsb;    wsb += (size_t)(N_NODES+1)*4;
  int* cursor  = (int*)wsb;    wsb += (size_t)N_NODES*4;
  int* elist   = (int*)wsb;    wsb += (size_t)N_EDGES*4;

  (void)hipMemsetAsync(deg, 0, N_NODES*4, stream);
  (void)hipMemsetAsync(cursor, 0, N_NODES*4, stream);
  (void)hipMemsetAsync(d_out, 0, (size_t)out_size*sizeof(float), stream);

  k_count<<<(N_EDGES+255)/256, 256, 0, stream>>>(tgtarr, deg);
  k_scan<<<1, 64, 0, stream>>>(deg, rowptr);
  k_fill<<<(N_EDGES+255)/256, 256, 0, stream>>>(tgtarr, rowptr, cursor, elist);
  k_efeat<<<N_EDGES/2, 256, 0, stream>>>(dist, We1, We2, efeat);
  k_efsum<<<N_NODES, 128, 0, stream>>>(efeat, rowptr, elist, efsum);
  k_deginit<<<N_NODES, 256, 0, stream>>>(efsum, Wdeg, emb, anum, x);

  for (int i=0;i<NL;i++){
    k_rmsnorm<<<N_NODES, 256, 0, stream>>>(x, ns1 + i*5*C, xn);
    k_qk<<<N_NODES, 256, 0, stream>>>(xn, Wq + i*C*512, Wk + i*C*512, qb, kb);
    k_logits<<<(N_EDGES+3)/4, 256, 0, stream>>>(qb, kb, alpha + i*512, srcarr, tgtarr, logit);
    k_softmax<<<(N_NODES*8+255)/256, 256, 0, stream>>>(logit, rowptr, elist, attnb);
    k_rad<<<(N_EDGES+3)/4, 256, 0, stream>>>(efeat, Wrad + i*C*MC, radb);
    k_e1<<<N_NODES, 256, 0, stream>>>(xn, radb, attnb, Wv + i*C*C, rowptr, elist, srcarr, msum);
    k_e2<<<N_NODES, 256, 0, stream>>>(msum, Wo + i*C*C, x);
    k_rmsnorm<<<N_NODES, 256, 0, stream>>>(x, ns2 + i*5*C, xn);
    k_ffn<<<N_NODES, 256, 0, stream>>>(xn, W1 + i*C*C, W2 + i*C*C, x);
  }
  k_final<<<N_NODES, 128, 0, stream>>>(x, nsf, Wef1, Wef2, batch, out);
}

// Round 3
// 3913.453 us; speedup vs baseline: 1.1924x; 1.1924x over previous
//
#include <hip/hip_runtime.h>

#define N_NODES 2500
#define N_EDGES 50000
#define C 128
#define MC 19
#define RSTR 20
#define NL 4
#define NB 600
#define GW 20
#define THSTR 132

__device__ __forceinline__ float silu(float v){ return v / (1.f + expf(-v)); }
__device__ __forceinline__ int l_of_m(int m){
  return (m==0)?0 : (m<4)?1 : (m<9)?2 : (m<14)?3 : 4;
}

// ---------------- CSR build ----------------
__global__ void k_count(const int* tgt, int* deg){
  int e = blockIdx.x*256 + threadIdx.x;
  if (e < N_EDGES) atomicAdd(&deg[tgt[e]], 1);
}

__global__ void k_scan(const int* deg, int* rowptr){
  int lane = threadIdx.x;               // 64 threads
  const int CH = (N_NODES + 63)/64;     // 40
  int base = lane*CH;
  int s = 0;
  for (int i=0;i<CH;i++){ int idx=base+i; if (idx<N_NODES) s += deg[idx]; }
  int inc = s;
  for (int d=1; d<64; d<<=1){
    int v = __shfl_up(inc, d, 64);
    if (lane >= d) inc += v;
  }
  int run = inc - s;                    // exclusive prefix
  for (int i=0;i<CH;i++){
    int idx = base+i;
    if (idx < N_NODES){ rowptr[idx] = run; run += deg[idx]; }
  }
  if (lane == 63) rowptr[N_NODES] = run;
}

__global__ void k_fill(const int* tgt, const int* rowptr, int* cursor, int* elist){
  int e = blockIdx.x*256 + threadIdx.x;
  if (e < N_EDGES){
    int n = tgt[e];
    int pos = atomicAdd(&cursor[n], 1);
    elist[rowptr[n] + pos] = e;
  }
}

// ---------------- edge features ----------------
__global__ __launch_bounds__(256) void k_efeat(const float* dist, const float* We1, const float* We2, float* efeat){
  __shared__ float gbuf[2][2*GW+1];
  __shared__ float t1[2][C];
  int t = threadIdx.x;
  int sub = t >> 7; int c = t & 127;
  int e = blockIdx.x*2 + sub;
  float d = dist[e];
  const float delta = 12.0f/599.0f;
  const float coeff = -0.5f/((2.0f*delta)*(2.0f*delta));
  int jc = (int)floorf(d/delta + 0.5f);
  int j0 = jc - GW; if (j0 < 0) j0 = 0;
  int j1 = jc + GW; if (j1 > NB-1) j1 = NB-1;
  int cnt = j1 - j0 + 1;
  if (c < cnt){
    float off = (float)(j0 + c) * delta;
    float dd = d - off;
    gbuf[sub][c] = expf(coeff*dd*dd);
  }
  __syncthreads();
  float acc = 0.f;
  for (int w=0; w<cnt; ++w)
    acc += gbuf[sub][w] * We1[(j0+w)*C + c];
  t1[sub][c] = silu(acc);
  __syncthreads();
  float acc2 = 0.f;
  for (int cc=0; cc<C; ++cc)
    acc2 += t1[sub][cc] * We2[cc*C + c];
  efeat[e*C + c] = silu(acc2);
}

__global__ void k_efsum(const float* efeat, const int* rowptr, const int* elist, float* efsum){
  int n = blockIdx.x; int t = threadIdx.x; // 128 threads
  float acc = 0.f;
  int beg = rowptr[n], end = rowptr[n+1];
  for (int i=beg;i<end;i++)
    acc += efeat[elist[i]*C + t];
  efsum[n*C + t] = acc;
}

__global__ __launch_bounds__(256) void k_deginit(const float* efsum, const float* Wdeg, const float* emb,
                                                 const int* anum, float* x){
  __shared__ float ef[C];
  int n = blockIdx.x; int t = threadIdx.x;
  if (t < C) ef[t] = efsum[n*C+t];
  __syncthreads();
  int an = anum[n];
  const float inv_avg = 1.0f/23.395238876342773f;
  for (int o = t; o < MC*C; o += 256){
    float acc = 0.f;
    for (int cc=0; cc<C; ++cc) acc += ef[cc]*Wdeg[cc*(MC*C) + o];
    float val = acc * inv_avg;
    if (o < C) val += emb[an*C + o];
    x[(size_t)n*MC*C + o] = val;
  }
}

// ---------------- rms norm (per-l) ----------------
__global__ __launch_bounds__(256) void k_rmsnorm(const float* x, const float* scale, float* xn){
  __shared__ float ssum[5];
  int n = blockIdx.x; int t = threadIdx.x;
  int g = t>>7, c = t&127;
  if (t < 5) ssum[t] = 0.f;
  __syncthreads();
  float vals[10];
  float pl[5] = {0,0,0,0,0};
  #pragma unroll
  for (int i=0;i<10;i++){
    int m = g + 2*i;
    if (m < MC){
      float v = x[(size_t)n*MC*C + m*C + c];
      vals[i] = v;
      pl[l_of_m(m)] += v*v;
    }
  }
  #pragma unroll
  for (int l=0;l<5;l++){
    float r = pl[l];
    for (int d=32; d>0; d>>=1) r += __shfl_down(r, d, 64);
    if ((t&63)==0) atomicAdd(&ssum[l], r);
  }
  __syncthreads();
  float inv[5];
  const float dens[5] = {128.f, 384.f, 640.f, 896.f, 1152.f};
  #pragma unroll
  for (int l=0;l<5;l++) inv[l] = 1.0f/sqrtf(ssum[l]/dens[l] + 1e-8f);
  #pragma unroll
  for (int i=0;i<10;i++){
    int m = g + 2*i;
    if (m < MC){
      int l = l_of_m(m);
      xn[(size_t)n*MC*C + m*C + c] = vals[i] * inv[l] * scale[l*C + c];
    }
  }
}

// ---------------- attention pieces ----------------
__global__ __launch_bounds__(256) void k_qk(const float* xn, const float* Wq, const float* Wk, float* qb, float* kb){
  __shared__ float s[C];
  int n = blockIdx.x; int t = threadIdx.x;
  if (t < C) s[t] = xn[(size_t)n*MC*C + t];   // m=0 row
  __syncthreads();
  for (int o=t; o<512; o+=256){
    float aq=0.f, ak=0.f;
    for (int cc=0; cc<C; ++cc){
      float sv = s[cc];
      aq += sv*Wq[cc*512+o];
      ak += sv*Wk[cc*512+o];
    }
    qb[n*512+o] = aq;
    kb[n*512+o] = ak;
  }
}

__global__ __launch_bounds__(256) void k_logits(const float* qb, const float* kb, const float* alpha,
                                                const int* srcarr, const int* tgtarr, float* logits){
  int wid = threadIdx.x >> 6; int lane = threadIdx.x & 63;
  int e = blockIdx.x*4 + wid;
  if (e >= N_EDGES) return;
  int s = srcarr[e], tg = tgtarr[e];
  #pragma unroll
  for (int h=0; h<8; ++h){
    float qv = qb[tg*512 + h*64 + lane] + kb[s*512 + h*64 + lane];
    float v = silu(qv) * alpha[h*64 + lane];
    for (int d=32; d>0; d>>=1) v += __shfl_down(v, d, 64);
    if (lane == 0) logits[e*8 + h] = v * 0.125f;
  }
}

// one wave per (n,h); lanes stride edges; writes attn in k_e1's (g,j) layout:
// slot = (h&1)*4 + (h>>1)  so head h=2j+g lands at e*8 + g*4 + j
__global__ __launch_bounds__(256) void k_softmax(const float* logits, const int* rowptr, const int* elist, float* attnb){
  int wid = blockIdx.x*4 + (threadIdx.x>>6);
  if (wid >= N_NODES*8) return;
  int n = wid >> 3; int h = wid & 7;
  int lane = threadIdx.x & 63;
  int beg = rowptr[n], end = rowptr[n+1];
  float mx = -1e30f;
  for (int i=beg+lane; i<end; i+=64) mx = fmaxf(mx, logits[elist[i]*8+h]);
  #pragma unroll
  for (int d=32; d>0; d>>=1) mx = fmaxf(mx, __shfl_xor(mx, d, 64));
  float sum = 0.f;
  for (int i=beg+lane; i<end; i+=64) sum += expf(logits[elist[i]*8+h] - mx);
  #pragma unroll
  for (int d=32; d>0; d>>=1) sum += __shfl_xor(sum, d, 64);
  float inv = 1.0f/(sum + 1e-9f);
  int slot = (h&1)*4 + (h>>1);
  for (int i=beg+lane; i<end; i+=64){
    int e = elist[i];
    attnb[e*8 + slot] = expf(logits[e*8+h]-mx)*inv;
  }
}

// rad: 16 edges/block, Wrad + efeat tiles staged in LDS; output stride RSTR=20 (16B-aligned rows)
__global__ __launch_bounds__(256) void k_rad(const float* efeat, const float* Wrad, float* radb){
  __shared__ float wsh[C*RSTR];     // wsh[cc*20+m]
  __shared__ float esh[16][132];    // padded vs 128-stride bank aliasing
  int t = threadIdx.x;
  for (int q=t; q<C*MC; q+=256){ int cc=q/MC, m=q-cc*MC; wsh[cc*RSTR+m] = Wrad[q]; }
  int e0 = blockIdx.x*16;
  for (int q=t; q<16*C; q+=256) esh[q>>7][q&127] = efeat[(size_t)(e0+(q>>7))*C + (q&127)];
  __syncthreads();
  for (int q=t; q<16*MC; q+=256){
    int el = q/MC, m = q-el*MC;
    float acc = 0.f;
    #pragma unroll 4
    for (int cc=0; cc<C; ++cc) acc += esh[el][cc]*wsh[cc*RSTR+m];
    radb[(size_t)(e0+el)*RSTR + m] = silu(acc);
  }
}

// ---------------- fused message build + Wo:  x[n] += (msum[n]) @ Wo
// T[n,m,h,c] = sum_e attn[e,h]*rad[e,m]*xn[src_e,m,c]  in registers (76/thread, STATIC idx only)
// msum[n,m,d] = sum_c T[n,m,h(d),c]*Wv[c,d]  via LDS;  then contract with Wo in-block.
__global__ __launch_bounds__(256,3) void k_e1(const float* __restrict__ xn, const float* __restrict__ radb,
        const float* __restrict__ attnb, const float* __restrict__ Wv, const float* __restrict__ Wo,
        const int* __restrict__ rowptr, const int* __restrict__ elist, const int* __restrict__ srcarr,
        float* __restrict__ x){
  __shared__ float Th[MC*4*THSTR];     // 40128 B
  __shared__ float msh[MC*C];          // 9728 B
  int n = blockIdx.x;
  int t = threadIdx.x; int g = t>>7; int c = t&127;
  float acc[MC][4];                    // acc[m][k] = T for head h=2k+g
  #pragma unroll
  for (int m=0;m<MC;m++){
    #pragma unroll
    for (int k=0;k<4;k++) acc[m][k]=0.f;
  }
  int beg = rowptr[n], end = rowptr[n+1];
  for (int idx=beg; idx<end; ++idx){
    int e = elist[idx];
    int s = srcarr[e];
    const float* xr = xn + (size_t)s*MC*C + c;
    const float4* rp = (const float4*)(radb + (size_t)e*RSTR);
    float4 r0=rp[0], r1=rp[1], r2=rp[2], r3=rp[3], r4=rp[4];
    float rm[20] = {r0.x,r0.y,r0.z,r0.w, r1.x,r1.y,r1.z,r1.w,
                    r2.x,r2.y,r2.z,r2.w, r3.x,r3.y,r3.z,r3.w,
                    r4.x,r4.y,r4.z,r4.w};
    float4 av = *(const float4*)(attnb + e*8 + g*4);   // heads g,2+g,4+g,6+g
    #pragma unroll
    for (int m=0;m<MC;m++){
      float ym = xr[m*C] * rm[m];
      acc[m][0] += av.x*ym;
      acc[m][1] += av.y*ym;
      acc[m][2] += av.z*ym;
      acc[m][3] += av.w*ym;
    }
  }
  // contract T with Wv in two h-halves; results to msh
  #pragma unroll
  for (int pass=0; pass<2; ++pass){
    #pragma unroll
    for (int m=0;m<MC;m++){
      #pragma unroll
      for (int jj=0;jj<2;jj++){
        // global head h = 4*pass + 2*jj + g stored at local slot 2*jj+g
        Th[(m*4 + 2*jj + g)*THSTR + c] = acc[m][2*pass + jj];
      }
    }
    __syncthreads();
    int dl = t & 63;
    int sg = t >> 6;
    int dglob = pass*64 + dl;
    int hloc = dl >> 4;
    float pacc[5];
    #pragma unroll
    for (int i=0;i<5;i++) pacc[i]=0.f;
    for (int cc=0; cc<C; ++cc){
      float wv = Wv[cc*C + dglob];
      #pragma unroll
      for (int i=0;i<5;i++){
        int m = sg + 4*i;
        if (m < MC) pacc[i] += Th[(m*4 + hloc)*THSTR + cc]*wv;
      }
    }
    #pragma unroll
    for (int i=0;i<5;i++){
      int m = sg + 4*i;
      if (m < MC) msh[m*C + dglob] = pacc[i];
    }
    __syncthreads();
  }
  // x[n] += msh @ Wo   (msh reads are wave-uniform broadcasts)
  float acc2[10];
  #pragma unroll
  for (int i=0;i<10;i++) acc2[i]=0.f;
  for (int d=0; d<C; ++d){
    float wo = Wo[d*C+c];
    #pragma unroll
    for (int i=0;i<10;i++){
      int m = g + 2*i;
      if (m < MC) acc2[i] += msh[m*C+d]*wo;
    }
  }
  #pragma unroll
  for (int i=0;i<10;i++){
    int m = g + 2*i;
    if (m < MC){
      size_t off = (size_t)n*MC*C + m*C + c;
      x[off] += acc2[i];
    }
  }
}

// ---------------- gated FFN ----------------
__global__ __launch_bounds__(256) void k_ffn(const float* xn, const float* W1, const float* W2, float* x){
  __shared__ float xs[MC*C];
  __shared__ float hb[MC*C];
  __shared__ float gate[C];
  int n = blockIdx.x; int t = threadIdx.x; int g = t>>7; int c = t&127;
  for (int q=t; q<MC*C; q+=256) xs[q] = xn[(size_t)n*MC*C+q];
  __syncthreads();
  {
    float acc[10];
    #pragma unroll
    for (int i=0;i<10;i++) acc[i]=0.f;
    for (int cc=0; cc<C; ++cc){
      float w = W1[cc*C+c];
      #pragma unroll
      for (int i=0;i<10;i++){
        int m = g+2*i;
        if (m<MC) acc[i] += xs[m*C+cc]*w;
      }
    }
    #pragma unroll
    for (int i=0;i<10;i++){
      int m = g+2*i;
      if (m<MC) hb[m*C+c] = acc[i];
    }
  }
  __syncthreads();
  if (t < C){ float v = hb[t]; gate[t] = silu(v); }
  __syncthreads();
  for (int q=t; q<MC*C; q+=256) hb[q] *= gate[q & 127];
  __syncthreads();
  {
    float acc[10];
    #pragma unroll
    for (int i=0;i<10;i++) acc[i]=0.f;
    for (int f=0; f<C; ++f){
      float w = W2[f*C+c];
      #pragma unroll
      for (int i=0;i<10;i++){
        int m = g+2*i;
        if (m<MC) acc[i] += hb[m*C+f]*w;
      }
    }
    #pragma unroll
    for (int i=0;i<10;i++){
      int m = g+2*i;
      if (m<MC){
        size_t off = (size_t)n*MC*C + m*C + c;
        x[off] += acc[i];
      }
    }
  }
}

// ---------------- final head (only l=0 row matters) ----------------
__global__ __launch_bounds__(128) void k_final(const float* x, const float* nsf, const float* Wef1,
        const float* Wef2, const int* batch, float* out){
  __shared__ float sl[C];
  __shared__ float red[2];
  __shared__ float red2[2];
  int n = blockIdx.x; int t = threadIdx.x;
  float v = x[(size_t)n*MC*C + t];
  float sq = v*v;
  for (int d=32; d>0; d>>=1) sq += __shfl_down(sq, d, 64);
  if ((t&63)==0) red[t>>6] = sq;
  __syncthreads();
  float ms = (red[0]+red[1]) * (1.0f/128.f);
  float inv = 1.0f/sqrtf(ms + 1e-8f);
  sl[t] = v*inv*nsf[t];
  __syncthreads();
  float acc = 0.f;
  for (int cc=0; cc<C; ++cc) acc += sl[cc]*Wef1[cc*C + t];
  float val = acc*silu(acc)*Wef2[t];
  for (int d=32; d>0; d>>=1) val += __shfl_down(val, d, 64);
  if ((t&63)==0) red2[t>>6] = val;
  __syncthreads();
  if (t==0){
    float ne = red2[0]+red2[1];
    atomicAdd(&out[batch[n]], ne * (1.0f/77.81317f));
  }
}

extern "C" void kernel_launch(void* const* d_in, const int* in_sizes, int n_in,
                              void* d_out, int out_size, void* d_ws, size_t ws_size,
                              hipStream_t stream){
  (void)in_sizes; (void)n_in; (void)ws_size;
  const int*   anum  = (const int*)d_in[0];
  const int*   eidx  = (const int*)d_in[1];
  const float* dist  = (const float*)d_in[2];
  const int*   batch = (const int*)d_in[3];
  const float* emb   = (const float*)d_in[4];
  const float* We1   = (const float*)d_in[5];
  const float* We2   = (const float*)d_in[6];
  const float* Wdeg  = (const float*)d_in[7];
  const float* ns1   = (const float*)d_in[8];
  const float* ns2   = (const float*)d_in[9];
  const float* Wq    = (const float*)d_in[10];
  const float* Wk    = (const float*)d_in[11];
  const float* alpha = (const float*)d_in[12];
  const float* Wv    = (const float*)d_in[13];
  const float* Wrad  = (const float*)d_in[14];
  const float* Wo    = (const float*)d_in[15];
  const float* W1    = (const float*)d_in[16];
  const float* W2    = (const float*)d_in[17];
  const float* nsf   = (const float*)d_in[18];
  const float* Wef1  = (const float*)d_in[19];
  const float* Wef2  = (const float*)d_in[20];
  float* out = (float*)d_out;

  const int* srcarr = eidx;
  const int* tgtarr = eidx + N_EDGES;

  char* wsb = (char*)d_ws;
  float* efeat = (float*)wsb;  wsb += (size_t)N_EDGES*C*4;
  float* efsum = (float*)wsb;  wsb += (size_t)N_NODES*C*4;
  float* x     = (float*)wsb;  wsb += (size_t)N_NODES*MC*C*4;
  float* xn    = (float*)wsb;  wsb += (size_t)N_NODES*MC*C*4;
  float* qb    = (float*)wsb;  wsb += (size_t)N_NODES*512*4;
  float* kb    = (float*)wsb;  wsb += (size_t)N_NODES*512*4;
  float* logit = (float*)wsb;  wsb += (size_t)N_EDGES*8*4;
  float* attnb = (float*)wsb;  wsb += (size_t)N_EDGES*8*4;
  float* radb  = (float*)wsb;  wsb += (size_t)N_EDGES*RSTR*4;
  int* deg     = (int*)wsb;    wsb += (size_t)N_NODES*4;
  int* rowptr  = (int*)wsb;    wsb += (size_t)(N_NODES+1)*4;
  int* cursor  = (int*)wsb;    wsb += (size_t)N_NODES*4;
  int* elist   = (int*)wsb;    wsb += (size_t)N_EDGES*4;

  (void)hipMemsetAsync(deg, 0, N_NODES*4, stream);
  (void)hipMemsetAsync(cursor, 0, N_NODES*4, stream);
  (void)hipMemsetAsync(d_out, 0, (size_t)out_size*sizeof(float), stream);

  k_count<<<(N_EDGES+255)/256, 256, 0, stream>>>(tgtarr, deg);
  k_scan<<<1, 64, 0, stream>>>(deg, rowptr);
  k_fill<<<(N_EDGES+255)/256, 256, 0, stream>>>(tgtarr, rowptr, cursor, elist);
  k_efeat<<<N_EDGES/2, 256, 0, stream>>>(dist, We1, We2, efeat);
  k_efsum<<<N_NODES, 128, 0, stream>>>(efeat, rowptr, elist, efsum);
  k_deginit<<<N_NODES, 256, 0, stream>>>(efsum, Wdeg, emb, anum, x);

  for (int i=0;i<NL;i++){
    k_rmsnorm<<<N_NODES, 256, 0, stream>>>(x, ns1 + i*5*C, xn);
    k_qk<<<N_NODES, 256, 0, stream>>>(xn, Wq + i*C*512, Wk + i*C*512, qb, kb);
    k_logits<<<(N_EDGES+3)/4, 256, 0, stream>>>(qb, kb, alpha + i*512, srcarr, tgtarr, logit);
    k_softmax<<<(N_NODES*8+3)/4/64 + 1, 256, 0, stream>>>(logit, rowptr, elist, attnb);
    k_rad<<<N_EDGES/16, 256, 0, stream>>>(efeat, Wrad + i*C*MC, radb);
    k_e1<<<N_NODES, 256, 0, stream>>>(xn, radb, attnb, Wv + i*C*C, Wo + i*C*C,
                                      rowptr, elist, srcarr, x);
    k_rmsnorm<<<N_NODES, 256, 0, stream>>>(x, ns2 + i*5*C, xn);
    k_ffn<<<N_NODES, 256, 0, stream>>>(xn, W1 + i*C*C, W2 + i*C*C, x);
  }
  k_final<<<N_NODES, 128, 0, stream>>>(x, nsf, Wef1, Wef2, batch, out);
}

// Round 4
// 2749.289 us; speedup vs baseline: 1.6974x; 1.4234x over previous
//
#include <hip/hip_runtime.h>

#define N_NODES 2500
#define N_EDGES 50000
#define C 128
#define MC 19
#define RSTR 20
#define NL 4
#define NB 600
#define GW 20

__device__ __forceinline__ float silu(float v){ return v / (1.f + expf(-v)); }
__device__ __forceinline__ int l_of_m(int m){
  return (m==0)?0 : (m<4)?1 : (m<9)?2 : (m<14)?3 : 4;
}

// ---------------- CSR build ----------------
__global__ void k_count(const int* tgt, int* deg){
  int e = blockIdx.x*256 + threadIdx.x;
  if (e < N_EDGES) atomicAdd(&deg[tgt[e]], 1);
}

__global__ void k_scan(const int* deg, int* rowptr){
  int lane = threadIdx.x;               // 64 threads
  const int CH = (N_NODES + 63)/64;     // 40
  int base = lane*CH;
  int s = 0;
  for (int i=0;i<CH;i++){ int idx=base+i; if (idx<N_NODES) s += deg[idx]; }
  int inc = s;
  for (int d=1; d<64; d<<=1){
    int v = __shfl_up(inc, d, 64);
    if (lane >= d) inc += v;
  }
  int run = inc - s;                    // exclusive prefix
  for (int i=0;i<CH;i++){
    int idx = base+i;
    if (idx < N_NODES){ rowptr[idx] = run; run += deg[idx]; }
  }
  if (lane == 63) rowptr[N_NODES] = run;
}

__global__ void k_fill(const int* tgt, const int* rowptr, int* cursor, int* elist){
  int e = blockIdx.x*256 + threadIdx.x;
  if (e < N_EDGES){
    int n = tgt[e];
    int pos = atomicAdd(&cursor[n], 1);
    elist[rowptr[n] + pos] = e;
  }
}

// ---------------- edge features ----------------
__global__ __launch_bounds__(256) void k_efeat(const float* dist, const float* We1, const float* We2, float* efeat){
  __shared__ float gbuf[2][2*GW+1];
  __shared__ float t1[2][C];
  int t = threadIdx.x;
  int sub = t >> 7; int c = t & 127;
  int e = blockIdx.x*2 + sub;
  float d = dist[e];
  const float delta = 12.0f/599.0f;
  const float coeff = -0.5f/((2.0f*delta)*(2.0f*delta));
  int jc = (int)floorf(d/delta + 0.5f);
  int j0 = jc - GW; if (j0 < 0) j0 = 0;
  int j1 = jc + GW; if (j1 > NB-1) j1 = NB-1;
  int cnt = j1 - j0 + 1;
  if (c < cnt){
    float off = (float)(j0 + c) * delta;
    float dd = d - off;
    gbuf[sub][c] = expf(coeff*dd*dd);
  }
  __syncthreads();
  float acc = 0.f;
  for (int w=0; w<cnt; ++w)
    acc += gbuf[sub][w] * We1[(j0+w)*C + c];
  t1[sub][c] = silu(acc);
  __syncthreads();
  float acc2 = 0.f;
  for (int cc=0; cc<C; ++cc)
    acc2 += t1[sub][cc] * We2[cc*C + c];
  efeat[e*C + c] = silu(acc2);
}

__global__ void k_efsum(const float* efeat, const int* rowptr, const int* elist, float* efsum){
  int n = blockIdx.x; int t = threadIdx.x; // 128 threads
  float acc = 0.f;
  int beg = rowptr[n], end = rowptr[n+1];
  for (int i=beg;i<end;i++)
    acc += efeat[elist[i]*C + t];
  efsum[n*C + t] = acc;
}

__global__ __launch_bounds__(256) void k_deginit(const float* efsum, const float* Wdeg, const float* emb,
                                                 const int* anum, float* x){
  __shared__ float ef[C];
  int n = blockIdx.x; int t = threadIdx.x;
  if (t < C) ef[t] = efsum[n*C+t];
  __syncthreads();
  int an = anum[n];
  const float inv_avg = 1.0f/23.395238876342773f;
  for (int o = t; o < MC*C; o += 256){
    float acc = 0.f;
    for (int cc=0; cc<C; ++cc) acc += ef[cc]*Wdeg[cc*(MC*C) + o];
    float val = acc * inv_avg;
    if (o < C) val += emb[an*C + o];
    x[(size_t)n*MC*C + o] = val;
  }
}

// ---------------- rms norm (per-l) ----------------
__global__ __launch_bounds__(256) void k_rmsnorm(const float* x, const float* scale, float* xn){
  __shared__ float ssum[5];
  int n = blockIdx.x; int t = threadIdx.x;
  int g = t>>7, c = t&127;
  if (t < 5) ssum[t] = 0.f;
  __syncthreads();
  float vals[10];
  float pl[5] = {0,0,0,0,0};
  #pragma unroll
  for (int i=0;i<10;i++){
    int m = g + 2*i;
    if (m < MC){
      float v = x[(size_t)n*MC*C + m*C + c];
      vals[i] = v;
      pl[l_of_m(m)] += v*v;
    }
  }
  #pragma unroll
  for (int l=0;l<5;l++){
    float r = pl[l];
    for (int d=32; d>0; d>>=1) r += __shfl_down(r, d, 64);
    if ((t&63)==0) atomicAdd(&ssum[l], r);
  }
  __syncthreads();
  float inv[5];
  const float dens[5] = {128.f, 384.f, 640.f, 896.f, 1152.f};
  #pragma unroll
  for (int l=0;l<5;l++) inv[l] = 1.0f/sqrtf(ssum[l]/dens[l] + 1e-8f);
  #pragma unroll
  for (int i=0;i<10;i++){
    int m = g + 2*i;
    if (m < MC){
      int l = l_of_m(m);
      xn[(size_t)n*MC*C + m*C + c] = vals[i] * inv[l] * scale[l*C + c];
    }
  }
}

// ---------------- attention pieces ----------------
__global__ __launch_bounds__(256) void k_qk(const float* xn, const float* Wq, const float* Wk, float* qb, float* kb){
  __shared__ float s[C];
  int n = blockIdx.x; int t = threadIdx.x;
  if (t < C) s[t] = xn[(size_t)n*MC*C + t];   // m=0 row
  __syncthreads();
  for (int o=t; o<512; o+=256){
    float aq=0.f, ak=0.f;
    for (int cc=0; cc<C; ++cc){
      float sv = s[cc];
      aq += sv*Wq[cc*512+o];
      ak += sv*Wk[cc*512+o];
    }
    qb[n*512+o] = aq;
    kb[n*512+o] = ak;
  }
}

__global__ __launch_bounds__(256) void k_logits(const float* qb, const float* kb, const float* alpha,
                                                const int* srcarr, const int* tgtarr, float* logits){
  int wid = threadIdx.x >> 6; int lane = threadIdx.x & 63;
  int e = blockIdx.x*4 + wid;
  if (e >= N_EDGES) return;
  int s = srcarr[e], tg = tgtarr[e];
  #pragma unroll
  for (int h=0; h<8; ++h){
    float qv = qb[tg*512 + h*64 + lane] + kb[s*512 + h*64 + lane];
    float v = silu(qv) * alpha[h*64 + lane];
    for (int d=32; d>0; d>>=1) v += __shfl_down(v, d, 64);
    if (lane == 0) logits[e*8 + h] = v * 0.125f;
  }
}

// one wave per node; lane = (edge-chunk<<3) | h; coalesced logits reads; natural attn layout
__global__ __launch_bounds__(256) void k_softmax(const float* logits, const int* rowptr, const int* elist, float* attnb){
  int n = blockIdx.x*4 + (threadIdx.x>>6);
  if (n >= N_NODES) return;
  int lane = threadIdx.x & 63;
  int h = lane & 7, ec = lane >> 3;     // 8 edges x 8 heads per pass
  int beg = rowptr[n], end = rowptr[n+1];
  float mx = -1e30f;
  for (int i=beg+ec; i<end; i+=8) mx = fmaxf(mx, logits[elist[i]*8+h]);
  #pragma unroll
  for (int dd=8; dd<64; dd<<=1) mx = fmaxf(mx, __shfl_xor(mx, dd, 64));
  float sum = 0.f;
  for (int i=beg+ec; i<end; i+=8) sum += expf(logits[elist[i]*8+h] - mx);
  #pragma unroll
  for (int dd=8; dd<64; dd<<=1) sum += __shfl_xor(sum, dd, 64);
  float inv = 1.0f/(sum + 1e-9f);
  for (int i=beg+ec; i<end; i+=8){
    int e = elist[i];
    attnb[e*8 + h] = expf(logits[e*8+h]-mx)*inv;
  }
}

// rad: 16 edges/block, Wrad + efeat tiles staged in LDS; output stride RSTR=20
__global__ __launch_bounds__(256) void k_rad(const float* efeat, const float* Wrad, float* radb){
  __shared__ float wsh[C*RSTR];     // wsh[cc*20+m]
  __shared__ float esh[16][132];
  int t = threadIdx.x;
  for (int q=t; q<C*MC; q+=256){ int cc=q/MC, m=q-cc*MC; wsh[cc*RSTR+m] = Wrad[q]; }
  int e0 = blockIdx.x*16;
  for (int q=t; q<16*C; q+=256) esh[q>>7][q&127] = efeat[(size_t)(e0+(q>>7))*C + (q&127)];
  __syncthreads();
  for (int q=t; q<16*MC; q+=256){
    int el = q/MC, m = q-el*MC;
    float acc = 0.f;
    #pragma unroll 4
    for (int cc=0; cc<C; ++cc) acc += esh[el][cc]*wsh[cc*RSTR+m];
    radb[(size_t)(e0+el)*RSTR + m] = silu(acc);
  }
}

// V[n] = xn[n] @ Wv   (19x128 @ 128x128 per node)
__global__ __launch_bounds__(256) void k_v(const float* __restrict__ xn, const float* __restrict__ Wv,
                                           float* __restrict__ V){
  __shared__ float xs[MC*C];
  int n = blockIdx.x; int t = threadIdx.x; int g = t>>7; int d = t&127;
  for (int q=t; q<MC*C; q+=256) xs[q] = xn[(size_t)n*MC*C+q];
  __syncthreads();
  float acc[10];
  #pragma unroll
  for (int i=0;i<10;i++) acc[i]=0.f;
  for (int cc=0; cc<C; ++cc){
    float w = Wv[cc*C + d];
    #pragma unroll
    for (int i=0;i<10;i++){
      int m = g + 2*i;
      if (m < MC) acc[i] += xs[m*C+cc]*w;
    }
  }
  #pragma unroll
  for (int i=0;i<10;i++){
    int m = g + 2*i;
    if (m < MC) V[(size_t)n*MC*C + m*C + d] = acc[i];
  }
}

// msum[n,m,d] = sum_e attn[e,h(d)]*rad[e,m]*V[src_e,m,d]  (10 accs/thread)
// then x[n] += msum @ Wo (fused via LDS)
__global__ __launch_bounds__(256) void k_e1(const float* __restrict__ V, const float* __restrict__ radb,
        const float* __restrict__ attnb, const float* __restrict__ Wo,
        const int* __restrict__ rowptr, const int* __restrict__ elist, const int* __restrict__ srcarr,
        float* __restrict__ x){
  __shared__ float msh[MC*C];          // 9728 B
  int n = blockIdx.x;
  int t = threadIdx.x; int g = t>>7; int c = t&127;
  int h = c >> 4;
  float acc[10];
  #pragma unroll
  for (int i=0;i<10;i++) acc[i]=0.f;
  int beg = rowptr[n], end = rowptr[n+1];
  for (int idx=beg; idx<end; ++idx){
    int e = elist[idx];
    int s = srcarr[e];
    float a = attnb[e*8 + h];
    const float* vr = V + (size_t)s*(MC*C) + c;
    const float* rr = radb + (size_t)e*RSTR;
    #pragma unroll
    for (int i=0;i<10;i++){
      int m = g + 2*i;
      if (m < MC) acc[i] += a * rr[m] * vr[m*C];
    }
  }
  #pragma unroll
  for (int i=0;i<10;i++){
    int m = g + 2*i;
    if (m < MC) msh[m*C + c] = acc[i];
  }
  __syncthreads();
  // x[n] += msh @ Wo
  float acc2[10];
  #pragma unroll
  for (int i=0;i<10;i++) acc2[i]=0.f;
  for (int d=0; d<C; ++d){
    float wo = Wo[d*C+c];
    #pragma unroll
    for (int i=0;i<10;i++){
      int m = g + 2*i;
      if (m < MC) acc2[i] += msh[m*C+d]*wo;
    }
  }
  #pragma unroll
  for (int i=0;i<10;i++){
    int m = g + 2*i;
    if (m < MC){
      size_t off = (size_t)n*MC*C + m*C + c;
      x[off] += acc2[i];
    }
  }
}

// ---------------- gated FFN ----------------
__global__ __launch_bounds__(256) void k_ffn(const float* xn, const float* W1, const float* W2, float* x){
  __shared__ float xs[MC*C];
  __shared__ float hb[MC*C];
  __shared__ float gate[C];
  int n = blockIdx.x; int t = threadIdx.x; int g = t>>7; int c = t&127;
  for (int q=t; q<MC*C; q+=256) xs[q] = xn[(size_t)n*MC*C+q];
  __syncthreads();
  {
    float acc[10];
    #pragma unroll
    for (int i=0;i<10;i++) acc[i]=0.f;
    for (int cc=0; cc<C; ++cc){
      float w = W1[cc*C+c];
      #pragma unroll
      for (int i=0;i<10;i++){
        int m = g+2*i;
        if (m<MC) acc[i] += xs[m*C+cc]*w;
      }
    }
    #pragma unroll
    for (int i=0;i<10;i++){
      int m = g+2*i;
      if (m<MC) hb[m*C+c] = acc[i];
    }
  }
  __syncthreads();
  if (t < C){ float v = hb[t]; gate[t] = silu(v); }
  __syncthreads();
  for (int q=t; q<MC*C; q+=256) hb[q] *= gate[q & 127];
  __syncthreads();
  {
    float acc[10];
    #pragma unroll
    for (int i=0;i<10;i++) acc[i]=0.f;
    for (int f=0; f<C; ++f){
      float w = W2[f*C+c];
      #pragma unroll
      for (int i=0;i<10;i++){
        int m = g+2*i;
        if (m<MC) acc[i] += hb[m*C+f]*w;
      }
    }
    #pragma unroll
    for (int i=0;i<10;i++){
      int m = g+2*i;
      if (m<MC){
        size_t off = (size_t)n*MC*C + m*C + c;
        x[off] += acc[i];
      }
    }
  }
}

// ---------------- final head (only l=0 row matters) ----------------
__global__ __launch_bounds__(128) void k_final(const float* x, const float* nsf, const float* Wef1,
        const float* Wef2, const int* batch, float* out){
  __shared__ float sl[C];
  __shared__ float red[2];
  __shared__ float red2[2];
  int n = blockIdx.x; int t = threadIdx.x;
  float v = x[(size_t)n*MC*C + t];
  float sq = v*v;
  for (int d=32; d>0; d>>=1) sq += __shfl_down(sq, d, 64);
  if ((t&63)==0) red[t>>6] = sq;
  __syncthreads();
  float ms = (red[0]+red[1]) * (1.0f/128.f);
  float inv = 1.0f/sqrtf(ms + 1e-8f);
  sl[t] = v*inv*nsf[t];
  __syncthreads();
  float acc = 0.f;
  for (int cc=0; cc<C; ++cc) acc += sl[cc]*Wef1[cc*C + t];
  float val = acc*silu(acc)*Wef2[t];
  for (int d=32; d>0; d>>=1) val += __shfl_down(val, d, 64);
  if ((t&63)==0) red2[t>>6] = val;
  __syncthreads();
  if (t==0){
    float ne = red2[0]+red2[1];
    atomicAdd(&out[batch[n]], ne * (1.0f/77.81317f));
  }
}

extern "C" void kernel_launch(void* const* d_in, const int* in_sizes, int n_in,
                              void* d_out, int out_size, void* d_ws, size_t ws_size,
                              hipStream_t stream){
  (void)in_sizes; (void)n_in; (void)ws_size;
  const int*   anum  = (const int*)d_in[0];
  const int*   eidx  = (const int*)d_in[1];
  const float* dist  = (const float*)d_in[2];
  const int*   batch = (const int*)d_in[3];
  const float* emb   = (const float*)d_in[4];
  const float* We1   = (const float*)d_in[5];
  const float* We2   = (const float*)d_in[6];
  const float* Wdeg  = (const float*)d_in[7];
  const float* ns1   = (const float*)d_in[8];
  const float* ns2   = (const float*)d_in[9];
  const float* Wq    = (const float*)d_in[10];
  const float* Wk    = (const float*)d_in[11];
  const float* alpha = (const float*)d_in[12];
  const float* Wv    = (const float*)d_in[13];
  const float* Wrad  = (const float*)d_in[14];
  const float* Wo    = (const float*)d_in[15];
  const float* W1    = (const float*)d_in[16];
  const float* W2    = (const float*)d_in[17];
  const float* nsf   = (const float*)d_in[18];
  const float* Wef1  = (const float*)d_in[19];
  const float* Wef2  = (const float*)d_in[20];
  float* out = (float*)d_out;

  const int* srcarr = eidx;
  const int* tgtarr = eidx + N_EDGES;

  char* wsb = (char*)d_ws;
  float* efeat = (float*)wsb;  wsb += (size_t)N_EDGES*C*4;
  float* efsum = (float*)wsb;  wsb += (size_t)N_NODES*C*4;
  float* x     = (float*)wsb;  wsb += (size_t)N_NODES*MC*C*4;
  float* xn    = (float*)wsb;  wsb += (size_t)N_NODES*MC*C*4;
  float* Vb    = (float*)wsb;  wsb += (size_t)N_NODES*MC*C*4;
  float* qb    = (float*)wsb;  wsb += (size_t)N_NODES*512*4;
  float* kb    = (float*)wsb;  wsb += (size_t)N_NODES*512*4;
  float* logit = (float*)wsb;  wsb += (size_t)N_EDGES*8*4;
  float* attnb = (float*)wsb;  wsb += (size_t)N_EDGES*8*4;
  float* radb  = (float*)wsb;  wsb += (size_t)N_EDGES*RSTR*4;
  int* deg     = (int*)wsb;    wsb += (size_t)N_NODES*4;
  int* rowptr  = (int*)wsb;    wsb += (size_t)(N_NODES+1)*4;
  int* cursor  = (int*)wsb;    wsb += (size_t)N_NODES*4;
  int* elist   = (int*)wsb;    wsb += (size_t)N_EDGES*4;

  (void)hipMemsetAsync(deg, 0, N_NODES*4, stream);
  (void)hipMemsetAsync(cursor, 0, N_NODES*4, stream);
  (void)hipMemsetAsync(d_out, 0, (size_t)out_size*sizeof(float), stream);

  k_count<<<(N_EDGES+255)/256, 256, 0, stream>>>(tgtarr, deg);
  k_scan<<<1, 64, 0, stream>>>(deg, rowptr);
  k_fill<<<(N_EDGES+255)/256, 256, 0, stream>>>(tgtarr, rowptr, cursor, elist);
  k_efeat<<<N_EDGES/2, 256, 0, stream>>>(dist, We1, We2, efeat);
  k_efsum<<<N_NODES, 128, 0, stream>>>(efeat, rowptr, elist, efsum);
  k_deginit<<<N_NODES, 256, 0, stream>>>(efsum, Wdeg, emb, anum, x);

  for (int i=0;i<NL;i++){
    k_rmsnorm<<<N_NODES, 256, 0, stream>>>(x, ns1 + i*5*C, xn);
    k_qk<<<N_NODES, 256, 0, stream>>>(xn, Wq + i*C*512, Wk + i*C*512, qb, kb);
    k_logits<<<(N_EDGES+3)/4, 256, 0, stream>>>(qb, kb, alpha + i*512, srcarr, tgtarr, logit);
    k_softmax<<<(N_NODES+3)/4, 256, 0, stream>>>(logit, rowptr, elist, attnb);
    k_rad<<<N_EDGES/16, 256, 0, stream>>>(efeat, Wrad + i*C*MC, radb);
    k_v<<<N_NODES, 256, 0, stream>>>(xn, Wv + i*C*C, Vb);
    k_e1<<<N_NODES, 256, 0, stream>>>(Vb, radb, attnb, Wo + i*C*C,
                                      rowptr, elist, srcarr, x);
    k_rmsnorm<<<N_NODES, 256, 0, stream>>>(x, ns2 + i*5*C, xn);
    k_ffn<<<N_NODES, 256, 0, stream>>>(xn, W1 + i*C*C, W2 + i*C*C, x);
  }
  k_final<<<N_NODES, 128, 0, stream>>>(x, nsf, Wef1, Wef2, batch, out);
}

// Round 5
// 2112.394 us; speedup vs baseline: 2.2091x; 1.3015x over previous
//
#include <hip/hip_runtime.h>

#define N_NODES 2500
#define N_EDGES 50000
#define C 128
#define MC 19
#define RSTR 20
#define NL 4
#define NB 600
#define GW 20

__device__ __forceinline__ float silu(float v){ return v / (1.f + expf(-v)); }
__device__ __forceinline__ int l_of_m(int m){
  return (m==0)?0 : (m<4)?1 : (m<9)?2 : (m<14)?3 : 4;
}

// ---------------- CSR build ----------------
__global__ void k_count(const int* tgt, int* deg){
  int e = blockIdx.x*256 + threadIdx.x;
  if (e < N_EDGES) atomicAdd(&deg[tgt[e]], 1);
}

__global__ void k_scan(const int* deg, int* rowptr){
  int lane = threadIdx.x;               // 64 threads
  const int CH = (N_NODES + 63)/64;     // 40
  int base = lane*CH;
  int s = 0;
  for (int i=0;i<CH;i++){ int idx=base+i; if (idx<N_NODES) s += deg[idx]; }
  int inc = s;
  for (int d=1; d<64; d<<=1){
    int v = __shfl_up(inc, d, 64);
    if (lane >= d) inc += v;
  }
  int run = inc - s;                    // exclusive prefix
  for (int i=0;i<CH;i++){
    int idx = base+i;
    if (idx < N_NODES){ rowptr[idx] = run; run += deg[idx]; }
  }
  if (lane == 63) rowptr[N_NODES] = run;
}

__global__ void k_fill(const int* tgt, const int* rowptr, int* cursor, int* elist){
  int e = blockIdx.x*256 + threadIdx.x;
  if (e < N_EDGES){
    int n = tgt[e];
    int pos = atomicAdd(&cursor[n], 1);
    elist[rowptr[n] + pos] = e;
  }
}

// ---------------- edge features ----------------
__global__ __launch_bounds__(256) void k_efeat(const float* dist, const float* We1, const float* We2, float* efeat){
  __shared__ float gbuf[2][2*GW+1];
  __shared__ float t1[2][C];
  int t = threadIdx.x;
  int sub = t >> 7; int c = t & 127;
  int e = blockIdx.x*2 + sub;
  float d = dist[e];
  const float delta = 12.0f/599.0f;
  const float coeff = -0.5f/((2.0f*delta)*(2.0f*delta));
  int jc = (int)floorf(d/delta + 0.5f);
  int j0 = jc - GW; if (j0 < 0) j0 = 0;
  int j1 = jc + GW; if (j1 > NB-1) j1 = NB-1;
  int cnt = j1 - j0 + 1;
  if (c < cnt){
    float off = (float)(j0 + c) * delta;
    float dd = d - off;
    gbuf[sub][c] = expf(coeff*dd*dd);
  }
  __syncthreads();
  float acc = 0.f;
  for (int w=0; w<cnt; ++w)
    acc += gbuf[sub][w] * We1[(j0+w)*C + c];
  t1[sub][c] = silu(acc);
  __syncthreads();
  float acc2 = 0.f;
  for (int cc=0; cc<C; ++cc)
    acc2 += t1[sub][cc] * We2[cc*C + c];
  efeat[e*C + c] = silu(acc2);
}

__global__ void k_efsum(const float* efeat, const int* rowptr, const int* elist, float* efsum){
  int n = blockIdx.x; int t = threadIdx.x; // 128 threads
  float acc = 0.f;
  int beg = rowptr[n], end = rowptr[n+1];
  for (int i=beg;i<end;i++)
    acc += efeat[elist[i]*C + t];
  efsum[n*C + t] = acc;
}

__global__ __launch_bounds__(256) void k_deginit(const float* efsum, const float* Wdeg, const float* emb,
                                                 const int* anum, float* x){
  __shared__ float ef[C];
  int n = blockIdx.x; int t = threadIdx.x;
  if (t < C) ef[t] = efsum[n*C+t];
  __syncthreads();
  int an = anum[n];
  const float inv_avg = 1.0f/23.395238876342773f;
  for (int o = t; o < MC*C; o += 256){
    float acc = 0.f;
    for (int cc=0; cc<C; ++cc) acc += ef[cc]*Wdeg[cc*(MC*C) + o];
    float val = acc * inv_avg;
    if (o < C) val += emb[an*C + o];
    x[(size_t)n*MC*C + o] = val;
  }
}

// ---------------- fused: rmsnorm1 + QK-proj + V-proj (xn stays in LDS) ----------------
__global__ __launch_bounds__(256) void k_nodeA(const float* __restrict__ x, const float* __restrict__ scale,
        const float* __restrict__ Wq, const float* __restrict__ Wk, const float* __restrict__ Wv,
        float* __restrict__ qb, float* __restrict__ kb, float* __restrict__ V){
  __shared__ __align__(16) float xs[MC*C];
  __shared__ float ssum[5];
  int n = blockIdx.x; int t = threadIdx.x;
  int g = t>>7, c = t&127;
  if (t < 5) ssum[t] = 0.f;
  __syncthreads();
  float vals[10];
  float pl[5] = {0,0,0,0,0};
  #pragma unroll
  for (int i=0;i<10;i++){
    int m = g + 2*i;
    if (m < MC){
      float v = x[(size_t)n*MC*C + m*C + c];
      vals[i] = v;
      pl[l_of_m(m)] += v*v;
    }
  }
  #pragma unroll
  for (int l=0;l<5;l++){
    float r = pl[l];
    for (int d=32; d>0; d>>=1) r += __shfl_down(r, d, 64);
    if ((t&63)==0) atomicAdd(&ssum[l], r);
  }
  __syncthreads();
  float inv[5];
  const float dens[5] = {128.f, 384.f, 640.f, 896.f, 1152.f};
  #pragma unroll
  for (int l=0;l<5;l++) inv[l] = 1.0f/sqrtf(ssum[l]/dens[l] + 1e-8f);
  #pragma unroll
  for (int i=0;i<10;i++){
    int m = g + 2*i;
    if (m < MC){
      int l = l_of_m(m);
      xs[m*C + c] = vals[i] * inv[l] * scale[l*C + c];
    }
  }
  __syncthreads();
  // ---- QK: thread owns outputs o, o+1 (o = 2t) ----
  {
    int o = t*2;
    float aq0=0,aq1=0,ak0=0,ak1=0;
    for (int cc=0; cc<C; cc+=4){
      float4 s4 = *(const float4*)&xs[cc];
      float2 q0 = *(const float2*)&Wq[(cc+0)*512 + o];
      float2 q1 = *(const float2*)&Wq[(cc+1)*512 + o];
      float2 q2 = *(const float2*)&Wq[(cc+2)*512 + o];
      float2 q3 = *(const float2*)&Wq[(cc+3)*512 + o];
      float2 k0 = *(const float2*)&Wk[(cc+0)*512 + o];
      float2 k1 = *(const float2*)&Wk[(cc+1)*512 + o];
      float2 k2 = *(const float2*)&Wk[(cc+2)*512 + o];
      float2 k3 = *(const float2*)&Wk[(cc+3)*512 + o];
      aq0 += s4.x*q0.x + s4.y*q1.x + s4.z*q2.x + s4.w*q3.x;
      aq1 += s4.x*q0.y + s4.y*q1.y + s4.z*q2.y + s4.w*q3.y;
      ak0 += s4.x*k0.x + s4.y*k1.x + s4.z*k2.x + s4.w*k3.x;
      ak1 += s4.x*k0.y + s4.y*k1.y + s4.z*k2.y + s4.w*k3.y;
    }
    qb[n*512+o] = aq0; qb[n*512+o+1] = aq1;
    kb[n*512+o] = ak0; kb[n*512+o+1] = ak1;
  }
  // ---- V = xs @ Wv : thread owns (m = g4+4i, cols c0,c0+1) ----
  {
    int c0 = (t&63)*2; int g4 = t>>6;
    float acc[5][2];
    #pragma unroll
    for (int i=0;i<5;i++){ acc[i][0]=0.f; acc[i][1]=0.f; }
    for (int cc=0; cc<C; cc+=4){
      float2 w0 = *(const float2*)&Wv[(cc+0)*C + c0];
      float2 w1 = *(const float2*)&Wv[(cc+1)*C + c0];
      float2 w2 = *(const float2*)&Wv[(cc+2)*C + c0];
      float2 w3 = *(const float2*)&Wv[(cc+3)*C + c0];
      #pragma unroll
      for (int i=0;i<5;i++){
        int m = g4 + 4*i;
        if (m < MC){
          float4 a4 = *(const float4*)&xs[m*C + cc];
          acc[i][0] += a4.x*w0.x + a4.y*w1.x + a4.z*w2.x + a4.w*w3.x;
          acc[i][1] += a4.x*w0.y + a4.y*w1.y + a4.z*w2.y + a4.w*w3.y;
        }
      }
    }
    #pragma unroll
    for (int i=0;i<5;i++){
      int m = g4 + 4*i;
      if (m < MC){
        V[(size_t)n*MC*C + m*C + c0]   = acc[i][0];
        V[(size_t)n*MC*C + m*C + c0+1] = acc[i][1];
      }
    }
  }
}

__global__ __launch_bounds__(256) void k_logits(const float* qb, const float* kb, const float* alpha,
                                                const int* srcarr, const int* tgtarr, float* logits){
  int wid = threadIdx.x >> 6; int lane = threadIdx.x & 63;
  int e = blockIdx.x*4 + wid;
  if (e >= N_EDGES) return;
  int s = srcarr[e], tg = tgtarr[e];
  #pragma unroll
  for (int h=0; h<8; ++h){
    float qv = qb[tg*512 + h*64 + lane] + kb[s*512 + h*64 + lane];
    float v = silu(qv) * alpha[h*64 + lane];
    for (int d=32; d>0; d>>=1) v += __shfl_down(v, d, 64);
    if (lane == 0) logits[e*8 + h] = v * 0.125f;
  }
}

// one wave per node; lane = (edge-chunk<<3) | h
__global__ __launch_bounds__(256) void k_softmax(const float* logits, const int* rowptr, const int* elist, float* attnb){
  int n = blockIdx.x*4 + (threadIdx.x>>6);
  if (n >= N_NODES) return;
  int lane = threadIdx.x & 63;
  int h = lane & 7, ec = lane >> 3;
  int beg = rowptr[n], end = rowptr[n+1];
  float mx = -1e30f;
  for (int i=beg+ec; i<end; i+=8) mx = fmaxf(mx, logits[elist[i]*8+h]);
  #pragma unroll
  for (int dd=8; dd<64; dd<<=1) mx = fmaxf(mx, __shfl_xor(mx, dd, 64));
  float sum = 0.f;
  for (int i=beg+ec; i<end; i+=8) sum += expf(logits[elist[i]*8+h] - mx);
  #pragma unroll
  for (int dd=8; dd<64; dd<<=1) sum += __shfl_xor(sum, dd, 64);
  float inv = 1.0f/(sum + 1e-9f);
  for (int i=beg+ec; i<end; i+=8){
    int e = elist[i];
    attnb[e*8 + h] = expf(logits[e*8+h]-mx)*inv;
  }
}

// rad: 16 edges/block
__global__ __launch_bounds__(256) void k_rad(const float* efeat, const float* Wrad, float* radb){
  __shared__ float wsh[C*RSTR];
  __shared__ float esh[16][132];
  int t = threadIdx.x;
  for (int q=t; q<C*MC; q+=256){ int cc=q/MC, m=q-cc*MC; wsh[cc*RSTR+m] = Wrad[q]; }
  int e0 = blockIdx.x*16;
  for (int q=t; q<16*C; q+=256) esh[q>>7][q&127] = efeat[(size_t)(e0+(q>>7))*C + (q&127)];
  __syncthreads();
  for (int q=t; q<16*MC; q+=256){
    int el = q/MC, m = q-el*MC;
    float acc = 0.f;
    #pragma unroll 4
    for (int cc=0; cc<C; ++cc) acc += esh[el][cc]*wsh[cc*RSTR+m];
    radb[(size_t)(e0+el)*RSTR + m] = silu(acc);
  }
}

// msum[n,m,d] = sum_e attn[e,h(d)]*rad[e,m]*V[src_e,m,d]; then x[n] += msum @ Wo
__global__ __launch_bounds__(256) void k_e1(const float* __restrict__ V, const float* __restrict__ radb,
        const float* __restrict__ attnb, const float* __restrict__ Wo,
        const int* __restrict__ rowptr, const int* __restrict__ elist, const int* __restrict__ srcarr,
        float* __restrict__ x){
  __shared__ __align__(16) float msh[MC*C];
  int n = blockIdx.x;
  int t = threadIdx.x;
  int c0 = (t&63)*2; int g4 = t>>6;
  int h = c0 >> 4;
  float acc[5][2];
  #pragma unroll
  for (int i=0;i<5;i++){ acc[i][0]=0.f; acc[i][1]=0.f; }
  int beg = rowptr[n], end = rowptr[n+1];
  for (int idx=beg; idx<end; ++idx){
    int e = elist[idx];
    int s = srcarr[e];
    float a = attnb[e*8 + h];
    const float* vr = V + (size_t)s*(MC*C) + c0;
    const float* rr = radb + (size_t)e*RSTR;
    #pragma unroll
    for (int i=0;i<5;i++){
      int m = g4 + 4*i;
      if (m < MC){
        float ar = a * rr[m];
        float2 v2 = *(const float2*)&vr[m*C];
        acc[i][0] += ar*v2.x;
        acc[i][1] += ar*v2.y;
      }
    }
  }
  #pragma unroll
  for (int i=0;i<5;i++){
    int m = g4 + 4*i;
    if (m < MC){ msh[m*C+c0] = acc[i][0]; msh[m*C+c0+1] = acc[i][1]; }
  }
  __syncthreads();
  // x[n] += msh @ Wo
  float acc2[5][2];
  #pragma unroll
  for (int i=0;i<5;i++){ acc2[i][0]=0.f; acc2[i][1]=0.f; }
  for (int d=0; d<C; d+=4){
    float2 w0 = *(const float2*)&Wo[(d+0)*C + c0];
    float2 w1 = *(const float2*)&Wo[(d+1)*C + c0];
    float2 w2 = *(const float2*)&Wo[(d+2)*C + c0];
    float2 w3 = *(const float2*)&Wo[(d+3)*C + c0];
    #pragma unroll
    for (int i=0;i<5;i++){
      int m = g4 + 4*i;
      if (m < MC){
        float4 m4 = *(const float4*)&msh[m*C + d];
        acc2[i][0] += m4.x*w0.x + m4.y*w1.x + m4.z*w2.x + m4.w*w3.x;
        acc2[i][1] += m4.x*w0.y + m4.y*w1.y + m4.z*w2.y + m4.w*w3.y;
      }
    }
  }
  #pragma unroll
  for (int i=0;i<5;i++){
    int m = g4 + 4*i;
    if (m < MC){
      size_t off = (size_t)n*MC*C + m*C + c0;
      x[off]   += acc2[i][0];
      x[off+1] += acc2[i][1];
    }
  }
}

// ---------------- fused: rmsnorm2 + gated FFN ----------------
__global__ __launch_bounds__(256) void k_nodeB(float* __restrict__ x, const float* __restrict__ scale,
        const float* __restrict__ W1, const float* __restrict__ W2){
  __shared__ __align__(16) float xs[MC*C];
  __shared__ __align__(16) float hb[MC*C];
  __shared__ float gate[C];
  __shared__ float ssum[5];
  int n = blockIdx.x; int t = threadIdx.x;
  int g = t>>7, c = t&127;
  if (t < 5) ssum[t] = 0.f;
  __syncthreads();
  {
    float vals[10];
    float pl[5] = {0,0,0,0,0};
    #pragma unroll
    for (int i=0;i<10;i++){
      int m = g + 2*i;
      if (m < MC){
        float v = x[(size_t)n*MC*C + m*C + c];
        vals[i] = v;
        pl[l_of_m(m)] += v*v;
      }
    }
    #pragma unroll
    for (int l=0;l<5;l++){
      float r = pl[l];
      for (int d=32; d>0; d>>=1) r += __shfl_down(r, d, 64);
      if ((t&63)==0) atomicAdd(&ssum[l], r);
    }
    __syncthreads();
    float inv[5];
    const float dens[5] = {128.f, 384.f, 640.f, 896.f, 1152.f};
    #pragma unroll
    for (int l=0;l<5;l++) inv[l] = 1.0f/sqrtf(ssum[l]/dens[l] + 1e-8f);
    #pragma unroll
    for (int i=0;i<10;i++){
      int m = g + 2*i;
      if (m < MC){
        int l = l_of_m(m);
        xs[m*C + c] = vals[i] * inv[l] * scale[l*C + c];
      }
    }
  }
  __syncthreads();
  int c0 = (t&63)*2; int g4 = t>>6;
  // hb = xs @ W1
  {
    float acc[5][2];
    #pragma unroll
    for (int i=0;i<5;i++){ acc[i][0]=0.f; acc[i][1]=0.f; }
    for (int cc=0; cc<C; cc+=4){
      float2 w0 = *(const float2*)&W1[(cc+0)*C + c0];
      float2 w1 = *(const float2*)&W1[(cc+1)*C + c0];
      float2 w2 = *(const float2*)&W1[(cc+2)*C + c0];
      float2 w3 = *(const float2*)&W1[(cc+3)*C + c0];
      #pragma unroll
      for (int i=0;i<5;i++){
        int m = g4 + 4*i;
        if (m < MC){
          float4 a4 = *(const float4*)&xs[m*C + cc];
          acc[i][0] += a4.x*w0.x + a4.y*w1.x + a4.z*w2.x + a4.w*w3.x;
          acc[i][1] += a4.x*w0.y + a4.y*w1.y + a4.z*w2.y + a4.w*w3.y;
        }
      }
    }
    #pragma unroll
    for (int i=0;i<5;i++){
      int m = g4 + 4*i;
      if (m < MC){ hb[m*C+c0] = acc[i][0]; hb[m*C+c0+1] = acc[i][1]; }
    }
  }
  __syncthreads();
  if (t < C){ float v = hb[t]; gate[t] = silu(v); }
  __syncthreads();
  for (int q=t; q<MC*C; q+=256) hb[q] *= gate[q & 127];
  __syncthreads();
  // x += hb @ W2
  {
    float acc[5][2];
    #pragma unroll
    for (int i=0;i<5;i++){ acc[i][0]=0.f; acc[i][1]=0.f; }
    for (int f=0; f<C; f+=4){
      float2 w0 = *(const float2*)&W2[(f+0)*C + c0];
      float2 w1 = *(const float2*)&W2[(f+1)*C + c0];
      float2 w2 = *(const float2*)&W2[(f+2)*C + c0];
      float2 w3 = *(const float2*)&W2[(f+3)*C + c0];
      #pragma unroll
      for (int i=0;i<5;i++){
        int m = g4 + 4*i;
        if (m < MC){
          float4 a4 = *(const float4*)&hb[m*C + f];
          acc[i][0] += a4.x*w0.x + a4.y*w1.x + a4.z*w2.x + a4.w*w3.x;
          acc[i][1] += a4.x*w0.y + a4.y*w1.y + a4.z*w2.y + a4.w*w3.y;
        }
      }
    }
    #pragma unroll
    for (int i=0;i<5;i++){
      int m = g4 + 4*i;
      if (m < MC){
        size_t off = (size_t)n*MC*C + m*C + c0;
        x[off]   += acc[i][0];
        x[off+1] += acc[i][1];
      }
    }
  }
}

// ---------------- final head (only l=0 row matters) ----------------
__global__ __launch_bounds__(128) void k_final(const float* x, const float* nsf, const float* Wef1,
        const float* Wef2, const int* batch, float* out){
  __shared__ float sl[C];
  __shared__ float red[2];
  __shared__ float red2[2];
  int n = blockIdx.x; int t = threadIdx.x;
  float v = x[(size_t)n*MC*C + t];
  float sq = v*v;
  for (int d=32; d>0; d>>=1) sq += __shfl_down(sq, d, 64);
  if ((t&63)==0) red[t>>6] = sq;
  __syncthreads();
  float ms = (red[0]+red[1]) * (1.0f/128.f);
  float inv = 1.0f/sqrtf(ms + 1e-8f);
  sl[t] = v*inv*nsf[t];
  __syncthreads();
  float acc = 0.f;
  for (int cc=0; cc<C; ++cc) acc += sl[cc]*Wef1[cc*C + t];
  float val = acc*silu(acc)*Wef2[t];
  for (int d=32; d>0; d>>=1) val += __shfl_down(val, d, 64);
  if ((t&63)==0) red2[t>>6] = val;
  __syncthreads();
  if (t==0){
    float ne = red2[0]+red2[1];
    atomicAdd(&out[batch[n]], ne * (1.0f/77.81317f));
  }
}

extern "C" void kernel_launch(void* const* d_in, const int* in_sizes, int n_in,
                              void* d_out, int out_size, void* d_ws, size_t ws_size,
                              hipStream_t stream){
  (void)in_sizes; (void)n_in; (void)ws_size;
  const int*   anum  = (const int*)d_in[0];
  const int*   eidx  = (const int*)d_in[1];
  const float* dist  = (const float*)d_in[2];
  const int*   batch = (const int*)d_in[3];
  const float* emb   = (const float*)d_in[4];
  const float* We1   = (const float*)d_in[5];
  const float* We2   = (const float*)d_in[6];
  const float* Wdeg  = (const float*)d_in[7];
  const float* ns1   = (const float*)d_in[8];
  const float* ns2   = (const float*)d_in[9];
  const float* Wq    = (const float*)d_in[10];
  const float* Wk    = (const float*)d_in[11];
  const float* alpha = (const float*)d_in[12];
  const float* Wv    = (const float*)d_in[13];
  const float* Wrad  = (const float*)d_in[14];
  const float* Wo    = (const float*)d_in[15];
  const float* W1    = (const float*)d_in[16];
  const float* W2    = (const float*)d_in[17];
  const float* nsf   = (const float*)d_in[18];
  const float* Wef1  = (const float*)d_in[19];
  const float* Wef2  = (const float*)d_in[20];
  float* out = (float*)d_out;

  const int* srcarr = eidx;
  const int* tgtarr = eidx + N_EDGES;

  char* wsb = (char*)d_ws;
  float* efeat = (float*)wsb;  wsb += (size_t)N_EDGES*C*4;
  float* efsum = (float*)wsb;  wsb += (size_t)N_NODES*C*4;
  float* x     = (float*)wsb;  wsb += (size_t)N_NODES*MC*C*4;
  float* Vb    = (float*)wsb;  wsb += (size_t)N_NODES*MC*C*4;
  float* qb    = (float*)wsb;  wsb += (size_t)N_NODES*512*4;
  float* kb    = (float*)wsb;  wsb += (size_t)N_NODES*512*4;
  float* logit = (float*)wsb;  wsb += (size_t)N_EDGES*8*4;
  float* attnb = (float*)wsb;  wsb += (size_t)N_EDGES*8*4;
  float* radb  = (float*)wsb;  wsb += (size_t)N_EDGES*RSTR*4;
  int* deg     = (int*)wsb;    wsb += (size_t)N_NODES*4;
  int* rowptr  = (int*)wsb;    wsb += (size_t)(N_NODES+1)*4;
  int* cursor  = (int*)wsb;    wsb += (size_t)N_NODES*4;
  int* elist   = (int*)wsb;    wsb += (size_t)N_EDGES*4;

  (void)hipMemsetAsync(deg, 0, N_NODES*4, stream);
  (void)hipMemsetAsync(cursor, 0, N_NODES*4, stream);
  (void)hipMemsetAsync(d_out, 0, (size_t)out_size*sizeof(float), stream);

  k_count<<<(N_EDGES+255)/256, 256, 0, stream>>>(tgtarr, deg);
  k_scan<<<1, 64, 0, stream>>>(deg, rowptr);
  k_fill<<<(N_EDGES+255)/256, 256, 0, stream>>>(tgtarr, rowptr, cursor, elist);
  k_efeat<<<N_EDGES/2, 256, 0, stream>>>(dist, We1, We2, efeat);
  k_efsum<<<N_NODES, 128, 0, stream>>>(efeat, rowptr, elist, efsum);
  k_deginit<<<N_NODES, 256, 0, stream>>>(efsum, Wdeg, emb, anum, x);

  for (int i=0;i<NL;i++){
    k_nodeA<<<N_NODES, 256, 0, stream>>>(x, ns1 + i*5*C, Wq + i*C*512, Wk + i*C*512,
                                         Wv + i*C*C, qb, kb, Vb);
    k_logits<<<(N_EDGES+3)/4, 256, 0, stream>>>(qb, kb, alpha + i*512, srcarr, tgtarr, logit);
    k_softmax<<<(N_NODES+3)/4, 256, 0, stream>>>(logit, rowptr, elist, attnb);
    k_rad<<<N_EDGES/16, 256, 0, stream>>>(efeat, Wrad + i*C*MC, radb);
    k_e1<<<N_NODES, 256, 0, stream>>>(Vb, radb, attnb, Wo + i*C*C,
                                      rowptr, elist, srcarr, x);
    k_nodeB<<<N_NODES, 256, 0, stream>>>(x, ns2 + i*5*C, W1 + i*C*C, W2 + i*C*C);
  }
  k_final<<<N_NODES, 128, 0, stream>>>(x, nsf, Wef1, Wef2, batch, out);
}

// Round 6
// 1884.101 us; speedup vs baseline: 2.4768x; 1.1212x over previous
//
#include <hip/hip_runtime.h>

#define N_NODES 2500
#define N_EDGES 50000
#define C 128
#define MC 19
#define RSTR 20
#define NL 4
#define NB 600
#define GW 20

__device__ __forceinline__ float silu(float v){ return v / (1.f + expf(-v)); }
__device__ __forceinline__ int l_of_m(int m){
  return (m==0)?0 : (m<4)?1 : (m<9)?2 : (m<14)?3 : 4;
}

// ---------------- CSR build ----------------
__global__ void k_count(const int* tgt, int* deg){
  int e = blockIdx.x*256 + threadIdx.x;
  if (e < N_EDGES) atomicAdd(&deg[tgt[e]], 1);
}

__global__ void k_scan(const int* deg, int* rowptr){
  int lane = threadIdx.x;               // 64 threads
  const int CH = (N_NODES + 63)/64;     // 40
  int base = lane*CH;
  int s = 0;
  for (int i=0;i<CH;i++){ int idx=base+i; if (idx<N_NODES) s += deg[idx]; }
  int inc = s;
  for (int d=1; d<64; d<<=1){
    int v = __shfl_up(inc, d, 64);
    if (lane >= d) inc += v;
  }
  int run = inc - s;                    // exclusive prefix
  for (int i=0;i<CH;i++){
    int idx = base+i;
    if (idx < N_NODES){ rowptr[idx] = run; run += deg[idx]; }
  }
  if (lane == 63) rowptr[N_NODES] = run;
}

__global__ void k_fill(const int* tgt, const int* rowptr, int* cursor, int* elist){
  int e = blockIdx.x*256 + threadIdx.x;
  if (e < N_EDGES){
    int n = tgt[e];
    int pos = atomicAdd(&cursor[n], 1);
    elist[rowptr[n] + pos] = e;
  }
}

// ---------------- edge features: 16 edges/block ----------------
__global__ __launch_bounds__(256) void k_efeat(const float* __restrict__ dist, const float* __restrict__ We1,
                                               const float* __restrict__ We2, float* __restrict__ efeat){
  __shared__ float gbuf[16][44];
  __shared__ __align__(16) float t1[16*132];
  __shared__ float dsh[16];
  __shared__ int j0s[16], cns[16];
  int t = threadIdx.x;
  int e0 = blockIdx.x*16;
  const float delta = 12.0f/599.0f;
  const float coeff = -0.5f/((2.0f*delta)*(2.0f*delta));
  if (t < 16){
    float d = dist[e0+t];
    int jc = (int)floorf(d/delta + 0.5f);
    int j0 = jc-GW; if (j0<0) j0=0;
    int j1 = jc+GW; if (j1>NB-1) j1=NB-1;
    dsh[t]=d; j0s[t]=j0; cns[t]=j1-j0+1;
  }
  __syncthreads();
  for (int q=t; q<16*41; q+=256){
    int el = q/41, w = q - el*41;
    float g = 0.f;
    if (w < cns[el]){
      float off = (float)(j0s[el]+w)*delta;
      float dd = dsh[el]-off;
      g = expf(coeff*dd*dd);
    }
    gbuf[el][w] = g;
  }
  __syncthreads();
  int el = t>>4, cl = t&15;
  int j0 = j0s[el];
  // stage 1: t1 = silu(gauss @ We1)   (gbuf zero-padded; row clamped)
  {
    float acc[8];
    #pragma unroll
    for (int k=0;k<8;k++) acc[k]=0.f;
    for (int w=0; w<41; ++w){
      float g = gbuf[el][w];
      int row = j0+w; if (row > NB-1) row = NB-1;
      const float* wr = We1 + (size_t)row*C + cl;
      #pragma unroll
      for (int k=0;k<8;k++) acc[k] += g*wr[16*k];
    }
    #pragma unroll
    for (int k=0;k<8;k++) t1[el*132 + cl + 16*k] = silu(acc[k]);
  }
  __syncthreads();
  // stage 2: efeat = silu(t1 @ We2)
  {
    float a0[4], a1[4];
    #pragma unroll
    for (int k=0;k<4;k++){ a0[k]=0.f; a1[k]=0.f; }
    for (int cc=0; cc<C; cc+=4){
      float4 v = *(const float4*)&t1[el*132 + cc];
      #pragma unroll
      for (int k=0;k<4;k++){
        int c0 = cl*2 + 32*k;
        float2 w0 = *(const float2*)&We2[(cc+0)*C + c0];
        float2 w1 = *(const float2*)&We2[(cc+1)*C + c0];
        float2 w2 = *(const float2*)&We2[(cc+2)*C + c0];
        float2 w3 = *(const float2*)&We2[(cc+3)*C + c0];
        a0[k] += v.x*w0.x + v.y*w1.x + v.z*w2.x + v.w*w3.x;
        a1[k] += v.x*w0.y + v.y*w1.y + v.z*w2.y + v.w*w3.y;
      }
    }
    #pragma unroll
    for (int k=0;k<4;k++){
      int c0 = cl*2 + 32*k;
      float2 st; st.x = silu(a0[k]); st.y = silu(a1[k]);
      *(float2*)&efeat[(size_t)(e0+el)*C + c0] = st;
    }
  }
}

__global__ void k_efsum(const float* efeat, const int* rowptr, const int* elist, float* efsum){
  int n = blockIdx.x; int t = threadIdx.x; // 128 threads
  float acc = 0.f;
  int beg = rowptr[n], end = rowptr[n+1];
  for (int i=beg;i<end;i++)
    acc += efeat[elist[i]*C + t];
  efsum[n*C + t] = acc;
}

// ---------------- deg-init: 8 nodes/block; x = emb(m=0) + (efsum@Wdeg)/avg ----------------
__global__ __launch_bounds__(256) void k_deginit(const float* __restrict__ efsum, const float* __restrict__ Wdeg,
        const float* __restrict__ emb, const int* __restrict__ anum, float* __restrict__ x){
  __shared__ __align__(16) float efT[C][8];
  int t = threadIdx.x;
  int n0 = blockIdx.x*8;
  for (int q=t; q<8*C; q+=256){
    int nd=q>>7, cc=q&127;
    int n=n0+nd;
    efT[cc][nd] = (n<N_NODES)? efsum[n*C+cc] : 0.f;
  }
  __syncthreads();
  const float inv_avg = 1.0f/23.395238876342773f;
  #pragma unroll
  for (int grp=0; grp<5; ++grp){
    int o = grp*512 + t*2;
    if (o < MC*C){
      float a0[8], a1[8];
      #pragma unroll
      for (int i=0;i<8;i++){ a0[i]=0.f; a1[i]=0.f; }
      for (int cc=0; cc<C; ++cc){
        float2 w = *(const float2*)&Wdeg[(size_t)cc*(MC*C)+o];
        float4 e0 = *(const float4*)&efT[cc][0];
        float4 e1 = *(const float4*)&efT[cc][4];
        a0[0]+=e0.x*w.x; a1[0]+=e0.x*w.y;
        a0[1]+=e0.y*w.x; a1[1]+=e0.y*w.y;
        a0[2]+=e0.z*w.x; a1[2]+=e0.z*w.y;
        a0[3]+=e0.w*w.x; a1[3]+=e0.w*w.y;
        a0[4]+=e1.x*w.x; a1[4]+=e1.x*w.y;
        a0[5]+=e1.y*w.x; a1[5]+=e1.y*w.y;
        a0[6]+=e1.z*w.x; a1[6]+=e1.z*w.y;
        a0[7]+=e1.w*w.x; a1[7]+=e1.w*w.y;
      }
      #pragma unroll
      for (int nd=0; nd<8; ++nd){
        int n = n0+nd;
        if (n < N_NODES){
          float v0 = a0[nd]*inv_avg, v1 = a1[nd]*inv_avg;
          if (o < C){ int an=anum[n]; v0 += emb[an*C+o]; v1 += emb[an*C+o+1]; }
          float2 st; st.x=v0; st.y=v1;
          *(float2*)&x[(size_t)n*MC*C + o] = st;
        }
      }
    }
  }
}

// ---------------- fused: rmsnorm1 + QK + V, 4 nodes/block ----------------
__global__ __launch_bounds__(256) void k_nodeA(const float* __restrict__ x, const float* __restrict__ scale,
        const float* __restrict__ Wq, const float* __restrict__ Wk, const float* __restrict__ Wv,
        float* __restrict__ qb, float* __restrict__ kb, float* __restrict__ V){
  __shared__ __align__(16) float xs[4*MC*C];   // 38912 B
  int t = threadIdx.x;
  int n0 = blockIdx.x*4;
  // norm: 64-lane group ng handles node n0+ng
  {
    int ng = t>>6, lane = t&63;
    int n = n0+ng;
    float2 xv[MC];
    float pl[5]={0.f,0.f,0.f,0.f,0.f};
    #pragma unroll
    for (int m=0;m<MC;m++){
      float2 v = *(const float2*)&x[(size_t)n*MC*C + m*C + lane*2];
      xv[m]=v;
      pl[l_of_m(m)] += v.x*v.x + v.y*v.y;
    }
    #pragma unroll
    for (int l=0;l<5;l++){
      float r = pl[l];
      #pragma unroll
      for (int d=32; d>0; d>>=1) r += __shfl_xor(r, d, 64);
      pl[l]=r;
    }
    const float dens[5] = {128.f,384.f,640.f,896.f,1152.f};
    float inv[5];
    #pragma unroll
    for (int l=0;l<5;l++) inv[l] = 1.0f/sqrtf(pl[l]/dens[l] + 1e-8f);
    #pragma unroll
    for (int m=0;m<MC;m++){
      int l = l_of_m(m);
      float2 sc = *(const float2*)&scale[l*C + lane*2];
      float2 st; st.x = xv[m].x*inv[l]*sc.x; st.y = xv[m].y*inv[l]*sc.y;
      *(float2*)&xs[ng*MC*C + m*C + lane*2] = st;
    }
  }
  __syncthreads();
  // QK: thread owns o,o+1 for all 4 nodes
  {
    int o = t*2;
    float aq[4][2], ak[4][2];
    #pragma unroll
    for (int nd=0; nd<4; ++nd){ aq[nd][0]=aq[nd][1]=ak[nd][0]=ak[nd][1]=0.f; }
    for (int cc=0; cc<C; cc+=4){
      float2 q0 = *(const float2*)&Wq[(cc+0)*512 + o];
      float2 q1 = *(const float2*)&Wq[(cc+1)*512 + o];
      float2 q2 = *(const float2*)&Wq[(cc+2)*512 + o];
      float2 q3 = *(const float2*)&Wq[(cc+3)*512 + o];
      float2 k0 = *(const float2*)&Wk[(cc+0)*512 + o];
      float2 k1 = *(const float2*)&Wk[(cc+1)*512 + o];
      float2 k2 = *(const float2*)&Wk[(cc+2)*512 + o];
      float2 k3 = *(const float2*)&Wk[(cc+3)*512 + o];
      #pragma unroll
      for (int nd=0; nd<4; ++nd){
        float4 s4 = *(const float4*)&xs[nd*MC*C + cc];
        aq[nd][0] += s4.x*q0.x + s4.y*q1.x + s4.z*q2.x + s4.w*q3.x;
        aq[nd][1] += s4.x*q0.y + s4.y*q1.y + s4.z*q2.y + s4.w*q3.y;
        ak[nd][0] += s4.x*k0.x + s4.y*k1.x + s4.z*k2.x + s4.w*k3.x;
        ak[nd][1] += s4.x*k0.y + s4.y*k1.y + s4.z*k2.y + s4.w*k3.y;
      }
    }
    #pragma unroll
    for (int nd=0; nd<4; ++nd){
      float2 sq; sq.x=aq[nd][0]; sq.y=aq[nd][1];
      float2 sk; sk.x=ak[nd][0]; sk.y=ak[nd][1];
      *(float2*)&qb[(size_t)(n0+nd)*512 + o] = sq;
      *(float2*)&kb[(size_t)(n0+nd)*512 + o] = sk;
    }
  }
  // V = xs @ Wv : thread owns (m-stripe g4, cols c0,c0+1) for all 4 nodes
  {
    int c0 = (t&63)*2, g4 = t>>6;
    float acc[4][5][2];
    #pragma unroll
    for (int nd=0; nd<4; ++nd)
      #pragma unroll
      for (int i=0;i<5;i++){ acc[nd][i][0]=0.f; acc[nd][i][1]=0.f; }
    for (int cc=0; cc<C; cc+=4){
      float2 w0 = *(const float2*)&Wv[(cc+0)*C + c0];
      float2 w1 = *(const float2*)&Wv[(cc+1)*C + c0];
      float2 w2 = *(const float2*)&Wv[(cc+2)*C + c0];
      float2 w3 = *(const float2*)&Wv[(cc+3)*C + c0];
      #pragma unroll
      for (int nd=0; nd<4; ++nd){
        #pragma unroll
        for (int i=0;i<5;i++){
          int m = g4 + 4*i;
          if (m < MC){
            float4 a4 = *(const float4*)&xs[nd*MC*C + m*C + cc];
            acc[nd][i][0] += a4.x*w0.x + a4.y*w1.x + a4.z*w2.x + a4.w*w3.x;
            acc[nd][i][1] += a4.x*w0.y + a4.y*w1.y + a4.z*w2.y + a4.w*w3.y;
          }
        }
      }
    }
    #pragma unroll
    for (int nd=0; nd<4; ++nd){
      #pragma unroll
      for (int i=0;i<5;i++){
        int m = g4 + 4*i;
        if (m < MC){
          float2 st; st.x=acc[nd][i][0]; st.y=acc[nd][i][1];
          *(float2*)&V[(size_t)(n0+nd)*MC*C + m*C + c0] = st;
        }
      }
    }
  }
}

__global__ __launch_bounds__(256) void k_logits(const float* qb, const float* kb, const float* alpha,
                                                const int* srcarr, const int* tgtarr, float* logits){
  int wid = threadIdx.x >> 6; int lane = threadIdx.x & 63;
  int e = blockIdx.x*4 + wid;
  if (e >= N_EDGES) return;
  int s = srcarr[e], tg = tgtarr[e];
  #pragma unroll
  for (int h=0; h<8; ++h){
    float qv = qb[tg*512 + h*64 + lane] + kb[s*512 + h*64 + lane];
    float v = silu(qv) * alpha[h*64 + lane];
    for (int d=32; d>0; d>>=1) v += __shfl_down(v, d, 64);
    if (lane == 0) logits[e*8 + h] = v * 0.125f;
  }
}

// one wave per node; lane = (edge-chunk<<3) | h
__global__ __launch_bounds__(256) void k_softmax(const float* logits, const int* rowptr, const int* elist, float* attnb){
  int n = blockIdx.x*4 + (threadIdx.x>>6);
  if (n >= N_NODES) return;
  int lane = threadIdx.x & 63;
  int h = lane & 7, ec = lane >> 3;
  int beg = rowptr[n], end = rowptr[n+1];
  float mx = -1e30f;
  for (int i=beg+ec; i<end; i+=8) mx = fmaxf(mx, logits[elist[i]*8+h]);
  #pragma unroll
  for (int dd=8; dd<64; dd<<=1) mx = fmaxf(mx, __shfl_xor(mx, dd, 64));
  float sum = 0.f;
  for (int i=beg+ec; i<end; i+=8) sum += expf(logits[elist[i]*8+h] - mx);
  #pragma unroll
  for (int dd=8; dd<64; dd<<=1) sum += __shfl_xor(sum, dd, 64);
  float inv = 1.0f/(sum + 1e-9f);
  for (int i=beg+ec; i<end; i+=8){
    int e = elist[i];
    attnb[e*8 + h] = expf(logits[e*8+h]-mx)*inv;
  }
}

// rad: 16 edges/block
__global__ __launch_bounds__(256) void k_rad(const float* efeat, const float* Wrad, float* radb){
  __shared__ float wsh[C*RSTR];
  __shared__ float esh[16][132];
  int t = threadIdx.x;
  for (int q=t; q<C*MC; q+=256){ int cc=q/MC, m=q-cc*MC; wsh[cc*RSTR+m] = Wrad[q]; }
  int e0 = blockIdx.x*16;
  for (int q=t; q<16*C; q+=256) esh[q>>7][q&127] = efeat[(size_t)(e0+(q>>7))*C + (q&127)];
  __syncthreads();
  for (int q=t; q<16*MC; q+=256){
    int el = q/MC, m = q-el*MC;
    float acc = 0.f;
    #pragma unroll 4
    for (int cc=0; cc<C; ++cc) acc += esh[el][cc]*wsh[cc*RSTR+m];
    radb[(size_t)(e0+el)*RSTR + m] = silu(acc);
  }
}

// msum[n,m,d] = sum_e attn[e,h(d)]*rad[e,m]*V[src_e,m,d]; then x[n] += msum @ Wo
__global__ __launch_bounds__(256) void k_e1(const float* __restrict__ V, const float* __restrict__ radb,
        const float* __restrict__ attnb, const float* __restrict__ Wo,
        const int* __restrict__ rowptr, const int* __restrict__ elist, const int* __restrict__ srcarr,
        float* __restrict__ x){
  __shared__ __align__(16) float msh[MC*C];
  int n = blockIdx.x;
  int t = threadIdx.x;
  int c0 = (t&63)*2; int g4 = t>>6;
  int h = c0 >> 4;
  float acc[5][2];
  #pragma unroll
  for (int i=0;i<5;i++){ acc[i][0]=0.f; acc[i][1]=0.f; }
  int beg = rowptr[n], end = rowptr[n+1];
  for (int idx=beg; idx<end; ++idx){
    int e = elist[idx];
    int s = srcarr[e];
    float a = attnb[e*8 + h];
    const float* vr = V + (size_t)s*(MC*C) + c0;
    const float* rr = radb + (size_t)e*RSTR;
    #pragma unroll
    for (int i=0;i<5;i++){
      int m = g4 + 4*i;
      if (m < MC){
        float ar = a * rr[m];
        float2 v2 = *(const float2*)&vr[m*C];
        acc[i][0] += ar*v2.x;
        acc[i][1] += ar*v2.y;
      }
    }
  }
  #pragma unroll
  for (int i=0;i<5;i++){
    int m = g4 + 4*i;
    if (m < MC){ msh[m*C+c0] = acc[i][0]; msh[m*C+c0+1] = acc[i][1]; }
  }
  __syncthreads();
  // x[n] += msh @ Wo
  float acc2[5][2];
  #pragma unroll
  for (int i=0;i<5;i++){ acc2[i][0]=0.f; acc2[i][1]=0.f; }
  for (int d=0; d<C; d+=4){
    float2 w0 = *(const float2*)&Wo[(d+0)*C + c0];
    float2 w1 = *(const float2*)&Wo[(d+1)*C + c0];
    float2 w2 = *(const float2*)&Wo[(d+2)*C + c0];
    float2 w3 = *(const float2*)&Wo[(d+3)*C + c0];
    #pragma unroll
    for (int i=0;i<5;i++){
      int m = g4 + 4*i;
      if (m < MC){
        float4 m4 = *(const float4*)&msh[m*C + d];
        acc2[i][0] += m4.x*w0.x + m4.y*w1.x + m4.z*w2.x + m4.w*w3.x;
        acc2[i][1] += m4.x*w0.y + m4.y*w1.y + m4.z*w2.y + m4.w*w3.y;
      }
    }
  }
  #pragma unroll
  for (int i=0;i<5;i++){
    int m = g4 + 4*i;
    if (m < MC){
      size_t off = (size_t)n*MC*C + m*C + c0;
      x[off]   += acc2[i][0];
      x[off+1] += acc2[i][1];
    }
  }
}

// ---------------- fused: rmsnorm2 + gated FFN, 2 nodes/block ----------------
__global__ __launch_bounds__(256) void k_nodeB(float* __restrict__ x, const float* __restrict__ scale,
        const float* __restrict__ W1, const float* __restrict__ W2){
  __shared__ __align__(16) float xs[2*MC*C];
  __shared__ __align__(16) float hb[2*MC*C];
  __shared__ float gate[2*C];
  __shared__ float ssum[2][5];
  int t = threadIdx.x;
  int n0 = blockIdx.x*2;
  int ng = t>>7, c = t&127;
  int n = n0+ng;
  if (t < 10) ssum[t/5][t%5] = 0.f;
  __syncthreads();
  {
    float vals[MC];
    float pl[5]={0.f,0.f,0.f,0.f,0.f};
    #pragma unroll
    for (int m=0;m<MC;m++){
      float v = x[(size_t)n*MC*C + m*C + c];
      vals[m]=v;
      pl[l_of_m(m)] += v*v;
    }
    #pragma unroll
    for (int l=0;l<5;l++){
      float r = pl[l];
      #pragma unroll
      for (int d=32; d>0; d>>=1) r += __shfl_down(r, d, 64);
      if ((t&63)==0) atomicAdd(&ssum[ng][l], r);
    }
    __syncthreads();
    const float dens[5] = {128.f,384.f,640.f,896.f,1152.f};
    float inv[5];
    #pragma unroll
    for (int l=0;l<5;l++) inv[l] = 1.0f/sqrtf(ssum[ng][l]/dens[l] + 1e-8f);
    #pragma unroll
    for (int m=0;m<MC;m++){
      int l = l_of_m(m);
      xs[ng*MC*C + m*C + c] = vals[m]*inv[l]*scale[l*C + c];
    }
  }
  __syncthreads();
  int c0 = (t&63)*2, g4 = t>>6;
  // hb = xs @ W1
  {
    float acc[2][5][2];
    #pragma unroll
    for (int nd=0; nd<2; ++nd)
      #pragma unroll
      for (int i=0;i<5;i++){ acc[nd][i][0]=0.f; acc[nd][i][1]=0.f; }
    for (int cc=0; cc<C; cc+=4){
      float2 w0 = *(const float2*)&W1[(cc+0)*C + c0];
      float2 w1 = *(const float2*)&W1[(cc+1)*C + c0];
      float2 w2 = *(const float2*)&W1[(cc+2)*C + c0];
      float2 w3 = *(const float2*)&W1[(cc+3)*C + c0];
      #pragma unroll
      for (int nd=0; nd<2; ++nd){
        #pragma unroll
        for (int i=0;i<5;i++){
          int m = g4 + 4*i;
          if (m < MC){
            float4 a4 = *(const float4*)&xs[nd*MC*C + m*C + cc];
            acc[nd][i][0] += a4.x*w0.x + a4.y*w1.x + a4.z*w2.x + a4.w*w3.x;
            acc[nd][i][1] += a4.x*w0.y + a4.y*w1.y + a4.z*w2.y + a4.w*w3.y;
          }
        }
      }
    }
    #pragma unroll
    for (int nd=0; nd<2; ++nd)
      #pragma unroll
      for (int i=0;i<5;i++){
        int m = g4 + 4*i;
        if (m < MC){ hb[nd*MC*C + m*C + c0] = acc[nd][i][0]; hb[nd*MC*C + m*C + c0+1] = acc[nd][i][1]; }
      }
  }
  __syncthreads();
  {
    int nd = t>>7, cg = t&127;
    gate[nd*C+cg] = silu(hb[nd*MC*C + cg]);
  }
  __syncthreads();
  #pragma unroll
  for (int nd=0; nd<2; ++nd)
    for (int q=t; q<MC*C; q+=256)
      hb[nd*MC*C + q] *= gate[nd*C + (q&127)];
  __syncthreads();
  // x += hb @ W2
  {
    float acc[2][5][2];
    #pragma unroll
    for (int nd=0; nd<2; ++nd)
      #pragma unroll
      for (int i=0;i<5;i++){ acc[nd][i][0]=0.f; acc[nd][i][1]=0.f; }
    for (int f=0; f<C; f+=4){
      float2 w0 = *(const float2*)&W2[(f+0)*C + c0];
      float2 w1 = *(const float2*)&W2[(f+1)*C + c0];
      float2 w2 = *(const float2*)&W2[(f+2)*C + c0];
      float2 w3 = *(const float2*)&W2[(f+3)*C + c0];
      #pragma unroll
      for (int nd=0; nd<2; ++nd){
        #pragma unroll
        for (int i=0;i<5;i++){
          int m = g4 + 4*i;
          if (m < MC){
            float4 a4 = *(const float4*)&hb[nd*MC*C + m*C + f];
            acc[nd][i][0] += a4.x*w0.x + a4.y*w1.x + a4.z*w2.x + a4.w*w3.x;
            acc[nd][i][1] += a4.x*w0.y + a4.y*w1.y + a4.z*w2.y + a4.w*w3.y;
          }
        }
      }
    }
    #pragma unroll
    for (int nd=0; nd<2; ++nd)
      #pragma unroll
      for (int i=0;i<5;i++){
        int m = g4 + 4*i;
        if (m < MC){
          size_t off = (size_t)(n0+nd)*MC*C + m*C + c0;
          float2 old = *(float2*)&x[off];
          old.x += acc[nd][i][0];
          old.y += acc[nd][i][1];
          *(float2*)&x[off] = old;
        }
      }
  }
}

// ---------------- final head (only l=0 row matters) ----------------
__global__ __launch_bounds__(128) void k_final(const float* x, const float* nsf, const float* Wef1,
        const float* Wef2, const int* batch, float* out){
  __shared__ float sl[C];
  __shared__ float red[2];
  __shared__ float red2[2];
  int n = blockIdx.x; int t = threadIdx.x;
  float v = x[(size_t)n*MC*C + t];
  float sq = v*v;
  for (int d=32; d>0; d>>=1) sq += __shfl_down(sq, d, 64);
  if ((t&63)==0) red[t>>6] = sq;
  __syncthreads();
  float ms = (red[0]+red[1]) * (1.0f/128.f);
  float inv = 1.0f/sqrtf(ms + 1e-8f);
  sl[t] = v*inv*nsf[t];
  __syncthreads();
  float acc = 0.f;
  for (int cc=0; cc<C; ++cc) acc += sl[cc]*Wef1[cc*C + t];
  float val = acc*silu(acc)*Wef2[t];
  for (int d=32; d>0; d>>=1) val += __shfl_down(val, d, 64);
  if ((t&63)==0) red2[t>>6] = val;
  __syncthreads();
  if (t==0){
    float ne = red2[0]+red2[1];
    atomicAdd(&out[batch[n]], ne * (1.0f/77.81317f));
  }
}

extern "C" void kernel_launch(void* const* d_in, const int* in_sizes, int n_in,
                              void* d_out, int out_size, void* d_ws, size_t ws_size,
                              hipStream_t stream){
  (void)in_sizes; (void)n_in; (void)ws_size;
  const int*   anum  = (const int*)d_in[0];
  const int*   eidx  = (const int*)d_in[1];
  const float* dist  = (const float*)d_in[2];
  const int*   batch = (const int*)d_in[3];
  const float* emb   = (const float*)d_in[4];
  const float* We1   = (const float*)d_in[5];
  const float* We2   = (const float*)d_in[6];
  const float* Wdeg  = (const float*)d_in[7];
  const float* ns1   = (const float*)d_in[8];
  const float* ns2   = (const float*)d_in[9];
  const float* Wq    = (const float*)d_in[10];
  const float* Wk    = (const float*)d_in[11];
  const float* alpha = (const float*)d_in[12];
  const float* Wv    = (const float*)d_in[13];
  const float* Wrad  = (const float*)d_in[14];
  const float* Wo    = (const float*)d_in[15];
  const float* W1    = (const float*)d_in[16];
  const float* W2    = (const float*)d_in[17];
  const float* nsf   = (const float*)d_in[18];
  const float* Wef1  = (const float*)d_in[19];
  const float* Wef2  = (const float*)d_in[20];
  float* out = (float*)d_out;

  const int* srcarr = eidx;
  const int* tgtarr = eidx + N_EDGES;

  char* wsb = (char*)d_ws;
  float* efeat = (float*)wsb;  wsb += (size_t)N_EDGES*C*4;
  float* efsum = (float*)wsb;  wsb += (size_t)N_NODES*C*4;
  float* x     = (float*)wsb;  wsb += (size_t)N_NODES*MC*C*4;
  float* Vb    = (float*)wsb;  wsb += (size_t)N_NODES*MC*C*4;
  float* qb    = (float*)wsb;  wsb += (size_t)N_NODES*512*4;
  float* kb    = (float*)wsb;  wsb += (size_t)N_NODES*512*4;
  float* logit = (float*)wsb;  wsb += (size_t)N_EDGES*8*4;
  float* attnb = (float*)wsb;  wsb += (size_t)N_EDGES*8*4;
  float* radb  = (float*)wsb;  wsb += (size_t)N_EDGES*RSTR*4;
  int* deg     = (int*)wsb;    wsb += (size_t)N_NODES*4;
  int* rowptr  = (int*)wsb;    wsb += (size_t)(N_NODES+1)*4;
  int* cursor  = (int*)wsb;    wsb += (size_t)N_NODES*4;
  int* elist   = (int*)wsb;    wsb += (size_t)N_EDGES*4;

  (void)hipMemsetAsync(deg, 0, N_NODES*4, stream);
  (void)hipMemsetAsync(cursor, 0, N_NODES*4, stream);
  (void)hipMemsetAsync(d_out, 0, (size_t)out_size*sizeof(float), stream);

  k_count<<<(N_EDGES+255)/256, 256, 0, stream>>>(tgtarr, deg);
  k_scan<<<1, 64, 0, stream>>>(deg, rowptr);
  k_fill<<<(N_EDGES+255)/256, 256, 0, stream>>>(tgtarr, rowptr, cursor, elist);
  k_efeat<<<N_EDGES/16, 256, 0, stream>>>(dist, We1, We2, efeat);
  k_efsum<<<N_NODES, 128, 0, stream>>>(efeat, rowptr, elist, efsum);
  k_deginit<<<(N_NODES+7)/8, 256, 0, stream>>>(efsum, Wdeg, emb, anum, x);

  for (int i=0;i<NL;i++){
    k_nodeA<<<N_NODES/4, 256, 0, stream>>>(x, ns1 + i*5*C, Wq + i*C*512, Wk + i*C*512,
                                           Wv + i*C*C, qb, kb, Vb);
    k_logits<<<(N_EDGES+3)/4, 256, 0, stream>>>(qb, kb, alpha + i*512, srcarr, tgtarr, logit);
    k_softmax<<<(N_NODES+3)/4, 256, 0, stream>>>(logit, rowptr, elist, attnb);
    k_rad<<<N_EDGES/16, 256, 0, stream>>>(efeat, Wrad + i*C*MC, radb);
    k_e1<<<N_NODES, 256, 0, stream>>>(Vb, radb, attnb, Wo + i*C*C,
                                      rowptr, elist, srcarr, x);
    k_nodeB<<<N_NODES/2, 256, 0, stream>>>(x, ns2 + i*5*C, W1 + i*C*C, W2 + i*C*C);
  }
  k_final<<<N_NODES, 128, 0, stream>>>(x, nsf, Wef1, Wef2, batch, out);
}

// Round 7
// 1750.594 us; speedup vs baseline: 2.6657x; 1.0763x over previous
//
#include <hip/hip_runtime.h>

#define N_NODES 2500
#define N_EDGES 50000
#define C 128
#define MC 19
#define RSTR 20
#define NL 4
#define NB 600
#define GW 20

__device__ __forceinline__ float silu(float v){ return v / (1.f + expf(-v)); }
__device__ __forceinline__ int l_of_m(int m){
  return (m==0)?0 : (m<4)?1 : (m<9)?2 : (m<14)?3 : 4;
}

// ---------------- CSR build ----------------
__global__ void k_count(const int* tgt, int* deg){
  int e = blockIdx.x*256 + threadIdx.x;
  if (e < N_EDGES) atomicAdd(&deg[tgt[e]], 1);
}

__global__ void k_scan(const int* deg, int* rowptr){
  int lane = threadIdx.x;               // 64 threads
  const int CH = (N_NODES + 63)/64;     // 40
  int base = lane*CH;
  int s = 0;
  for (int i=0;i<CH;i++){ int idx=base+i; if (idx<N_NODES) s += deg[idx]; }
  int inc = s;
  for (int d=1; d<64; d<<=1){
    int v = __shfl_up(inc, d, 64);
    if (lane >= d) inc += v;
  }
  int run = inc - s;                    // exclusive prefix
  for (int i=0;i<CH;i++){
    int idx = base+i;
    if (idx < N_NODES){ rowptr[idx] = run; run += deg[idx]; }
  }
  if (lane == 63) rowptr[N_NODES] = run;
}

__global__ void k_fill(const int* tgt, const int* rowptr, int* cursor, int* elist){
  int e = blockIdx.x*256 + threadIdx.x;
  if (e < N_EDGES){
    int n = tgt[e];
    int pos = atomicAdd(&cursor[n], 1);
    elist[rowptr[n] + pos] = e;
  }
}

// ---------------- edge features: 16 edges/block, coalesced both stages ----------------
__global__ __launch_bounds__(256) void k_efeat(const float* __restrict__ dist, const float* __restrict__ We1,
                                               const float* __restrict__ We2, float* __restrict__ efeat){
  __shared__ float gbuf[16][44];
  __shared__ __align__(16) float t1[16*132];
  __shared__ float dsh[16];
  __shared__ int j0s[16];
  __shared__ int cns[16];
  int t = threadIdx.x;
  int e0 = blockIdx.x*16;
  const float delta = 12.0f/599.0f;
  const float coeff = -0.5f/((2.0f*delta)*(2.0f*delta));
  if (t < 16){
    float d = dist[e0+t];
    int jc = (int)floorf(d/delta + 0.5f);
    int j0 = jc-GW; if (j0<0) j0=0;
    int j1 = jc+GW; if (j1>NB-1) j1=NB-1;
    dsh[t]=d; j0s[t]=j0; cns[t]=j1-j0+1;
  }
  __syncthreads();
  for (int q=t; q<16*41; q+=256){
    int el = q/41, w = q - el*41;
    float g = 0.f;
    if (w < cns[el]){
      float off = (float)(j0s[el]+w)*delta;
      float dd = dsh[el]-off;
      g = expf(coeff*dd*dd);
    }
    gbuf[el][w] = g;
  }
  __syncthreads();
  // stage 1: t1[el][c] = silu(sum_w gbuf[el][w]*We1[clamp(j0+w)][c])
  // thread = (el = t>>5 (+8 per half), c4 = (t&31)*4): 512B coalesced row loads
  {
    int elb = t>>5, c4 = (t&31)*4;
    #pragma unroll
    for (int half=0; half<2; ++half){
      int el = elb + 8*half;
      int j0 = j0s[el];
      float a0=0.f,a1=0.f,a2=0.f,a3=0.f;
      for (int w=0; w<41; ++w){
        float g = gbuf[el][w];
        int row = j0+w; if (row > NB-1) row = NB-1;
        float4 wv = *(const float4*)&We1[(size_t)row*C + c4];
        a0 += g*wv.x; a1 += g*wv.y; a2 += g*wv.z; a3 += g*wv.w;
      }
      float4 st; st.x=silu(a0); st.y=silu(a1); st.z=silu(a2); st.w=silu(a3);
      *(float4*)&t1[el*132 + c4] = st;
    }
  }
  __syncthreads();
  // stage 2: efeat[el] = silu(t1[el] @ We2); wave owns 4 edges, c2 = (t&63)*2
  {
    int grp = t>>6;               // wave id: edges grp*4 .. grp*4+3
    int c2 = (t&63)*2;
    float acc[4][2];
    #pragma unroll
    for (int i=0;i<4;i++){ acc[i][0]=0.f; acc[i][1]=0.f; }
    for (int cc=0; cc<C; cc+=4){
      float2 w0 = *(const float2*)&We2[(cc+0)*C + c2];
      float2 w1 = *(const float2*)&We2[(cc+1)*C + c2];
      float2 w2 = *(const float2*)&We2[(cc+2)*C + c2];
      float2 w3 = *(const float2*)&We2[(cc+3)*C + c2];
      #pragma unroll
      for (int i=0;i<4;i++){
        int el = grp*4 + i;
        float4 a4 = *(const float4*)&t1[el*132 + cc];
        acc[i][0] += a4.x*w0.x + a4.y*w1.x + a4.z*w2.x + a4.w*w3.x;
        acc[i][1] += a4.x*w0.y + a4.y*w1.y + a4.z*w2.y + a4.w*w3.y;
      }
    }
    #pragma unroll
    for (int i=0;i<4;i++){
      int el = grp*4 + i;
      float2 st; st.x = silu(acc[i][0]); st.y = silu(acc[i][1]);
      *(float2*)&efeat[(size_t)(e0+el)*C + c2] = st;
    }
  }
}

__global__ void k_efsum(const float* efeat, const int* rowptr, const int* elist, float* efsum){
  int n = blockIdx.x; int t = threadIdx.x; // 128 threads
  float acc = 0.f;
  int beg = rowptr[n], end = rowptr[n+1];
  for (int i=beg;i<end;i++)
    acc += efeat[elist[i]*C + t];
  efsum[n*C + t] = acc;
}

// ---------------- deg-init: 8 nodes/block; x = emb(m=0) + (efsum@Wdeg)/avg ----------------
__global__ __launch_bounds__(256) void k_deginit(const float* __restrict__ efsum, const float* __restrict__ Wdeg,
        const float* __restrict__ emb, const int* __restrict__ anum, float* __restrict__ x){
  __shared__ __align__(16) float efT[C][8];
  int t = threadIdx.x;
  int n0 = blockIdx.x*8;
  for (int q=t; q<8*C; q+=256){
    int nd=q>>7, cc=q&127;
    int n=n0+nd;
    efT[cc][nd] = (n<N_NODES)? efsum[n*C+cc] : 0.f;
  }
  __syncthreads();
  const float inv_avg = 1.0f/23.395238876342773f;
  #pragma unroll
  for (int grp=0; grp<5; ++grp){
    int o = grp*512 + t*2;
    if (o < MC*C){
      float a0[8], a1[8];
      #pragma unroll
      for (int i=0;i<8;i++){ a0[i]=0.f; a1[i]=0.f; }
      for (int cc=0; cc<C; ++cc){
        float2 w = *(const float2*)&Wdeg[(size_t)cc*(MC*C)+o];
        float4 e0 = *(const float4*)&efT[cc][0];
        float4 e1 = *(const float4*)&efT[cc][4];
        a0[0]+=e0.x*w.x; a1[0]+=e0.x*w.y;
        a0[1]+=e0.y*w.x; a1[1]+=e0.y*w.y;
        a0[2]+=e0.z*w.x; a1[2]+=e0.z*w.y;
        a0[3]+=e0.w*w.x; a1[3]+=e0.w*w.y;
        a0[4]+=e1.x*w.x; a1[4]+=e1.x*w.y;
        a0[5]+=e1.y*w.x; a1[5]+=e1.y*w.y;
        a0[6]+=e1.z*w.x; a1[6]+=e1.z*w.y;
        a0[7]+=e1.w*w.x; a1[7]+=e1.w*w.y;
      }
      #pragma unroll
      for (int nd=0; nd<8; ++nd){
        int n = n0+nd;
        if (n < N_NODES){
          float v0 = a0[nd]*inv_avg, v1 = a1[nd]*inv_avg;
          if (o < C){ int an=anum[n]; v0 += emb[an*C+o]; v1 += emb[an*C+o+1]; }
          float2 st; st.x=v0; st.y=v1;
          *(float2*)&x[(size_t)n*MC*C + o] = st;
        }
      }
    }
  }
}

// ---------------- fused: rmsnorm1 + QK + V, 4 nodes/block ----------------
__global__ __launch_bounds__(256) void k_nodeA(const float* __restrict__ x, const float* __restrict__ scale,
        const float* __restrict__ Wq, const float* __restrict__ Wk, const float* __restrict__ Wv,
        float* __restrict__ qb, float* __restrict__ kb, float* __restrict__ V){
  __shared__ __align__(16) float xs[4*MC*C];   // 38912 B
  int t = threadIdx.x;
  int n0 = blockIdx.x*4;
  // norm: 64-lane group ng handles node n0+ng
  {
    int ng = t>>6, lane = t&63;
    int n = n0+ng;
    float2 xv[MC];
    float pl[5]={0.f,0.f,0.f,0.f,0.f};
    #pragma unroll
    for (int m=0;m<MC;m++){
      float2 v = *(const float2*)&x[(size_t)n*MC*C + m*C + lane*2];
      xv[m]=v;
      pl[l_of_m(m)] += v.x*v.x + v.y*v.y;
    }
    #pragma unroll
    for (int l=0;l<5;l++){
      float r = pl[l];
      #pragma unroll
      for (int d=32; d>0; d>>=1) r += __shfl_xor(r, d, 64);
      pl[l]=r;
    }
    const float dens[5] = {128.f,384.f,640.f,896.f,1152.f};
    float inv[5];
    #pragma unroll
    for (int l=0;l<5;l++) inv[l] = 1.0f/sqrtf(pl[l]/dens[l] + 1e-8f);
    #pragma unroll
    for (int m=0;m<MC;m++){
      int l = l_of_m(m);
      float2 sc = *(const float2*)&scale[l*C + lane*2];
      float2 st; st.x = xv[m].x*inv[l]*sc.x; st.y = xv[m].y*inv[l]*sc.y;
      *(float2*)&xs[ng*MC*C + m*C + lane*2] = st;
    }
  }
  __syncthreads();
  // QK: thread owns o,o+1 for all 4 nodes
  {
    int o = t*2;
    float aq[4][2], ak[4][2];
    #pragma unroll
    for (int nd=0; nd<4; ++nd){ aq[nd][0]=aq[nd][1]=ak[nd][0]=ak[nd][1]=0.f; }
    for (int cc=0; cc<C; cc+=4){
      float2 q0 = *(const float2*)&Wq[(cc+0)*512 + o];
      float2 q1 = *(const float2*)&Wq[(cc+1)*512 + o];
      float2 q2 = *(const float2*)&Wq[(cc+2)*512 + o];
      float2 q3 = *(const float2*)&Wq[(cc+3)*512 + o];
      float2 k0 = *(const float2*)&Wk[(cc+0)*512 + o];
      float2 k1 = *(const float2*)&Wk[(cc+1)*512 + o];
      float2 k2 = *(const float2*)&Wk[(cc+2)*512 + o];
      float2 k3 = *(const float2*)&Wk[(cc+3)*512 + o];
      #pragma unroll
      for (int nd=0; nd<4; ++nd){
        float4 s4 = *(const float4*)&xs[nd*MC*C + cc];
        aq[nd][0] += s4.x*q0.x + s4.y*q1.x + s4.z*q2.x + s4.w*q3.x;
        aq[nd][1] += s4.x*q0.y + s4.y*q1.y + s4.z*q2.y + s4.w*q3.y;
        ak[nd][0] += s4.x*k0.x + s4.y*k1.x + s4.z*k2.x + s4.w*k3.x;
        ak[nd][1] += s4.x*k0.y + s4.y*k1.y + s4.z*k2.y + s4.w*k3.y;
      }
    }
    #pragma unroll
    for (int nd=0; nd<4; ++nd){
      float2 sq; sq.x=aq[nd][0]; sq.y=aq[nd][1];
      float2 sk; sk.x=ak[nd][0]; sk.y=ak[nd][1];
      *(float2*)&qb[(size_t)(n0+nd)*512 + o] = sq;
      *(float2*)&kb[(size_t)(n0+nd)*512 + o] = sk;
    }
  }
  // V = xs @ Wv : thread owns (m-stripe g4, cols c0,c0+1) for all 4 nodes
  {
    int c0 = (t&63)*2, g4 = t>>6;
    float acc[4][5][2];
    #pragma unroll
    for (int nd=0; nd<4; ++nd)
      #pragma unroll
      for (int i=0;i<5;i++){ acc[nd][i][0]=0.f; acc[nd][i][1]=0.f; }
    for (int cc=0; cc<C; cc+=4){
      float2 w0 = *(const float2*)&Wv[(cc+0)*C + c0];
      float2 w1 = *(const float2*)&Wv[(cc+1)*C + c0];
      float2 w2 = *(const float2*)&Wv[(cc+2)*C + c0];
      float2 w3 = *(const float2*)&Wv[(cc+3)*C + c0];
      #pragma unroll
      for (int nd=0; nd<4; ++nd){
        #pragma unroll
        for (int i=0;i<5;i++){
          int m = g4 + 4*i;
          if (m < MC){
            float4 a4 = *(const float4*)&xs[nd*MC*C + m*C + cc];
            acc[nd][i][0] += a4.x*w0.x + a4.y*w1.x + a4.z*w2.x + a4.w*w3.x;
            acc[nd][i][1] += a4.x*w0.y + a4.y*w1.y + a4.z*w2.y + a4.w*w3.y;
          }
        }
      }
    }
    #pragma unroll
    for (int nd=0; nd<4; ++nd){
      #pragma unroll
      for (int i=0;i<5;i++){
        int m = g4 + 4*i;
        if (m < MC){
          float2 st; st.x=acc[nd][i][0]; st.y=acc[nd][i][1];
          *(float2*)&V[(size_t)(n0+nd)*MC*C + m*C + c0] = st;
        }
      }
    }
  }
}

__global__ __launch_bounds__(256) void k_logits(const float* qb, const float* kb, const float* alpha,
                                                const int* srcarr, const int* tgtarr, float* logits){
  int wid = threadIdx.x >> 6; int lane = threadIdx.x & 63;
  int e = blockIdx.x*4 + wid;
  if (e >= N_EDGES) return;
  int s = srcarr[e], tg = tgtarr[e];
  #pragma unroll
  for (int h=0; h<8; ++h){
    float qv = qb[tg*512 + h*64 + lane] + kb[s*512 + h*64 + lane];
    float v = silu(qv) * alpha[h*64 + lane];
    for (int d=32; d>0; d>>=1) v += __shfl_down(v, d, 64);
    if (lane == 0) logits[e*8 + h] = v * 0.125f;
  }
}

// one wave per node; lane = (edge-chunk<<3) | h
__global__ __launch_bounds__(256) void k_softmax(const float* logits, const int* rowptr, const int* elist, float* attnb){
  int n = blockIdx.x*4 + (threadIdx.x>>6);
  if (n >= N_NODES) return;
  int lane = threadIdx.x & 63;
  int h = lane & 7, ec = lane >> 3;
  int beg = rowptr[n], end = rowptr[n+1];
  float mx = -1e30f;
  for (int i=beg+ec; i<end; i+=8) mx = fmaxf(mx, logits[elist[i]*8+h]);
  #pragma unroll
  for (int dd=8; dd<64; dd<<=1) mx = fmaxf(mx, __shfl_xor(mx, dd, 64));
  float sum = 0.f;
  for (int i=beg+ec; i<end; i+=8) sum += expf(logits[elist[i]*8+h] - mx);
  #pragma unroll
  for (int dd=8; dd<64; dd<<=1) sum += __shfl_xor(sum, dd, 64);
  float inv = 1.0f/(sum + 1e-9f);
  for (int i=beg+ec; i<end; i+=8){
    int e = elist[i];
    attnb[e*8 + h] = expf(logits[e*8+h]-mx)*inv;
  }
}

// rad: 16 edges/block
__global__ __launch_bounds__(256) void k_rad(const float* efeat, const float* Wrad, float* radb){
  __shared__ float wsh[C*RSTR];
  __shared__ float esh[16][132];
  int t = threadIdx.x;
  for (int q=t; q<C*MC; q+=256){ int cc=q/MC, m=q-cc*MC; wsh[cc*RSTR+m] = Wrad[q]; }
  int e0 = blockIdx.x*16;
  for (int q=t; q<16*C; q+=256) esh[q>>7][q&127] = efeat[(size_t)(e0+(q>>7))*C + (q&127)];
  __syncthreads();
  for (int q=t; q<16*MC; q+=256){
    int el = q/MC, m = q-el*MC;
    float acc = 0.f;
    #pragma unroll 4
    for (int cc=0; cc<C; ++cc) acc += esh[el][cc]*wsh[cc*RSTR+m];
    radb[(size_t)(e0+el)*RSTR + m] = silu(acc);
  }
}

// msum[n,m,d] = sum_e attn[e,h(d)]*rad[e,m]*V[src_e,m,d]; then x[n] += msum @ Wo
__global__ __launch_bounds__(256) void k_e1(const float* __restrict__ V, const float* __restrict__ radb,
        const float* __restrict__ attnb, const float* __restrict__ Wo,
        const int* __restrict__ rowptr, const int* __restrict__ elist, const int* __restrict__ srcarr,
        float* __restrict__ x){
  __shared__ __align__(16) float msh[MC*C];
  int n = blockIdx.x;
  int t = threadIdx.x;
  int c0 = (t&63)*2; int g4 = t>>6;
  int h = c0 >> 4;
  float acc[5][2];
  #pragma unroll
  for (int i=0;i<5;i++){ acc[i][0]=0.f; acc[i][1]=0.f; }
  int beg = rowptr[n], end = rowptr[n+1];
  for (int idx=beg; idx<end; ++idx){
    int e = elist[idx];
    int s = srcarr[e];
    float a = attnb[e*8 + h];
    const float* vr = V + (size_t)s*(MC*C) + c0;
    const float* rr = radb + (size_t)e*RSTR;
    #pragma unroll
    for (int i=0;i<5;i++){
      int m = g4 + 4*i;
      if (m < MC){
        float ar = a * rr[m];
        float2 v2 = *(const float2*)&vr[m*C];
        acc[i][0] += ar*v2.x;
        acc[i][1] += ar*v2.y;
      }
    }
  }
  #pragma unroll
  for (int i=0;i<5;i++){
    int m = g4 + 4*i;
    if (m < MC){ msh[m*C+c0] = acc[i][0]; msh[m*C+c0+1] = acc[i][1]; }
  }
  __syncthreads();
  // x[n] += msh @ Wo
  float acc2[5][2];
  #pragma unroll
  for (int i=0;i<5;i++){ acc2[i][0]=0.f; acc2[i][1]=0.f; }
  for (int d=0; d<C; d+=4){
    float2 w0 = *(const float2*)&Wo[(d+0)*C + c0];
    float2 w1 = *(const float2*)&Wo[(d+1)*C + c0];
    float2 w2 = *(const float2*)&Wo[(d+2)*C + c0];
    float2 w3 = *(const float2*)&Wo[(d+3)*C + c0];
    #pragma unroll
    for (int i=0;i<5;i++){
      int m = g4 + 4*i;
      if (m < MC){
        float4 m4 = *(const float4*)&msh[m*C + d];
        acc2[i][0] += m4.x*w0.x + m4.y*w1.x + m4.z*w2.x + m4.w*w3.x;
        acc2[i][1] += m4.x*w0.y + m4.y*w1.y + m4.z*w2.y + m4.w*w3.y;
      }
    }
  }
  #pragma unroll
  for (int i=0;i<5;i++){
    int m = g4 + 4*i;
    if (m < MC){
      size_t off = (size_t)n*MC*C + m*C + c0;
      x[off]   += acc2[i][0];
      x[off+1] += acc2[i][1];
    }
  }
}

// ---------------- fused: rmsnorm2 + gated FFN, 2 nodes/block ----------------
__global__ __launch_bounds__(256) void k_nodeB(float* __restrict__ x, const float* __restrict__ scale,
        const float* __restrict__ W1, const float* __restrict__ W2){
  __shared__ __align__(16) float xs[2*MC*C];
  __shared__ __align__(16) float hb[2*MC*C];
  __shared__ float gate[2*C];
  __shared__ float ssum[2][5];
  int t = threadIdx.x;
  int n0 = blockIdx.x*2;
  int ng = t>>7, c = t&127;
  int n = n0+ng;
  if (t < 10) ssum[t/5][t%5] = 0.f;
  __syncthreads();
  {
    float vals[MC];
    float pl[5]={0.f,0.f,0.f,0.f,0.f};
    #pragma unroll
    for (int m=0;m<MC;m++){
      float v = x[(size_t)n*MC*C + m*C + c];
      vals[m]=v;
      pl[l_of_m(m)] += v*v;
    }
    #pragma unroll
    for (int l=0;l<5;l++){
      float r = pl[l];
      #pragma unroll
      for (int d=32; d>0; d>>=1) r += __shfl_down(r, d, 64);
      if ((t&63)==0) atomicAdd(&ssum[ng][l], r);
    }
    __syncthreads();
    const float dens[5] = {128.f,384.f,640.f,896.f,1152.f};
    float inv[5];
    #pragma unroll
    for (int l=0;l<5;l++) inv[l] = 1.0f/sqrtf(ssum[ng][l]/dens[l] + 1e-8f);
    #pragma unroll
    for (int m=0;m<MC;m++){
      int l = l_of_m(m);
      xs[ng*MC*C + m*C + c] = vals[m]*inv[l]*scale[l*C + c];
    }
  }
  __syncthreads();
  int c0 = (t&63)*2, g4 = t>>6;
  // hb = xs @ W1
  {
    float acc[2][5][2];
    #pragma unroll
    for (int nd=0; nd<2; ++nd)
      #pragma unroll
      for (int i=0;i<5;i++){ acc[nd][i][0]=0.f; acc[nd][i][1]=0.f; }
    for (int cc=0; cc<C; cc+=4){
      float2 w0 = *(const float2*)&W1[(cc+0)*C + c0];
      float2 w1 = *(const float2*)&W1[(cc+1)*C + c0];
      float2 w2 = *(const float2*)&W1[(cc+2)*C + c0];
      float2 w3 = *(const float2*)&W1[(cc+3)*C + c0];
      #pragma unroll
      for (int nd=0; nd<2; ++nd){
        #pragma unroll
        for (int i=0;i<5;i++){
          int m = g4 + 4*i;
          if (m < MC){
            float4 a4 = *(const float4*)&xs[nd*MC*C + m*C + cc];
            acc[nd][i][0] += a4.x*w0.x + a4.y*w1.x + a4.z*w2.x + a4.w*w3.x;
            acc[nd][i][1] += a4.x*w0.y + a4.y*w1.y + a4.z*w2.y + a4.w*w3.y;
          }
        }
      }
    }
    #pragma unroll
    for (int nd=0; nd<2; ++nd)
      #pragma unroll
      for (int i=0;i<5;i++){
        int m = g4 + 4*i;
        if (m < MC){ hb[nd*MC*C + m*C + c0] = acc[nd][i][0]; hb[nd*MC*C + m*C + c0+1] = acc[nd][i][1]; }
      }
  }
  __syncthreads();
  {
    int nd = t>>7, cg = t&127;
    gate[nd*C+cg] = silu(hb[nd*MC*C + cg]);
  }
  __syncthreads();
  #pragma unroll
  for (int nd=0; nd<2; ++nd)
    for (int q=t; q<MC*C; q+=256)
      hb[nd*MC*C + q] *= gate[nd*C + (q&127)];
  __syncthreads();
  // x += hb @ W2
  {
    float acc[2][5][2];
    #pragma unroll
    for (int nd=0; nd<2; ++nd)
      #pragma unroll
      for (int i=0;i<5;i++){ acc[nd][i][0]=0.f; acc[nd][i][1]=0.f; }
    for (int f=0; f<C; f+=4){
      float2 w0 = *(const float2*)&W2[(f+0)*C + c0];
      float2 w1 = *(const float2*)&W2[(f+1)*C + c0];
      float2 w2 = *(const float2*)&W2[(f+2)*C + c0];
      float2 w3 = *(const float2*)&W2[(f+3)*C + c0];
      #pragma unroll
      for (int nd=0; nd<2; ++nd){
        #pragma unroll
        for (int i=0;i<5;i++){
          int m = g4 + 4*i;
          if (m < MC){
            float4 a4 = *(const float4*)&hb[nd*MC*C + m*C + f];
            acc[nd][i][0] += a4.x*w0.x + a4.y*w1.x + a4.z*w2.x + a4.w*w3.x;
            acc[nd][i][1] += a4.x*w0.y + a4.y*w1.y + a4.z*w2.y + a4.w*w3.y;
          }
        }
      }
    }
    #pragma unroll
    for (int nd=0; nd<2; ++nd)
      #pragma unroll
      for (int i=0;i<5;i++){
        int m = g4 + 4*i;
        if (m < MC){
          size_t off = (size_t)(n0+nd)*MC*C + m*C + c0;
          float2 old = *(float2*)&x[off];
          old.x += acc[nd][i][0];
          old.y += acc[nd][i][1];
          *(float2*)&x[off] = old;
        }
      }
  }
}

// ---------------- final head (only l=0 row matters) ----------------
__global__ __launch_bounds__(128) void k_final(const float* x, const float* nsf, const float* Wef1,
        const float* Wef2, const int* batch, float* out){
  __shared__ float sl[C];
  __shared__ float red[2];
  __shared__ float red2[2];
  int n = blockIdx.x; int t = threadIdx.x;
  float v = x[(size_t)n*MC*C + t];
  float sq = v*v;
  for (int d=32; d>0; d>>=1) sq += __shfl_down(sq, d, 64);
  if ((t&63)==0) red[t>>6] = sq;
  __syncthreads();
  float ms = (red[0]+red[1]) * (1.0f/128.f);
  float inv = 1.0f/sqrtf(ms + 1e-8f);
  sl[t] = v*inv*nsf[t];
  __syncthreads();
  float acc = 0.f;
  for (int cc=0; cc<C; ++cc) acc += sl[cc]*Wef1[cc*C + t];
  float val = acc*silu(acc)*Wef2[t];
  for (int d=32; d>0; d>>=1) val += __shfl_down(val, d, 64);
  if ((t&63)==0) red2[t>>6] = val;
  __syncthreads();
  if (t==0){
    float ne = red2[0]+red2[1];
    atomicAdd(&out[batch[n]], ne * (1.0f/77.81317f));
  }
}

extern "C" void kernel_launch(void* const* d_in, const int* in_sizes, int n_in,
                              void* d_out, int out_size, void* d_ws, size_t ws_size,
                              hipStream_t stream){
  (void)in_sizes; (void)n_in; (void)ws_size;
  const int*   anum  = (const int*)d_in[0];
  const int*   eidx  = (const int*)d_in[1];
  const float* dist  = (const float*)d_in[2];
  const int*   batch = (const int*)d_in[3];
  const float* emb   = (const float*)d_in[4];
  const float* We1   = (const float*)d_in[5];
  const float* We2   = (const float*)d_in[6];
  const float* Wdeg  = (const float*)d_in[7];
  const float* ns1   = (const float*)d_in[8];
  const float* ns2   = (const float*)d_in[9];
  const float* Wq    = (const float*)d_in[10];
  const float* Wk    = (const float*)d_in[11];
  const float* alpha = (const float*)d_in[12];
  const float* Wv    = (const float*)d_in[13];
  const float* Wrad  = (const float*)d_in[14];
  const float* Wo    = (const float*)d_in[15];
  const float* W1    = (const float*)d_in[16];
  const float* W2    = (const float*)d_in[17];
  const float* nsf   = (const float*)d_in[18];
  const float* Wef1  = (const float*)d_in[19];
  const float* Wef2  = (const float*)d_in[20];
  float* out = (float*)d_out;

  const int* srcarr = eidx;
  const int* tgtarr = eidx + N_EDGES;

  char* wsb = (char*)d_ws;
  float* efeat = (float*)wsb;  wsb += (size_t)N_EDGES*C*4;
  float* efsum = (float*)wsb;  wsb += (size_t)N_NODES*C*4;
  float* x     = (float*)wsb;  wsb += (size_t)N_NODES*MC*C*4;
  float* Vb    = (float*)wsb;  wsb += (size_t)N_NODES*MC*C*4;
  float* qb    = (float*)wsb;  wsb += (size_t)N_NODES*512*4;
  float* kb    = (float*)wsb;  wsb += (size_t)N_NODES*512*4;
  float* logit = (float*)wsb;  wsb += (size_t)N_EDGES*8*4;
  float* attnb = (float*)wsb;  wsb += (size_t)N_EDGES*8*4;
  float* radb  = (float*)wsb;  wsb += (size_t)N_EDGES*RSTR*4;
  int* deg     = (int*)wsb;    wsb += (size_t)N_NODES*4;
  int* rowptr  = (int*)wsb;    wsb += (size_t)(N_NODES+1)*4;
  int* cursor  = (int*)wsb;    wsb += (size_t)N_NODES*4;
  int* elist   = (int*)wsb;    wsb += (size_t)N_EDGES*4;

  (void)hipMemsetAsync(deg, 0, N_NODES*4, stream);
  (void)hipMemsetAsync(cursor, 0, N_NODES*4, stream);
  (void)hipMemsetAsync(d_out, 0, (size_t)out_size*sizeof(float), stream);

  k_count<<<(N_EDGES+255)/256, 256, 0, stream>>>(tgtarr, deg);
  k_scan<<<1, 64, 0, stream>>>(deg, rowptr);
  k_fill<<<(N_EDGES+255)/256, 256, 0, stream>>>(tgtarr, rowptr, cursor, elist);
  k_efeat<<<N_EDGES/16, 256, 0, stream>>>(dist, We1, We2, efeat);
  k_efsum<<<N_NODES, 128, 0, stream>>>(efeat, rowptr, elist, efsum);
  k_deginit<<<(N_NODES+7)/8, 256, 0, stream>>>(efsum, Wdeg, emb, anum, x);

  for (int i=0;i<NL;i++){
    k_nodeA<<<N_NODES/4, 256, 0, stream>>>(x, ns1 + i*5*C, Wq + i*C*512, Wk + i*C*512,
                                           Wv + i*C*C, qb, kb, Vb);
    k_logits<<<(N_EDGES+3)/4, 256, 0, stream>>>(qb, kb, alpha + i*512, srcarr, tgtarr, logit);
    k_softmax<<<(N_NODES+3)/4, 256, 0, stream>>>(logit, rowptr, elist, attnb);
    k_rad<<<N_EDGES/16, 256, 0, stream>>>(efeat, Wrad + i*C*MC, radb);
    k_e1<<<N_NODES, 256, 0, stream>>>(Vb, radb, attnb, Wo + i*C*C,
                                      rowptr, elist, srcarr, x);
    k_nodeB<<<N_NODES/2, 256, 0, stream>>>(x, ns2 + i*5*C, W1 + i*C*C, W2 + i*C*C);
  }
  k_final<<<N_NODES, 128, 0, stream>>>(x, nsf, Wef1, Wef2, batch, out);
}

// Round 8
// 1634.509 us; speedup vs baseline: 2.8550x; 1.0710x over previous
//
#include <hip/hip_runtime.h>
#include <hip/hip_bf16.h>

#define N_NODES 2500
#define N_EDGES 50000
#define C 128
#define MC 19
#define RSTR 20
#define NL 4
#define NB 600
#define GW 20

__device__ __forceinline__ float silu(float v){ return v / (1.f + expf(-v)); }
__device__ __forceinline__ int l_of_m(int m){
  return (m==0)?0 : (m<4)?1 : (m<9)?2 : (m<14)?3 : 4;
}
__device__ __forceinline__ unsigned pack2(float a, float b){
  __hip_bfloat162 h2;
  h2.x = __float2bfloat16(a);
  h2.y = __float2bfloat16(b);
  return *(unsigned*)&h2;
}
__device__ __forceinline__ float2 bf2f2(unsigned u){
  float2 r;
  r.x = __uint_as_float(u << 16);
  r.y = __uint_as_float(u & 0xffff0000u);
  return r;
}

// ---------------- CSR build ----------------
__global__ void k_count(const int* tgt, int* deg){
  int e = blockIdx.x*256 + threadIdx.x;
  if (e < N_EDGES) atomicAdd(&deg[tgt[e]], 1);
}

__global__ void k_scan(const int* deg, int* rowptr){
  int lane = threadIdx.x;               // 64 threads
  const int CH = (N_NODES + 63)/64;     // 40
  int base = lane*CH;
  int s = 0;
  for (int i=0;i<CH;i++){ int idx=base+i; if (idx<N_NODES) s += deg[idx]; }
  int inc = s;
  for (int d=1; d<64; d<<=1){
    int v = __shfl_up(inc, d, 64);
    if (lane >= d) inc += v;
  }
  int run = inc - s;                    // exclusive prefix
  for (int i=0;i<CH;i++){
    int idx = base+i;
    if (idx < N_NODES){ rowptr[idx] = run; run += deg[idx]; }
  }
  if (lane == 63) rowptr[N_NODES] = run;
}

__global__ void k_fill(const int* tgt, const int* rowptr, int* cursor, int* elist){
  int e = blockIdx.x*256 + threadIdx.x;
  if (e < N_EDGES){
    int n = tgt[e];
    int pos = atomicAdd(&cursor[n], 1);
    elist[rowptr[n] + pos] = e;
  }
}

// ---------------- edge features: 16 edges/block, coalesced both stages ----------------
__global__ __launch_bounds__(256) void k_efeat(const float* __restrict__ dist, const float* __restrict__ We1,
                                               const float* __restrict__ We2, float* __restrict__ efeat){
  __shared__ float gbuf[16][44];
  __shared__ __align__(16) float t1[16*132];
  __shared__ float dsh[16];
  __shared__ int j0s[16];
  __shared__ int cns[16];
  int t = threadIdx.x;
  int e0 = blockIdx.x*16;
  const float delta = 12.0f/599.0f;
  const float coeff = -0.5f/((2.0f*delta)*(2.0f*delta));
  if (t < 16){
    float d = dist[e0+t];
    int jc = (int)floorf(d/delta + 0.5f);
    int j0 = jc-GW; if (j0<0) j0=0;
    int j1 = jc+GW; if (j1>NB-1) j1=NB-1;
    dsh[t]=d; j0s[t]=j0; cns[t]=j1-j0+1;
  }
  __syncthreads();
  for (int q=t; q<16*41; q+=256){
    int el = q/41, w = q - el*41;
    float g = 0.f;
    if (w < cns[el]){
      float off = (float)(j0s[el]+w)*delta;
      float dd = dsh[el]-off;
      g = expf(coeff*dd*dd);
    }
    gbuf[el][w] = g;
  }
  __syncthreads();
  {
    int elb = t>>5, c4 = (t&31)*4;
    #pragma unroll
    for (int half=0; half<2; ++half){
      int el = elb + 8*half;
      int j0 = j0s[el];
      float a0=0.f,a1=0.f,a2=0.f,a3=0.f;
      for (int w=0; w<41; ++w){
        float g = gbuf[el][w];
        int row = j0+w; if (row > NB-1) row = NB-1;
        float4 wv = *(const float4*)&We1[(size_t)row*C + c4];
        a0 += g*wv.x; a1 += g*wv.y; a2 += g*wv.z; a3 += g*wv.w;
      }
      float4 st; st.x=silu(a0); st.y=silu(a1); st.z=silu(a2); st.w=silu(a3);
      *(float4*)&t1[el*132 + c4] = st;
    }
  }
  __syncthreads();
  {
    int grp = t>>6;
    int c2 = (t&63)*2;
    float acc[4][2];
    #pragma unroll
    for (int i=0;i<4;i++){ acc[i][0]=0.f; acc[i][1]=0.f; }
    for (int cc=0; cc<C; cc+=4){
      float2 w0 = *(const float2*)&We2[(cc+0)*C + c2];
      float2 w1 = *(const float2*)&We2[(cc+1)*C + c2];
      float2 w2 = *(const float2*)&We2[(cc+2)*C + c2];
      float2 w3 = *(const float2*)&We2[(cc+3)*C + c2];
      #pragma unroll
      for (int i=0;i<4;i++){
        int el = grp*4 + i;
        float4 a4 = *(const float4*)&t1[el*132 + cc];
        acc[i][0] += a4.x*w0.x + a4.y*w1.x + a4.z*w2.x + a4.w*w3.x;
        acc[i][1] += a4.x*w0.y + a4.y*w1.y + a4.z*w2.y + a4.w*w3.y;
      }
    }
    #pragma unroll
    for (int i=0;i<4;i++){
      int el = grp*4 + i;
      float2 st; st.x = silu(acc[i][0]); st.y = silu(acc[i][1]);
      *(float2*)&efeat[(size_t)(e0+el)*C + c2] = st;
    }
  }
}

__global__ void k_efsum(const float* efeat, const int* rowptr, const int* elist, float* efsum){
  int n = blockIdx.x; int t = threadIdx.x; // 128 threads
  float acc = 0.f;
  int beg = rowptr[n], end = rowptr[n+1];
  for (int i=beg;i<end;i++)
    acc += efeat[elist[i]*C + t];
  efsum[n*C + t] = acc;
}

// ---------------- deg-init: 8 nodes/block ----------------
__global__ __launch_bounds__(256) void k_deginit(const float* __restrict__ efsum, const float* __restrict__ Wdeg,
        const float* __restrict__ emb, const int* __restrict__ anum, float* __restrict__ x){
  __shared__ __align__(16) float efT[C][8];
  int t = threadIdx.x;
  int n0 = blockIdx.x*8;
  for (int q=t; q<8*C; q+=256){
    int nd=q>>7, cc=q&127;
    int n=n0+nd;
    efT[cc][nd] = (n<N_NODES)? efsum[n*C+cc] : 0.f;
  }
  __syncthreads();
  const float inv_avg = 1.0f/23.395238876342773f;
  #pragma unroll
  for (int grp=0; grp<5; ++grp){
    int o = grp*512 + t*2;
    if (o < MC*C){
      float a0[8], a1[8];
      #pragma unroll
      for (int i=0;i<8;i++){ a0[i]=0.f; a1[i]=0.f; }
      for (int cc=0; cc<C; ++cc){
        float2 w = *(const float2*)&Wdeg[(size_t)cc*(MC*C)+o];
        float4 e0 = *(const float4*)&efT[cc][0];
        float4 e1 = *(const float4*)&efT[cc][4];
        a0[0]+=e0.x*w.x; a1[0]+=e0.x*w.y;
        a0[1]+=e0.y*w.x; a1[1]+=e0.y*w.y;
        a0[2]+=e0.z*w.x; a1[2]+=e0.z*w.y;
        a0[3]+=e0.w*w.x; a1[3]+=e0.w*w.y;
        a0[4]+=e1.x*w.x; a1[4]+=e1.x*w.y;
        a0[5]+=e1.y*w.x; a1[5]+=e1.y*w.y;
        a0[6]+=e1.z*w.x; a1[6]+=e1.z*w.y;
        a0[7]+=e1.w*w.x; a1[7]+=e1.w*w.y;
      }
      #pragma unroll
      for (int nd=0; nd<8; ++nd){
        int n = n0+nd;
        if (n < N_NODES){
          float v0 = a0[nd]*inv_avg, v1 = a1[nd]*inv_avg;
          if (o < C){ int an=anum[n]; v0 += emb[an*C+o]; v1 += emb[an*C+o+1]; }
          float2 st; st.x=v0; st.y=v1;
          *(float2*)&x[(size_t)n*MC*C + o] = st;
        }
      }
    }
  }
}

// ---------------- fused: rmsnorm1 + QK + V, 4 nodes/block; qb/kb/V stored bf16 ----------------
__global__ __launch_bounds__(256) void k_nodeA(const float* __restrict__ x, const float* __restrict__ scale,
        const float* __restrict__ Wq, const float* __restrict__ Wk, const float* __restrict__ Wv,
        unsigned short* __restrict__ qb, unsigned short* __restrict__ kb, unsigned short* __restrict__ V){
  __shared__ __align__(16) float xs[4*MC*C];   // 38912 B
  int t = threadIdx.x;
  int n0 = blockIdx.x*4;
  {
    int ng = t>>6, lane = t&63;
    int n = n0+ng;
    float2 xv[MC];
    float pl[5]={0.f,0.f,0.f,0.f,0.f};
    #pragma unroll
    for (int m=0;m<MC;m++){
      float2 v = *(const float2*)&x[(size_t)n*MC*C + m*C + lane*2];
      xv[m]=v;
      pl[l_of_m(m)] += v.x*v.x + v.y*v.y;
    }
    #pragma unroll
    for (int l=0;l<5;l++){
      float r = pl[l];
      #pragma unroll
      for (int d=32; d>0; d>>=1) r += __shfl_xor(r, d, 64);
      pl[l]=r;
    }
    const float dens[5] = {128.f,384.f,640.f,896.f,1152.f};
    float inv[5];
    #pragma unroll
    for (int l=0;l<5;l++) inv[l] = 1.0f/sqrtf(pl[l]/dens[l] + 1e-8f);
    #pragma unroll
    for (int m=0;m<MC;m++){
      int l = l_of_m(m);
      float2 sc = *(const float2*)&scale[l*C + lane*2];
      float2 st; st.x = xv[m].x*inv[l]*sc.x; st.y = xv[m].y*inv[l]*sc.y;
      *(float2*)&xs[ng*MC*C + m*C + lane*2] = st;
    }
  }
  __syncthreads();
  // QK: thread owns o,o+1 for all 4 nodes
  {
    int o = t*2;
    float aq[4][2], ak[4][2];
    #pragma unroll
    for (int nd=0; nd<4; ++nd){ aq[nd][0]=aq[nd][1]=ak[nd][0]=ak[nd][1]=0.f; }
    for (int cc=0; cc<C; cc+=4){
      float2 q0 = *(const float2*)&Wq[(cc+0)*512 + o];
      float2 q1 = *(const float2*)&Wq[(cc+1)*512 + o];
      float2 q2 = *(const float2*)&Wq[(cc+2)*512 + o];
      float2 q3 = *(const float2*)&Wq[(cc+3)*512 + o];
      float2 k0 = *(const float2*)&Wk[(cc+0)*512 + o];
      float2 k1 = *(const float2*)&Wk[(cc+1)*512 + o];
      float2 k2 = *(const float2*)&Wk[(cc+2)*512 + o];
      float2 k3 = *(const float2*)&Wk[(cc+3)*512 + o];
      #pragma unroll
      for (int nd=0; nd<4; ++nd){
        float4 s4 = *(const float4*)&xs[nd*MC*C + cc];
        aq[nd][0] += s4.x*q0.x + s4.y*q1.x + s4.z*q2.x + s4.w*q3.x;
        aq[nd][1] += s4.x*q0.y + s4.y*q1.y + s4.z*q2.y + s4.w*q3.y;
        ak[nd][0] += s4.x*k0.x + s4.y*k1.x + s4.z*k2.x + s4.w*k3.x;
        ak[nd][1] += s4.x*k0.y + s4.y*k1.y + s4.z*k2.y + s4.w*k3.y;
      }
    }
    #pragma unroll
    for (int nd=0; nd<4; ++nd){
      *(unsigned*)&qb[(size_t)(n0+nd)*512 + o] = pack2(aq[nd][0], aq[nd][1]);
      *(unsigned*)&kb[(size_t)(n0+nd)*512 + o] = pack2(ak[nd][0], ak[nd][1]);
    }
  }
  // V = xs @ Wv
  {
    int c0 = (t&63)*2, g4 = t>>6;
    float acc[4][5][2];
    #pragma unroll
    for (int nd=0; nd<4; ++nd)
      #pragma unroll
      for (int i=0;i<5;i++){ acc[nd][i][0]=0.f; acc[nd][i][1]=0.f; }
    for (int cc=0; cc<C; cc+=4){
      float2 w0 = *(const float2*)&Wv[(cc+0)*C + c0];
      float2 w1 = *(const float2*)&Wv[(cc+1)*C + c0];
      float2 w2 = *(const float2*)&Wv[(cc+2)*C + c0];
      float2 w3 = *(const float2*)&Wv[(cc+3)*C + c0];
      #pragma unroll
      for (int nd=0; nd<4; ++nd){
        #pragma unroll
        for (int i=0;i<5;i++){
          int m = g4 + 4*i;
          if (m < MC){
            float4 a4 = *(const float4*)&xs[nd*MC*C + m*C + cc];
            acc[nd][i][0] += a4.x*w0.x + a4.y*w1.x + a4.z*w2.x + a4.w*w3.x;
            acc[nd][i][1] += a4.x*w0.y + a4.y*w1.y + a4.z*w2.y + a4.w*w3.y;
          }
        }
      }
    }
    #pragma unroll
    for (int nd=0; nd<4; ++nd){
      #pragma unroll
      for (int i=0;i<5;i++){
        int m = g4 + 4*i;
        if (m < MC)
          *(unsigned*)&V[(size_t)(n0+nd)*MC*C + m*C + c0] = pack2(acc[nd][i][0], acc[nd][i][1]);
      }
    }
  }
}

// ---------------- logits: wave per edge; lane owns 8 bf16 (one dwordx4 per operand) ----------------
__global__ __launch_bounds__(256) void k_logits(const unsigned short* __restrict__ qb,
        const unsigned short* __restrict__ kb, const float* __restrict__ alpha,
        const int* __restrict__ srcarr, const int* __restrict__ tgtarr, float* __restrict__ logits){
  int wid = threadIdx.x >> 6; int lane = threadIdx.x & 63;
  int e = blockIdx.x*4 + wid;
  if (e >= N_EDGES) return;
  float al[8];
  {
    float4 a0 = *(const float4*)&alpha[lane*8];
    float4 a1 = *(const float4*)&alpha[lane*8+4];
    al[0]=a0.x; al[1]=a0.y; al[2]=a0.z; al[3]=a0.w;
    al[4]=a1.x; al[5]=a1.y; al[6]=a1.z; al[7]=a1.w;
  }
  int s = srcarr[e], tg = tgtarr[e];
  int4 qv = *(const int4*)&qb[(size_t)tg*512 + lane*8];
  int4 kv = *(const int4*)&kb[(size_t)s*512 + lane*8];
  unsigned qu[4] = {(unsigned)qv.x,(unsigned)qv.y,(unsigned)qv.z,(unsigned)qv.w};
  unsigned ku[4] = {(unsigned)kv.x,(unsigned)kv.y,(unsigned)kv.z,(unsigned)kv.w};
  float acc = 0.f;
  #pragma unroll
  for (int j=0;j<4;j++){
    float2 q2 = bf2f2(qu[j]);
    float2 k2 = bf2f2(ku[j]);
    acc += silu(q2.x+k2.x)*al[2*j]   + silu(q2.y+k2.y)*al[2*j+1];
  }
  // second half of the 8 elements is interleaved in the same 4 uints? No: 4 uints = 8 bf16 total. done.
  #pragma unroll
  for (int d=1; d<8; d<<=1) acc += __shfl_down(acc, d, 64);
  if ((lane&7)==0) logits[e*8 + (lane>>3)] = acc * 0.125f;
}

// one wave per node; lane = (edge-chunk<<3) | h
__global__ __launch_bounds__(256) void k_softmax(const float* logits, const int* rowptr, const int* elist, float* attnb){
  int n = blockIdx.x*4 + (threadIdx.x>>6);
  if (n >= N_NODES) return;
  int lane = threadIdx.x & 63;
  int h = lane & 7, ec = lane >> 3;
  int beg = rowptr[n], end = rowptr[n+1];
  float mx = -1e30f;
  for (int i=beg+ec; i<end; i+=8) mx = fmaxf(mx, logits[elist[i]*8+h]);
  #pragma unroll
  for (int dd=8; dd<64; dd<<=1) mx = fmaxf(mx, __shfl_xor(mx, dd, 64));
  float sum = 0.f;
  for (int i=beg+ec; i<end; i+=8) sum += expf(logits[elist[i]*8+h] - mx);
  #pragma unroll
  for (int dd=8; dd<64; dd<<=1) sum += __shfl_xor(sum, dd, 64);
  float inv = 1.0f/(sum + 1e-9f);
  for (int i=beg+ec; i<end; i+=8){
    int e = elist[i];
    attnb[e*8 + h] = expf(logits[e*8+h]-mx)*inv;
  }
}

// rad: 16 edges/block
__global__ __launch_bounds__(256) void k_rad(const float* efeat, const float* Wrad, float* radb){
  __shared__ float wsh[C*RSTR];
  __shared__ float esh[16][132];
  int t = threadIdx.x;
  for (int q=t; q<C*MC; q+=256){ int cc=q/MC, m=q-cc*MC; wsh[cc*RSTR+m] = Wrad[q]; }
  int e0 = blockIdx.x*16;
  for (int q=t; q<16*C; q+=256) esh[q>>7][q&127] = efeat[(size_t)(e0+(q>>7))*C + (q&127)];
  __syncthreads();
  for (int q=t; q<16*MC; q+=256){
    int el = q/MC, m = q-el*MC;
    float acc = 0.f;
    #pragma unroll 4
    for (int cc=0; cc<C; ++cc) acc += esh[el][cc]*wsh[cc*RSTR+m];
    radb[(size_t)(e0+el)*RSTR + m] = silu(acc);
  }
}

// msum[n,m,d] = sum_e attn[e,h(d)]*rad[e,m]*V[src_e,m,d] (V bf16); then x[n] += msum @ Wo
__global__ __launch_bounds__(256) void k_e1(const unsigned short* __restrict__ V, const float* __restrict__ radb,
        const float* __restrict__ attnb, const float* __restrict__ Wo,
        const int* __restrict__ rowptr, const int* __restrict__ elist, const int* __restrict__ srcarr,
        float* __restrict__ x){
  __shared__ __align__(16) float msh[MC*C];
  int n = blockIdx.x;
  int t = threadIdx.x;
  int c0 = (t&63)*2; int g4 = t>>6;
  int h = c0 >> 4;
  float acc[5][2];
  #pragma unroll
  for (int i=0;i<5;i++){ acc[i][0]=0.f; acc[i][1]=0.f; }
  int beg = rowptr[n], end = rowptr[n+1];
  for (int idx=beg; idx<end; ++idx){
    int e = elist[idx];
    int s = srcarr[e];
    float a = attnb[e*8 + h];
    const unsigned short* vr = V + (size_t)s*(MC*C) + c0;
    const float* rr = radb + (size_t)e*RSTR;
    #pragma unroll
    for (int i=0;i<5;i++){
      int m = g4 + 4*i;
      if (m < MC){
        float ar = a * rr[m];
        float2 v2 = bf2f2(*(const unsigned*)&vr[m*C]);
        acc[i][0] += ar*v2.x;
        acc[i][1] += ar*v2.y;
      }
    }
  }
  #pragma unroll
  for (int i=0;i<5;i++){
    int m = g4 + 4*i;
    if (m < MC){ msh[m*C+c0] = acc[i][0]; msh[m*C+c0+1] = acc[i][1]; }
  }
  __syncthreads();
  // x[n] += msh @ Wo
  float acc2[5][2];
  #pragma unroll
  for (int i=0;i<5;i++){ acc2[i][0]=0.f; acc2[i][1]=0.f; }
  for (int d=0; d<C; d+=4){
    float2 w0 = *(const float2*)&Wo[(d+0)*C + c0];
    float2 w1 = *(const float2*)&Wo[(d+1)*C + c0];
    float2 w2 = *(const float2*)&Wo[(d+2)*C + c0];
    float2 w3 = *(const float2*)&Wo[(d+3)*C + c0];
    #pragma unroll
    for (int i=0;i<5;i++){
      int m = g4 + 4*i;
      if (m < MC){
        float4 m4 = *(const float4*)&msh[m*C + d];
        acc2[i][0] += m4.x*w0.x + m4.y*w1.x + m4.z*w2.x + m4.w*w3.x;
        acc2[i][1] += m4.x*w0.y + m4.y*w1.y + m4.z*w2.y + m4.w*w3.y;
      }
    }
  }
  #pragma unroll
  for (int i=0;i<5;i++){
    int m = g4 + 4*i;
    if (m < MC){
      size_t off = (size_t)n*MC*C + m*C + c0;
      x[off]   += acc2[i][0];
      x[off+1] += acc2[i][1];
    }
  }
}

// ---------------- fused: rmsnorm2 + gated FFN, 2 nodes/block ----------------
__global__ __launch_bounds__(256) void k_nodeB(float* __restrict__ x, const float* __restrict__ scale,
        const float* __restrict__ W1, const float* __restrict__ W2){
  __shared__ __align__(16) float xs[2*MC*C];
  __shared__ __align__(16) float hb[2*MC*C];
  __shared__ float gate[2*C];
  __shared__ float ssum[2][5];
  int t = threadIdx.x;
  int n0 = blockIdx.x*2;
  int ng = t>>7, c = t&127;
  int n = n0+ng;
  if (t < 10) ssum[t/5][t%5] = 0.f;
  __syncthreads();
  {
    float vals[MC];
    float pl[5]={0.f,0.f,0.f,0.f,0.f};
    #pragma unroll
    for (int m=0;m<MC;m++){
      float v = x[(size_t)n*MC*C + m*C + c];
      vals[m]=v;
      pl[l_of_m(m)] += v*v;
    }
    #pragma unroll
    for (int l=0;l<5;l++){
      float r = pl[l];
      #pragma unroll
      for (int d=32; d>0; d>>=1) r += __shfl_down(r, d, 64);
      if ((t&63)==0) atomicAdd(&ssum[ng][l], r);
    }
    __syncthreads();
    const float dens[5] = {128.f,384.f,640.f,896.f,1152.f};
    float inv[5];
    #pragma unroll
    for (int l=0;l<5;l++) inv[l] = 1.0f/sqrtf(ssum[ng][l]/dens[l] + 1e-8f);
    #pragma unroll
    for (int m=0;m<MC;m++){
      int l = l_of_m(m);
      xs[ng*MC*C + m*C + c] = vals[m]*inv[l]*scale[l*C + c];
    }
  }
  __syncthreads();
  int c0 = (t&63)*2, g4 = t>>6;
  // hb = xs @ W1
  {
    float acc[2][5][2];
    #pragma unroll
    for (int nd=0; nd<2; ++nd)
      #pragma unroll
      for (int i=0;i<5;i++){ acc[nd][i][0]=0.f; acc[nd][i][1]=0.f; }
    for (int cc=0; cc<C; cc+=4){
      float2 w0 = *(const float2*)&W1[(cc+0)*C + c0];
      float2 w1 = *(const float2*)&W1[(cc+1)*C + c0];
      float2 w2 = *(const float2*)&W1[(cc+2)*C + c0];
      float2 w3 = *(const float2*)&W1[(cc+3)*C + c0];
      #pragma unroll
      for (int nd=0; nd<2; ++nd){
        #pragma unroll
        for (int i=0;i<5;i++){
          int m = g4 + 4*i;
          if (m < MC){
            float4 a4 = *(const float4*)&xs[nd*MC*C + m*C + cc];
            acc[nd][i][0] += a4.x*w0.x + a4.y*w1.x + a4.z*w2.x + a4.w*w3.x;
            acc[nd][i][1] += a4.x*w0.y + a4.y*w1.y + a4.z*w2.y + a4.w*w3.y;
          }
        }
      }
    }
    #pragma unroll
    for (int nd=0; nd<2; ++nd)
      #pragma unroll
      for (int i=0;i<5;i++){
        int m = g4 + 4*i;
        if (m < MC){ hb[nd*MC*C + m*C + c0] = acc[nd][i][0]; hb[nd*MC*C + m*C + c0+1] = acc[nd][i][1]; }
      }
  }
  __syncthreads();
  {
    int nd = t>>7, cg = t&127;
    gate[nd*C+cg] = silu(hb[nd*MC*C + cg]);
  }
  __syncthreads();
  #pragma unroll
  for (int nd=0; nd<2; ++nd)
    for (int q=t; q<MC*C; q+=256)
      hb[nd*MC*C + q] *= gate[nd*C + (q&127)];
  __syncthreads();
  // x += hb @ W2
  {
    float acc[2][5][2];
    #pragma unroll
    for (int nd=0; nd<2; ++nd)
      #pragma unroll
      for (int i=0;i<5;i++){ acc[nd][i][0]=0.f; acc[nd][i][1]=0.f; }
    for (int f=0; f<C; f+=4){
      float2 w0 = *(const float2*)&W2[(f+0)*C + c0];
      float2 w1 = *(const float2*)&W2[(f+1)*C + c0];
      float2 w2 = *(const float2*)&W2[(f+2)*C + c0];
      float2 w3 = *(const float2*)&W2[(f+3)*C + c0];
      #pragma unroll
      for (int nd=0; nd<2; ++nd){
        #pragma unroll
        for (int i=0;i<5;i++){
          int m = g4 + 4*i;
          if (m < MC){
            float4 a4 = *(const float4*)&hb[nd*MC*C + m*C + f];
            acc[nd][i][0] += a4.x*w0.x + a4.y*w1.x + a4.z*w2.x + a4.w*w3.x;
            acc[nd][i][1] += a4.x*w0.y + a4.y*w1.y + a4.z*w2.y + a4.w*w3.y;
          }
        }
      }
    }
    #pragma unroll
    for (int nd=0; nd<2; ++nd)
      #pragma unroll
      for (int i=0;i<5;i++){
        int m = g4 + 4*i;
        if (m < MC){
          size_t off = (size_t)(n0+nd)*MC*C + m*C + c0;
          float2 old = *(float2*)&x[off];
          old.x += acc[nd][i][0];
          old.y += acc[nd][i][1];
          *(float2*)&x[off] = old;
        }
      }
  }
}

// ---------------- final head ----------------
__global__ __launch_bounds__(128) void k_final(const float* x, const float* nsf, const float* Wef1,
        const float* Wef2, const int* batch, float* out){
  __shared__ float sl[C];
  __shared__ float red[2];
  __shared__ float red2[2];
  int n = blockIdx.x; int t = threadIdx.x;
  float v = x[(size_t)n*MC*C + t];
  float sq = v*v;
  for (int d=32; d>0; d>>=1) sq += __shfl_down(sq, d, 64);
  if ((t&63)==0) red[t>>6] = sq;
  __syncthreads();
  float ms = (red[0]+red[1]) * (1.0f/128.f);
  float inv = 1.0f/sqrtf(ms + 1e-8f);
  sl[t] = v*inv*nsf[t];
  __syncthreads();
  float acc = 0.f;
  for (int cc=0; cc<C; ++cc) acc += sl[cc]*Wef1[cc*C + t];
  float val = acc*silu(acc)*Wef2[t];
  for (int d=32; d>0; d>>=1) val += __shfl_down(val, d, 64);
  if ((t&63)==0) red2[t>>6] = val;
  __syncthreads();
  if (t==0){
    float ne = red2[0]+red2[1];
    atomicAdd(&out[batch[n]], ne * (1.0f/77.81317f));
  }
}

extern "C" void kernel_launch(void* const* d_in, const int* in_sizes, int n_in,
                              void* d_out, int out_size, void* d_ws, size_t ws_size,
                              hipStream_t stream){
  (void)in_sizes; (void)n_in; (void)ws_size;
  const int*   anum  = (const int*)d_in[0];
  const int*   eidx  = (const int*)d_in[1];
  const float* dist  = (const float*)d_in[2];
  const int*   batch = (const int*)d_in[3];
  const float* emb   = (const float*)d_in[4];
  const float* We1   = (const float*)d_in[5];
  const float* We2   = (const float*)d_in[6];
  const float* Wdeg  = (const float*)d_in[7];
  const float* ns1   = (const float*)d_in[8];
  const float* ns2   = (const float*)d_in[9];
  const float* Wq    = (const float*)d_in[10];
  const float* Wk    = (const float*)d_in[11];
  const float* alpha = (const float*)d_in[12];
  const float* Wv    = (const float*)d_in[13];
  const float* Wrad  = (const float*)d_in[14];
  const float* Wo    = (const float*)d_in[15];
  const float* W1    = (const float*)d_in[16];
  const float* W2    = (const float*)d_in[17];
  const float* nsf   = (const float*)d_in[18];
  const float* Wef1  = (const float*)d_in[19];
  const float* Wef2  = (const float*)d_in[20];
  float* out = (float*)d_out;

  const int* srcarr = eidx;
  const int* tgtarr = eidx + N_EDGES;

  char* wsb = (char*)d_ws;
  float* efeat = (float*)wsb;  wsb += (size_t)N_EDGES*C*4;
  float* efsum = (float*)wsb;  wsb += (size_t)N_NODES*C*4;
  float* x     = (float*)wsb;  wsb += (size_t)N_NODES*MC*C*4;
  unsigned short* Vb = (unsigned short*)wsb; wsb += (size_t)N_NODES*MC*C*2;
  unsigned short* qb = (unsigned short*)wsb; wsb += (size_t)N_NODES*512*2;
  unsigned short* kb = (unsigned short*)wsb; wsb += (size_t)N_NODES*512*2;
  float* logit = (float*)wsb;  wsb += (size_t)N_EDGES*8*4;
  float* attnb = (float*)wsb;  wsb += (size_t)N_EDGES*8*4;
  float* radb  = (float*)wsb;  wsb += (size_t)N_EDGES*RSTR*4;
  int* deg     = (int*)wsb;    wsb += (size_t)N_NODES*4;
  int* rowptr  = (int*)wsb;    wsb += (size_t)(N_NODES+1)*4;
  int* cursor  = (int*)wsb;    wsb += (size_t)N_NODES*4;
  int* elist   = (int*)wsb;    wsb += (size_t)N_EDGES*4;

  (void)hipMemsetAsync(deg, 0, N_NODES*4, stream);
  (void)hipMemsetAsync(cursor, 0, N_NODES*4, stream);
  (void)hipMemsetAsync(d_out, 0, (size_t)out_size*sizeof(float), stream);

  k_count<<<(N_EDGES+255)/256, 256, 0, stream>>>(tgtarr, deg);
  k_scan<<<1, 64, 0, stream>>>(deg, rowptr);
  k_fill<<<(N_EDGES+255)/256, 256, 0, stream>>>(tgtarr, rowptr, cursor, elist);
  k_efeat<<<N_EDGES/16, 256, 0, stream>>>(dist, We1, We2, efeat);
  k_efsum<<<N_NODES, 128, 0, stream>>>(efeat, rowptr, elist, efsum);
  k_deginit<<<(N_NODES+7)/8, 256, 0, stream>>>(efsum, Wdeg, emb, anum, x);

  for (int i=0;i<NL;i++){
    k_nodeA<<<N_NODES/4, 256, 0, stream>>>(x, ns1 + i*5*C, Wq + i*C*512, Wk + i*C*512,
                                           Wv + i*C*C, qb, kb, Vb);
    k_logits<<<(N_EDGES+3)/4, 256, 0, stream>>>(qb, kb, alpha + i*512, srcarr, tgtarr, logit);
    k_softmax<<<(N_NODES+3)/4, 256, 0, stream>>>(logit, rowptr, elist, attnb);
    k_rad<<<N_EDGES/16, 256, 0, stream>>>(efeat, Wrad + i*C*MC, radb);
    k_e1<<<N_NODES, 256, 0, stream>>>(Vb, radb, attnb, Wo + i*C*C,
                                      rowptr, elist, srcarr, x);
    k_nodeB<<<N_NODES/2, 256, 0, stream>>>(x, ns2 + i*5*C, W1 + i*C*C, W2 + i*C*C);
  }
  k_final<<<N_NODES, 128, 0, stream>>>(x, nsf, Wef1, Wef2, batch, out);
}

// Round 9
// 1496.161 us; speedup vs baseline: 3.1190x; 1.0925x over previous
//
#include <hip/hip_runtime.h>
#include <hip/hip_bf16.h>

#define N_NODES 2500
#define N_EDGES 50000
#define C 128
#define MC 19
#define RSTR 20
#define NL 4
#define NB 600
#define GW 20

__device__ __forceinline__ float silu(float v){ return v / (1.f + expf(-v)); }
__device__ __forceinline__ int l_of_m(int m){
  return (m==0)?0 : (m<4)?1 : (m<9)?2 : (m<14)?3 : 4;
}
__device__ __forceinline__ unsigned pack2(float a, float b){
  __hip_bfloat162 h2;
  h2.x = __float2bfloat16(a);
  h2.y = __float2bfloat16(b);
  return *(unsigned*)&h2;
}
__device__ __forceinline__ float2 bf2f2(unsigned u){
  float2 r;
  r.x = __uint_as_float(u << 16);
  r.y = __uint_as_float(u & 0xffff0000u);
  return r;
}

// ---------------- CSR build ----------------
__global__ void k_count(const int* tgt, int* deg){
  int e = blockIdx.x*256 + threadIdx.x;
  if (e < N_EDGES) atomicAdd(&deg[tgt[e]], 1);
}

__global__ void k_scan(const int* deg, int* rowptr){
  int lane = threadIdx.x;               // 64 threads
  const int CH = (N_NODES + 63)/64;     // 40
  int base = lane*CH;
  int s = 0;
  for (int i=0;i<CH;i++){ int idx=base+i; if (idx<N_NODES) s += deg[idx]; }
  int inc = s;
  for (int d=1; d<64; d<<=1){
    int v = __shfl_up(inc, d, 64);
    if (lane >= d) inc += v;
  }
  int run = inc - s;                    // exclusive prefix
  for (int i=0;i<CH;i++){
    int idx = base+i;
    if (idx < N_NODES){ rowptr[idx] = run; run += deg[idx]; }
  }
  if (lane == 63) rowptr[N_NODES] = run;
}

__global__ void k_fill(const int* tgt, const int* rowptr, int* cursor, int* elist){
  int e = blockIdx.x*256 + threadIdx.x;
  if (e < N_EDGES){
    int n = tgt[e];
    int pos = atomicAdd(&cursor[n], 1);
    elist[rowptr[n] + pos] = e;
  }
}

// ---------------- edge features: 16 edges/block, coalesced both stages ----------------
__global__ __launch_bounds__(256) void k_efeat(const float* __restrict__ dist, const float* __restrict__ We1,
                                               const float* __restrict__ We2, float* __restrict__ efeat){
  __shared__ float gbuf[16][44];
  __shared__ __align__(16) float t1[16*132];
  __shared__ float dsh[16];
  __shared__ int j0s[16];
  __shared__ int cns[16];
  int t = threadIdx.x;
  int e0 = blockIdx.x*16;
  const float delta = 12.0f/599.0f;
  const float coeff = -0.5f/((2.0f*delta)*(2.0f*delta));
  if (t < 16){
    float d = dist[e0+t];
    int jc = (int)floorf(d/delta + 0.5f);
    int j0 = jc-GW; if (j0<0) j0=0;
    int j1 = jc+GW; if (j1>NB-1) j1=NB-1;
    dsh[t]=d; j0s[t]=j0; cns[t]=j1-j0+1;
  }
  __syncthreads();
  for (int q=t; q<16*41; q+=256){
    int el = q/41, w = q - el*41;
    float g = 0.f;
    if (w < cns[el]){
      float off = (float)(j0s[el]+w)*delta;
      float dd = dsh[el]-off;
      g = expf(coeff*dd*dd);
    }
    gbuf[el][w] = g;
  }
  __syncthreads();
  {
    int elb = t>>5, c4 = (t&31)*4;
    #pragma unroll
    for (int half=0; half<2; ++half){
      int el = elb + 8*half;
      int j0 = j0s[el];
      float a0=0.f,a1=0.f,a2=0.f,a3=0.f;
      for (int w=0; w<41; ++w){
        float g = gbuf[el][w];
        int row = j0+w; if (row > NB-1) row = NB-1;
        float4 wv = *(const float4*)&We1[(size_t)row*C + c4];
        a0 += g*wv.x; a1 += g*wv.y; a2 += g*wv.z; a3 += g*wv.w;
      }
      float4 st; st.x=silu(a0); st.y=silu(a1); st.z=silu(a2); st.w=silu(a3);
      *(float4*)&t1[el*132 + c4] = st;
    }
  }
  __syncthreads();
  {
    int grp = t>>6;
    int c2 = (t&63)*2;
    float acc[4][2];
    #pragma unroll
    for (int i=0;i<4;i++){ acc[i][0]=0.f; acc[i][1]=0.f; }
    for (int cc=0; cc<C; cc+=4){
      float2 w0 = *(const float2*)&We2[(cc+0)*C + c2];
      float2 w1 = *(const float2*)&We2[(cc+1)*C + c2];
      float2 w2 = *(const float2*)&We2[(cc+2)*C + c2];
      float2 w3 = *(const float2*)&We2[(cc+3)*C + c2];
      #pragma unroll
      for (int i=0;i<4;i++){
        int el = grp*4 + i;
        float4 a4 = *(const float4*)&t1[el*132 + cc];
        acc[i][0] += a4.x*w0.x + a4.y*w1.x + a4.z*w2.x + a4.w*w3.x;
        acc[i][1] += a4.x*w0.y + a4.y*w1.y + a4.z*w2.y + a4.w*w3.y;
      }
    }
    #pragma unroll
    for (int i=0;i<4;i++){
      int el = grp*4 + i;
      float2 st; st.x = silu(acc[i][0]); st.y = silu(acc[i][1]);
      *(float2*)&efeat[(size_t)(e0+el)*C + c2] = st;
    }
  }
}

__global__ void k_efsum(const float* efeat, const int* rowptr, const int* elist, float* efsum){
  int n = blockIdx.x; int t = threadIdx.x; // 128 threads
  float acc = 0.f;
  int beg = rowptr[n], end = rowptr[n+1];
  for (int i=beg;i<end;i++)
    acc += efeat[elist[i]*C + t];
  efsum[n*C + t] = acc;
}

// ---------------- deg-init: 8 nodes/block ----------------
__global__ __launch_bounds__(256) void k_deginit(const float* __restrict__ efsum, const float* __restrict__ Wdeg,
        const float* __restrict__ emb, const int* __restrict__ anum, float* __restrict__ x){
  __shared__ __align__(16) float efT[C][8];
  int t = threadIdx.x;
  int n0 = blockIdx.x*8;
  for (int q=t; q<8*C; q+=256){
    int nd=q>>7, cc=q&127;
    int n=n0+nd;
    efT[cc][nd] = (n<N_NODES)? efsum[n*C+cc] : 0.f;
  }
  __syncthreads();
  const float inv_avg = 1.0f/23.395238876342773f;
  #pragma unroll
  for (int grp=0; grp<5; ++grp){
    int o = grp*512 + t*2;
    if (o < MC*C){
      float a0[8], a1[8];
      #pragma unroll
      for (int i=0;i<8;i++){ a0[i]=0.f; a1[i]=0.f; }
      for (int cc=0; cc<C; ++cc){
        float2 w = *(const float2*)&Wdeg[(size_t)cc*(MC*C)+o];
        float4 e0 = *(const float4*)&efT[cc][0];
        float4 e1 = *(const float4*)&efT[cc][4];
        a0[0]+=e0.x*w.x; a1[0]+=e0.x*w.y;
        a0[1]+=e0.y*w.x; a1[1]+=e0.y*w.y;
        a0[2]+=e0.z*w.x; a1[2]+=e0.z*w.y;
        a0[3]+=e0.w*w.x; a1[3]+=e0.w*w.y;
        a0[4]+=e1.x*w.x; a1[4]+=e1.x*w.y;
        a0[5]+=e1.y*w.x; a1[5]+=e1.y*w.y;
        a0[6]+=e1.z*w.x; a1[6]+=e1.z*w.y;
        a0[7]+=e1.w*w.x; a1[7]+=e1.w*w.y;
      }
      #pragma unroll
      for (int nd=0; nd<8; ++nd){
        int n = n0+nd;
        if (n < N_NODES){
          float v0 = a0[nd]*inv_avg, v1 = a1[nd]*inv_avg;
          if (o < C){ int an=anum[n]; v0 += emb[an*C+o]; v1 += emb[an*C+o+1]; }
          float2 st; st.x=v0; st.y=v1;
          *(float2*)&x[(size_t)n*MC*C + o] = st;
        }
      }
    }
  }
}

// ---------------- fused: rmsnorm1 + QK + V, 4 nodes/block; qb/kb/V stored bf16 ----------------
__global__ __launch_bounds__(256) void k_nodeA(const float* __restrict__ x, const float* __restrict__ scale,
        const float* __restrict__ Wq, const float* __restrict__ Wk, const float* __restrict__ Wv,
        unsigned short* __restrict__ qb, unsigned short* __restrict__ kb, unsigned short* __restrict__ V){
  __shared__ __align__(16) float xs[4*MC*C];   // 38912 B
  int t = threadIdx.x;
  int n0 = blockIdx.x*4;
  {
    int ng = t>>6, lane = t&63;
    int n = n0+ng;
    float2 xv[MC];
    float pl[5]={0.f,0.f,0.f,0.f,0.f};
    #pragma unroll
    for (int m=0;m<MC;m++){
      float2 v = *(const float2*)&x[(size_t)n*MC*C + m*C + lane*2];
      xv[m]=v;
      pl[l_of_m(m)] += v.x*v.x + v.y*v.y;
    }
    #pragma unroll
    for (int l=0;l<5;l++){
      float r = pl[l];
      #pragma unroll
      for (int d=32; d>0; d>>=1) r += __shfl_xor(r, d, 64);
      pl[l]=r;
    }
    const float dens[5] = {128.f,384.f,640.f,896.f,1152.f};
    float inv[5];
    #pragma unroll
    for (int l=0;l<5;l++) inv[l] = 1.0f/sqrtf(pl[l]/dens[l] + 1e-8f);
    #pragma unroll
    for (int m=0;m<MC;m++){
      int l = l_of_m(m);
      float2 sc = *(const float2*)&scale[l*C + lane*2];
      float2 st; st.x = xv[m].x*inv[l]*sc.x; st.y = xv[m].y*inv[l]*sc.y;
      *(float2*)&xs[ng*MC*C + m*C + lane*2] = st;
    }
  }
  __syncthreads();
  // QK: thread owns o,o+1 for all 4 nodes
  {
    int o = t*2;
    float aq[4][2], ak[4][2];
    #pragma unroll
    for (int nd=0; nd<4; ++nd){ aq[nd][0]=aq[nd][1]=ak[nd][0]=ak[nd][1]=0.f; }
    for (int cc=0; cc<C; cc+=4){
      float2 q0 = *(const float2*)&Wq[(cc+0)*512 + o];
      float2 q1 = *(const float2*)&Wq[(cc+1)*512 + o];
      float2 q2 = *(const float2*)&Wq[(cc+2)*512 + o];
      float2 q3 = *(const float2*)&Wq[(cc+3)*512 + o];
      float2 k0 = *(const float2*)&Wk[(cc+0)*512 + o];
      float2 k1 = *(const float2*)&Wk[(cc+1)*512 + o];
      float2 k2 = *(const float2*)&Wk[(cc+2)*512 + o];
      float2 k3 = *(const float2*)&Wk[(cc+3)*512 + o];
      #pragma unroll
      for (int nd=0; nd<4; ++nd){
        float4 s4 = *(const float4*)&xs[nd*MC*C + cc];
        aq[nd][0] += s4.x*q0.x + s4.y*q1.x + s4.z*q2.x + s4.w*q3.x;
        aq[nd][1] += s4.x*q0.y + s4.y*q1.y + s4.z*q2.y + s4.w*q3.y;
        ak[nd][0] += s4.x*k0.x + s4.y*k1.x + s4.z*k2.x + s4.w*k3.x;
        ak[nd][1] += s4.x*k0.y + s4.y*k1.y + s4.z*k2.y + s4.w*k3.y;
      }
    }
    #pragma unroll
    for (int nd=0; nd<4; ++nd){
      *(unsigned*)&qb[(size_t)(n0+nd)*512 + o] = pack2(aq[nd][0], aq[nd][1]);
      *(unsigned*)&kb[(size_t)(n0+nd)*512 + o] = pack2(ak[nd][0], ak[nd][1]);
    }
  }
  // V = xs @ Wv
  {
    int c0 = (t&63)*2, g4 = t>>6;
    float acc[4][5][2];
    #pragma unroll
    for (int nd=0; nd<4; ++nd)
      #pragma unroll
      for (int i=0;i<5;i++){ acc[nd][i][0]=0.f; acc[nd][i][1]=0.f; }
    for (int cc=0; cc<C; cc+=4){
      float2 w0 = *(const float2*)&Wv[(cc+0)*C + c0];
      float2 w1 = *(const float2*)&Wv[(cc+1)*C + c0];
      float2 w2 = *(const float2*)&Wv[(cc+2)*C + c0];
      float2 w3 = *(const float2*)&Wv[(cc+3)*C + c0];
      #pragma unroll
      for (int nd=0; nd<4; ++nd){
        #pragma unroll
        for (int i=0;i<5;i++){
          int m = g4 + 4*i;
          if (m < MC){
            float4 a4 = *(const float4*)&xs[nd*MC*C + m*C + cc];
            acc[nd][i][0] += a4.x*w0.x + a4.y*w1.x + a4.z*w2.x + a4.w*w3.x;
            acc[nd][i][1] += a4.x*w0.y + a4.y*w1.y + a4.z*w2.y + a4.w*w3.y;
          }
        }
      }
    }
    #pragma unroll
    for (int nd=0; nd<4; ++nd){
      #pragma unroll
      for (int i=0;i<5;i++){
        int m = g4 + 4*i;
        if (m < MC)
          *(unsigned*)&V[(size_t)(n0+nd)*MC*C + m*C + c0] = pack2(acc[nd][i][0], acc[nd][i][1]);
      }
    }
  }
}

// ---------------- logits: wave per edge; lane owns 8 bf16 (one dwordx4 per operand) ----------------
__global__ __launch_bounds__(256) void k_logits(const unsigned short* __restrict__ qb,
        const unsigned short* __restrict__ kb, const float* __restrict__ alpha,
        const int* __restrict__ srcarr, const int* __restrict__ tgtarr, float* __restrict__ logits){
  int wid = threadIdx.x >> 6; int lane = threadIdx.x & 63;
  int e = blockIdx.x*4 + wid;
  if (e >= N_EDGES) return;
  float al[8];
  {
    float4 a0 = *(const float4*)&alpha[lane*8];
    float4 a1 = *(const float4*)&alpha[lane*8+4];
    al[0]=a0.x; al[1]=a0.y; al[2]=a0.z; al[3]=a0.w;
    al[4]=a1.x; al[5]=a1.y; al[6]=a1.z; al[7]=a1.w;
  }
  int s = srcarr[e], tg = tgtarr[e];
  int4 qv = *(const int4*)&qb[(size_t)tg*512 + lane*8];
  int4 kv = *(const int4*)&kb[(size_t)s*512 + lane*8];
  unsigned qu[4] = {(unsigned)qv.x,(unsigned)qv.y,(unsigned)qv.z,(unsigned)qv.w};
  unsigned ku[4] = {(unsigned)kv.x,(unsigned)kv.y,(unsigned)kv.z,(unsigned)kv.w};
  float acc = 0.f;
  #pragma unroll
  for (int j=0;j<4;j++){
    float2 q2 = bf2f2(qu[j]);
    float2 k2 = bf2f2(ku[j]);
    acc += silu(q2.x+k2.x)*al[2*j]   + silu(q2.y+k2.y)*al[2*j+1];
  }
  #pragma unroll
  for (int d=1; d<8; d<<=1) acc += __shfl_down(acc, d, 64);
  if ((lane&7)==0) logits[e*8 + (lane>>3)] = acc * 0.125f;
}

// one wave per node; lane = (edge-chunk<<3) | h
__global__ __launch_bounds__(256) void k_softmax(const float* logits, const int* rowptr, const int* elist, float* attnb){
  int n = blockIdx.x*4 + (threadIdx.x>>6);
  if (n >= N_NODES) return;
  int lane = threadIdx.x & 63;
  int h = lane & 7, ec = lane >> 3;
  int beg = rowptr[n], end = rowptr[n+1];
  float mx = -1e30f;
  for (int i=beg+ec; i<end; i+=8) mx = fmaxf(mx, logits[elist[i]*8+h]);
  #pragma unroll
  for (int dd=8; dd<64; dd<<=1) mx = fmaxf(mx, __shfl_xor(mx, dd, 64));
  float sum = 0.f;
  for (int i=beg+ec; i<end; i+=8) sum += expf(logits[elist[i]*8+h] - mx);
  #pragma unroll
  for (int dd=8; dd<64; dd<<=1) sum += __shfl_xor(sum, dd, 64);
  float inv = 1.0f/(sum + 1e-9f);
  for (int i=beg+ec; i<end; i+=8){
    int e = elist[i];
    attnb[e*8 + h] = expf(logits[e*8+h]-mx)*inv;
  }
}

// rad: 16 edges/block
__global__ __launch_bounds__(256) void k_rad(const float* efeat, const float* Wrad, float* radb){
  __shared__ float wsh[C*RSTR];
  __shared__ float esh[16][132];
  int t = threadIdx.x;
  for (int q=t; q<C*MC; q+=256){ int cc=q/MC, m=q-cc*MC; wsh[cc*RSTR+m] = Wrad[q]; }
  int e0 = blockIdx.x*16;
  for (int q=t; q<16*C; q+=256) esh[q>>7][q&127] = efeat[(size_t)(e0+(q>>7))*C + (q&127)];
  __syncthreads();
  for (int q=t; q<16*MC; q+=256){
    int el = q/MC, m = q-el*MC;
    float acc = 0.f;
    #pragma unroll 4
    for (int cc=0; cc<C; ++cc) acc += esh[el][cc]*wsh[cc*RSTR+m];
    radb[(size_t)(e0+el)*RSTR + m] = silu(acc);
  }
}

// msum[n,m,d] = sum_e attn[e,h(d)]*rad[e,m]*V[src_e,m,d]  (V bf16)
// wave w handles edges beg+w, beg+w+4, ... with the FULL m range (19x2 accs) for max MLP;
// 4 LDS partials reduced, then x[n] += msum @ Wo.
__global__ __launch_bounds__(256) void k_e1(const unsigned short* __restrict__ V, const float* __restrict__ radb,
        const float* __restrict__ attnb, const float* __restrict__ Wo,
        const int* __restrict__ rowptr, const int* __restrict__ elist, const int* __restrict__ srcarr,
        float* __restrict__ x){
  __shared__ __align__(16) float part[4][MC*C];   // 38912 B; part[0] doubles as msum
  int n = blockIdx.x;
  int t = threadIdx.x;
  int w = t>>6, lane = t&63;
  int c0 = lane*2;
  int h = c0 >> 4;
  float acc[MC][2];
  #pragma unroll
  for (int m=0;m<MC;m++){ acc[m][0]=0.f; acc[m][1]=0.f; }
  int beg = rowptr[n], end = rowptr[n+1];
  for (int idx=beg+w; idx<end; idx+=4){
    int e = elist[idx];
    int s = srcarr[e];
    float a = attnb[e*8 + h];
    const unsigned short* vr = V + (size_t)s*(MC*C) + c0;
    const float* rr = radb + (size_t)e*RSTR;
    float4 r0 = *(const float4*)&rr[0];
    float4 r1 = *(const float4*)&rr[4];
    float4 r2 = *(const float4*)&rr[8];
    float4 r3 = *(const float4*)&rr[12];
    float4 r4 = *(const float4*)&rr[16];
    float rm[20] = {r0.x,r0.y,r0.z,r0.w, r1.x,r1.y,r1.z,r1.w,
                    r2.x,r2.y,r2.z,r2.w, r3.x,r3.y,r3.z,r3.w,
                    r4.x,r4.y,r4.z,r4.w};
    #pragma unroll
    for (int m=0;m<MC;m++){
      float ar = a * rm[m];
      float2 v2 = bf2f2(*(const unsigned*)&vr[m*C]);
      acc[m][0] += ar*v2.x;
      acc[m][1] += ar*v2.y;
    }
  }
  #pragma unroll
  for (int m=0;m<MC;m++){
    part[w][m*C+c0]   = acc[m][0];
    part[w][m*C+c0+1] = acc[m][1];
  }
  __syncthreads();
  for (int q=t; q<MC*C; q+=256)
    part[0][q] = part[0][q] + part[1][q] + part[2][q] + part[3][q];
  __syncthreads();
  // x[n] += part[0] @ Wo
  int c0e = (t&63)*2; int g4 = t>>6;
  float acc2[5][2];
  #pragma unroll
  for (int i=0;i<5;i++){ acc2[i][0]=0.f; acc2[i][1]=0.f; }
  for (int d=0; d<C; d+=4){
    float2 w0 = *(const float2*)&Wo[(d+0)*C + c0e];
    float2 w1 = *(const float2*)&Wo[(d+1)*C + c0e];
    float2 w2 = *(const float2*)&Wo[(d+2)*C + c0e];
    float2 w3 = *(const float2*)&Wo[(d+3)*C + c0e];
    #pragma unroll
    for (int i=0;i<5;i++){
      int m = g4 + 4*i;
      if (m < MC){
        float4 m4 = *(const float4*)&part[0][m*C + d];
        acc2[i][0] += m4.x*w0.x + m4.y*w1.x + m4.z*w2.x + m4.w*w3.x;
        acc2[i][1] += m4.x*w0.y + m4.y*w1.y + m4.z*w2.y + m4.w*w3.y;
      }
    }
  }
  #pragma unroll
  for (int i=0;i<5;i++){
    int m = g4 + 4*i;
    if (m < MC){
      size_t off = (size_t)n*MC*C + m*C + c0e;
      x[off]   += acc2[i][0];
      x[off+1] += acc2[i][1];
    }
  }
}

// ---------------- fused: rmsnorm2 + gated FFN, 2 nodes/block ----------------
__global__ __launch_bounds__(256) void k_nodeB(float* __restrict__ x, const float* __restrict__ scale,
        const float* __restrict__ W1, const float* __restrict__ W2){
  __shared__ __align__(16) float xs[2*MC*C];
  __shared__ __align__(16) float hb[2*MC*C];
  __shared__ float gate[2*C];
  __shared__ float ssum[2][5];
  int t = threadIdx.x;
  int n0 = blockIdx.x*2;
  int ng = t>>7, c = t&127;
  int n = n0+ng;
  if (t < 10) ssum[t/5][t%5] = 0.f;
  __syncthreads();
  {
    float vals[MC];
    float pl[5]={0.f,0.f,0.f,0.f,0.f};
    #pragma unroll
    for (int m=0;m<MC;m++){
      float v = x[(size_t)n*MC*C + m*C + c];
      vals[m]=v;
      pl[l_of_m(m)] += v*v;
    }
    #pragma unroll
    for (int l=0;l<5;l++){
      float r = pl[l];
      #pragma unroll
      for (int d=32; d>0; d>>=1) r += __shfl_down(r, d, 64);
      if ((t&63)==0) atomicAdd(&ssum[ng][l], r);
    }
    __syncthreads();
    const float dens[5] = {128.f,384.f,640.f,896.f,1152.f};
    float inv[5];
    #pragma unroll
    for (int l=0;l<5;l++) inv[l] = 1.0f/sqrtf(ssum[ng][l]/dens[l] + 1e-8f);
    #pragma unroll
    for (int m=0;m<MC;m++){
      int l = l_of_m(m);
      xs[ng*MC*C + m*C + c] = vals[m]*inv[l]*scale[l*C + c];
    }
  }
  __syncthreads();
  int c0 = (t&63)*2, g4 = t>>6;
  // hb = xs @ W1
  {
    float acc[2][5][2];
    #pragma unroll
    for (int nd=0; nd<2; ++nd)
      #pragma unroll
      for (int i=0;i<5;i++){ acc[nd][i][0]=0.f; acc[nd][i][1]=0.f; }
    for (int cc=0; cc<C; cc+=4){
      float2 w0 = *(const float2*)&W1[(cc+0)*C + c0];
      float2 w1 = *(const float2*)&W1[(cc+1)*C + c0];
      float2 w2 = *(const float2*)&W1[(cc+2)*C + c0];
      float2 w3 = *(const float2*)&W1[(cc+3)*C + c0];
      #pragma unroll
      for (int nd=0; nd<2; ++nd){
        #pragma unroll
        for (int i=0;i<5;i++){
          int m = g4 + 4*i;
          if (m < MC){
            float4 a4 = *(const float4*)&xs[nd*MC*C + m*C + cc];
            acc[nd][i][0] += a4.x*w0.x + a4.y*w1.x + a4.z*w2.x + a4.w*w3.x;
            acc[nd][i][1] += a4.x*w0.y + a4.y*w1.y + a4.z*w2.y + a4.w*w3.y;
          }
        }
      }
    }
    #pragma unroll
    for (int nd=0; nd<2; ++nd)
      #pragma unroll
      for (int i=0;i<5;i++){
        int m = g4 + 4*i;
        if (m < MC){ hb[nd*MC*C + m*C + c0] = acc[nd][i][0]; hb[nd*MC*C + m*C + c0+1] = acc[nd][i][1]; }
      }
  }
  __syncthreads();
  {
    int nd = t>>7, cg = t&127;
    gate[nd*C+cg] = silu(hb[nd*MC*C + cg]);
  }
  __syncthreads();
  #pragma unroll
  for (int nd=0; nd<2; ++nd)
    for (int q=t; q<MC*C; q+=256)
      hb[nd*MC*C + q] *= gate[nd*C + (q&127)];
  __syncthreads();
  // x += hb @ W2
  {
    float acc[2][5][2];
    #pragma unroll
    for (int nd=0; nd<2; ++nd)
      #pragma unroll
      for (int i=0;i<5;i++){ acc[nd][i][0]=0.f; acc[nd][i][1]=0.f; }
    for (int f=0; f<C; f+=4){
      float2 w0 = *(const float2*)&W2[(f+0)*C + c0];
      float2 w1 = *(const float2*)&W2[(f+1)*C + c0];
      float2 w2 = *(const float2*)&W2[(f+2)*C + c0];
      float2 w3 = *(const float2*)&W2[(f+3)*C + c0];
      #pragma unroll
      for (int nd=0; nd<2; ++nd){
        #pragma unroll
        for (int i=0;i<5;i++){
          int m = g4 + 4*i;
          if (m < MC){
            float4 a4 = *(const float4*)&hb[nd*MC*C + m*C + f];
            acc[nd][i][0] += a4.x*w0.x + a4.y*w1.x + a4.z*w2.x + a4.w*w3.x;
            acc[nd][i][1] += a4.x*w0.y + a4.y*w1.y + a4.z*w2.y + a4.w*w3.y;
          }
        }
      }
    }
    #pragma unroll
    for (int nd=0; nd<2; ++nd)
      #pragma unroll
      for (int i=0;i<5;i++){
        int m = g4 + 4*i;
        if (m < MC){
          size_t off = (size_t)(n0+nd)*MC*C + m*C + c0;
          float2 old = *(float2*)&x[off];
          old.x += acc[nd][i][0];
          old.y += acc[nd][i][1];
          *(float2*)&x[off] = old;
        }
      }
  }
}

// ---------------- final head ----------------
__global__ __launch_bounds__(128) void k_final(const float* x, const float* nsf, const float* Wef1,
        const float* Wef2, const int* batch, float* out){
  __shared__ float sl[C];
  __shared__ float red[2];
  __shared__ float red2[2];
  int n = blockIdx.x; int t = threadIdx.x;
  float v = x[(size_t)n*MC*C + t];
  float sq = v*v;
  for (int d=32; d>0; d>>=1) sq += __shfl_down(sq, d, 64);
  if ((t&63)==0) red[t>>6] = sq;
  __syncthreads();
  float ms = (red[0]+red[1]) * (1.0f/128.f);
  float inv = 1.0f/sqrtf(ms + 1e-8f);
  sl[t] = v*inv*nsf[t];
  __syncthreads();
  float acc = 0.f;
  for (int cc=0; cc<C; ++cc) acc += sl[cc]*Wef1[cc*C + t];
  float val = acc*silu(acc)*Wef2[t];
  for (int d=32; d>0; d>>=1) val += __shfl_down(val, d, 64);
  if ((t&63)==0) red2[t>>6] = val;
  __syncthreads();
  if (t==0){
    float ne = red2[0]+red2[1];
    atomicAdd(&out[batch[n]], ne * (1.0f/77.81317f));
  }
}

extern "C" void kernel_launch(void* const* d_in, const int* in_sizes, int n_in,
                              void* d_out, int out_size, void* d_ws, size_t ws_size,
                              hipStream_t stream){
  (void)in_sizes; (void)n_in; (void)ws_size;
  const int*   anum  = (const int*)d_in[0];
  const int*   eidx  = (const int*)d_in[1];
  const float* dist  = (const float*)d_in[2];
  const int*   batch = (const int*)d_in[3];
  const float* emb   = (const float*)d_in[4];
  const float* We1   = (const float*)d_in[5];
  const float* We2   = (const float*)d_in[6];
  const float* Wdeg  = (const float*)d_in[7];
  const float* ns1   = (const float*)d_in[8];
  const float* ns2   = (const float*)d_in[9];
  const float* Wq    = (const float*)d_in[10];
  const float* Wk    = (const float*)d_in[11];
  const float* alpha = (const float*)d_in[12];
  const float* Wv    = (const float*)d_in[13];
  const float* Wrad  = (const float*)d_in[14];
  const float* Wo    = (const float*)d_in[15];
  const float* W1    = (const float*)d_in[16];
  const float* W2    = (const float*)d_in[17];
  const float* nsf   = (const float*)d_in[18];
  const float* Wef1  = (const float*)d_in[19];
  const float* Wef2  = (const float*)d_in[20];
  float* out = (float*)d_out;

  const int* srcarr = eidx;
  const int* tgtarr = eidx + N_EDGES;

  char* wsb = (char*)d_ws;
  float* efeat = (float*)wsb;  wsb += (size_t)N_EDGES*C*4;
  float* efsum = (float*)wsb;  wsb += (size_t)N_NODES*C*4;
  float* x     = (float*)wsb;  wsb += (size_t)N_NODES*MC*C*4;
  unsigned short* Vb = (unsigned short*)wsb; wsb += (size_t)N_NODES*MC*C*2;
  unsigned short* qb = (unsigned short*)wsb; wsb += (size_t)N_NODES*512*2;
  unsigned short* kb = (unsigned short*)wsb; wsb += (size_t)N_NODES*512*2;
  float* logit = (float*)wsb;  wsb += (size_t)N_EDGES*8*4;
  float* attnb = (float*)wsb;  wsb += (size_t)N_EDGES*8*4;
  float* radb  = (float*)wsb;  wsb += (size_t)N_EDGES*RSTR*4;
  int* deg     = (int*)wsb;    wsb += (size_t)N_NODES*4;
  int* rowptr  = (int*)wsb;    wsb += (size_t)(N_NODES+1)*4;
  int* cursor  = (int*)wsb;    wsb += (size_t)N_NODES*4;
  int* elist   = (int*)wsb;    wsb += (size_t)N_EDGES*4;

  (void)hipMemsetAsync(deg, 0, N_NODES*4, stream);
  (void)hipMemsetAsync(cursor, 0, N_NODES*4, stream);
  (void)hipMemsetAsync(d_out, 0, (size_t)out_size*sizeof(float), stream);

  k_count<<<(N_EDGES+255)/256, 256, 0, stream>>>(tgtarr, deg);
  k_scan<<<1, 64, 0, stream>>>(deg, rowptr);
  k_fill<<<(N_EDGES+255)/256, 256, 0, stream>>>(tgtarr, rowptr, cursor, elist);
  k_efeat<<<N_EDGES/16, 256, 0, stream>>>(dist, We1, We2, efeat);
  k_efsum<<<N_NODES, 128, 0, stream>>>(efeat, rowptr, elist, efsum);
  k_deginit<<<(N_NODES+7)/8, 256, 0, stream>>>(efsum, Wdeg, emb, anum, x);

  for (int i=0;i<NL;i++){
    k_nodeA<<<N_NODES/4, 256, 0, stream>>>(x, ns1 + i*5*C, Wq + i*C*512, Wk + i*C*512,
                                           Wv + i*C*C, qb, kb, Vb);
    k_logits<<<(N_EDGES+3)/4, 256, 0, stream>>>(qb, kb, alpha + i*512, srcarr, tgtarr, logit);
    k_softmax<<<(N_NODES+3)/4, 256, 0, stream>>>(logit, rowptr, elist, attnb);
    k_rad<<<N_EDGES/16, 256, 0, stream>>>(efeat, Wrad + i*C*MC, radb);
    k_e1<<<N_NODES, 256, 0, stream>>>(Vb, radb, attnb, Wo + i*C*C,
                                      rowptr, elist, srcarr, x);
    k_nodeB<<<N_NODES/2, 256, 0, stream>>>(x, ns2 + i*5*C, W1 + i*C*C, W2 + i*C*C);
  }
  k_final<<<N_NODES, 128, 0, stream>>>(x, nsf, Wef1, Wef2, batch, out);
}

// Round 10
// 1378.688 us; speedup vs baseline: 3.3848x; 1.0852x over previous
//
#include <hip/hip_runtime.h>
#include <hip/hip_bf16.h>

#define N_NODES 2500
#define N_EDGES 50000
#define C 128
#define MC 19
#define RSTR 20
#define NL 4
#define NB 600
#define GW 20

__device__ __forceinline__ float silu(float v){ return v / (1.f + expf(-v)); }
__device__ __forceinline__ int l_of_m(int m){
  return (m==0)?0 : (m<4)?1 : (m<9)?2 : (m<14)?3 : 4;
}
__device__ __forceinline__ unsigned pack2(float a, float b){
  __hip_bfloat162 h2;
  h2.x = __float2bfloat16(a);
  h2.y = __float2bfloat16(b);
  return *(unsigned*)&h2;
}
__device__ __forceinline__ float2 bf2f2(unsigned u){
  float2 r;
  r.x = __uint_as_float(u << 16);
  r.y = __uint_as_float(u & 0xffff0000u);
  return r;
}

// ---------------- CSR build ----------------
__global__ void k_count(const int* tgt, int* deg){
  int e = blockIdx.x*256 + threadIdx.x;
  if (e < N_EDGES) atomicAdd(&deg[tgt[e]], 1);
}

__global__ void k_scan(const int* deg, int* rowptr){
  int lane = threadIdx.x;               // 64 threads
  const int CH = (N_NODES + 63)/64;     // 40
  int base = lane*CH;
  int s = 0;
  for (int i=0;i<CH;i++){ int idx=base+i; if (idx<N_NODES) s += deg[idx]; }
  int inc = s;
  for (int d=1; d<64; d<<=1){
    int v = __shfl_up(inc, d, 64);
    if (lane >= d) inc += v;
  }
  int run = inc - s;                    // exclusive prefix
  for (int i=0;i<CH;i++){
    int idx = base+i;
    if (idx < N_NODES){ rowptr[idx] = run; run += deg[idx]; }
  }
  if (lane == 63) rowptr[N_NODES] = run;
}

__global__ void k_fill(const int* tgt, const int* rowptr, int* cursor, int* elist){
  int e = blockIdx.x*256 + threadIdx.x;
  if (e < N_EDGES){
    int n = tgt[e];
    int pos = atomicAdd(&cursor[n], 1);
    elist[rowptr[n] + pos] = e;
  }
}

// ---------------- edge features: 16 edges/block, coalesced both stages ----------------
__global__ __launch_bounds__(256) void k_efeat(const float* __restrict__ dist, const float* __restrict__ We1,
                                               const float* __restrict__ We2, float* __restrict__ efeat){
  __shared__ float gbuf[16][44];
  __shared__ __align__(16) float t1[16*132];
  __shared__ float dsh[16];
  __shared__ int j0s[16];
  __shared__ int cns[16];
  int t = threadIdx.x;
  int e0 = blockIdx.x*16;
  const float delta = 12.0f/599.0f;
  const float coeff = -0.5f/((2.0f*delta)*(2.0f*delta));
  if (t < 16){
    float d = dist[e0+t];
    int jc = (int)floorf(d/delta + 0.5f);
    int j0 = jc-GW; if (j0<0) j0=0;
    int j1 = jc+GW; if (j1>NB-1) j1=NB-1;
    dsh[t]=d; j0s[t]=j0; cns[t]=j1-j0+1;
  }
  __syncthreads();
  for (int q=t; q<16*41; q+=256){
    int el = q/41, w = q - el*41;
    float g = 0.f;
    if (w < cns[el]){
      float off = (float)(j0s[el]+w)*delta;
      float dd = dsh[el]-off;
      g = expf(coeff*dd*dd);
    }
    gbuf[el][w] = g;
  }
  __syncthreads();
  {
    int elb = t>>5, c4 = (t&31)*4;
    #pragma unroll
    for (int half=0; half<2; ++half){
      int el = elb + 8*half;
      int j0 = j0s[el];
      float a0=0.f,a1=0.f,a2=0.f,a3=0.f;
      for (int w=0; w<41; ++w){
        float g = gbuf[el][w];
        int row = j0+w; if (row > NB-1) row = NB-1;
        float4 wv = *(const float4*)&We1[(size_t)row*C + c4];
        a0 += g*wv.x; a1 += g*wv.y; a2 += g*wv.z; a3 += g*wv.w;
      }
      float4 st; st.x=silu(a0); st.y=silu(a1); st.z=silu(a2); st.w=silu(a3);
      *(float4*)&t1[el*132 + c4] = st;
    }
  }
  __syncthreads();
  {
    int grp = t>>6;
    int c2 = (t&63)*2;
    float acc[4][2];
    #pragma unroll
    for (int i=0;i<4;i++){ acc[i][0]=0.f; acc[i][1]=0.f; }
    for (int cc=0; cc<C; cc+=4){
      float2 w0 = *(const float2*)&We2[(cc+0)*C + c2];
      float2 w1 = *(const float2*)&We2[(cc+1)*C + c2];
      float2 w2 = *(const float2*)&We2[(cc+2)*C + c2];
      float2 w3 = *(const float2*)&We2[(cc+3)*C + c2];
      #pragma unroll
      for (int i=0;i<4;i++){
        int el = grp*4 + i;
        float4 a4 = *(const float4*)&t1[el*132 + cc];
        acc[i][0] += a4.x*w0.x + a4.y*w1.x + a4.z*w2.x + a4.w*w3.x;
        acc[i][1] += a4.x*w0.y + a4.y*w1.y + a4.z*w2.y + a4.w*w3.y;
      }
    }
    #pragma unroll
    for (int i=0;i<4;i++){
      int el = grp*4 + i;
      float2 st; st.x = silu(acc[i][0]); st.y = silu(acc[i][1]);
      *(float2*)&efeat[(size_t)(e0+el)*C + c2] = st;
    }
  }
}

__global__ void k_efsum(const float* efeat, const int* rowptr, const int* elist, float* efsum){
  int n = blockIdx.x; int t = threadIdx.x; // 128 threads
  float acc = 0.f;
  int beg = rowptr[n], end = rowptr[n+1];
  for (int i=beg;i<end;i++)
    acc += efeat[elist[i]*C + t];
  efsum[n*C + t] = acc;
}

// ---------------- deg-init: 8 nodes/block ----------------
__global__ __launch_bounds__(256) void k_deginit(const float* __restrict__ efsum, const float* __restrict__ Wdeg,
        const float* __restrict__ emb, const int* __restrict__ anum, float* __restrict__ x){
  __shared__ __align__(16) float efT[C][8];
  int t = threadIdx.x;
  int n0 = blockIdx.x*8;
  for (int q=t; q<8*C; q+=256){
    int nd=q>>7, cc=q&127;
    int n=n0+nd;
    efT[cc][nd] = (n<N_NODES)? efsum[n*C+cc] : 0.f;
  }
  __syncthreads();
  const float inv_avg = 1.0f/23.395238876342773f;
  #pragma unroll
  for (int grp=0; grp<5; ++grp){
    int o = grp*512 + t*2;
    if (o < MC*C){
      float a0[8], a1[8];
      #pragma unroll
      for (int i=0;i<8;i++){ a0[i]=0.f; a1[i]=0.f; }
      for (int cc=0; cc<C; ++cc){
        float2 w = *(const float2*)&Wdeg[(size_t)cc*(MC*C)+o];
        float4 e0 = *(const float4*)&efT[cc][0];
        float4 e1 = *(const float4*)&efT[cc][4];
        a0[0]+=e0.x*w.x; a1[0]+=e0.x*w.y;
        a0[1]+=e0.y*w.x; a1[1]+=e0.y*w.y;
        a0[2]+=e0.z*w.x; a1[2]+=e0.z*w.y;
        a0[3]+=e0.w*w.x; a1[3]+=e0.w*w.y;
        a0[4]+=e1.x*w.x; a1[4]+=e1.x*w.y;
        a0[5]+=e1.y*w.x; a1[5]+=e1.y*w.y;
        a0[6]+=e1.z*w.x; a1[6]+=e1.z*w.y;
        a0[7]+=e1.w*w.x; a1[7]+=e1.w*w.y;
      }
      #pragma unroll
      for (int nd=0; nd<8; ++nd){
        int n = n0+nd;
        if (n < N_NODES){
          float v0 = a0[nd]*inv_avg, v1 = a1[nd]*inv_avg;
          if (o < C){ int an=anum[n]; v0 += emb[an*C+o]; v1 += emb[an*C+o+1]; }
          float2 st; st.x=v0; st.y=v1;
          *(float2*)&x[(size_t)n*MC*C + o] = st;
        }
      }
    }
  }
}

// ---------------- fused: rmsnorm1 + QK + V, 4 nodes/block; qb/kb/V stored bf16 ----------------
__global__ __launch_bounds__(256) void k_nodeA(const float* __restrict__ x, const float* __restrict__ scale,
        const float* __restrict__ Wq, const float* __restrict__ Wk, const float* __restrict__ Wv,
        unsigned short* __restrict__ qb, unsigned short* __restrict__ kb, unsigned short* __restrict__ V){
  __shared__ __align__(16) float xs[4*MC*C];   // 38912 B
  int t = threadIdx.x;
  int n0 = blockIdx.x*4;
  {
    int ng = t>>6, lane = t&63;
    int n = n0+ng;
    float2 xv[MC];
    float pl[5]={0.f,0.f,0.f,0.f,0.f};
    #pragma unroll
    for (int m=0;m<MC;m++){
      float2 v = *(const float2*)&x[(size_t)n*MC*C + m*C + lane*2];
      xv[m]=v;
      pl[l_of_m(m)] += v.x*v.x + v.y*v.y;
    }
    #pragma unroll
    for (int l=0;l<5;l++){
      float r = pl[l];
      #pragma unroll
      for (int d=32; d>0; d>>=1) r += __shfl_xor(r, d, 64);
      pl[l]=r;
    }
    const float dens[5] = {128.f,384.f,640.f,896.f,1152.f};
    float inv[5];
    #pragma unroll
    for (int l=0;l<5;l++) inv[l] = 1.0f/sqrtf(pl[l]/dens[l] + 1e-8f);
    #pragma unroll
    for (int m=0;m<MC;m++){
      int l = l_of_m(m);
      float2 sc = *(const float2*)&scale[l*C + lane*2];
      float2 st; st.x = xv[m].x*inv[l]*sc.x; st.y = xv[m].y*inv[l]*sc.y;
      *(float2*)&xs[ng*MC*C + m*C + lane*2] = st;
    }
  }
  __syncthreads();
  // QK: thread owns o,o+1 for all 4 nodes
  {
    int o = t*2;
    float aq[4][2], ak[4][2];
    #pragma unroll
    for (int nd=0; nd<4; ++nd){ aq[nd][0]=aq[nd][1]=ak[nd][0]=ak[nd][1]=0.f; }
    for (int cc=0; cc<C; cc+=4){
      float2 q0 = *(const float2*)&Wq[(cc+0)*512 + o];
      float2 q1 = *(const float2*)&Wq[(cc+1)*512 + o];
      float2 q2 = *(const float2*)&Wq[(cc+2)*512 + o];
      float2 q3 = *(const float2*)&Wq[(cc+3)*512 + o];
      float2 k0 = *(const float2*)&Wk[(cc+0)*512 + o];
      float2 k1 = *(const float2*)&Wk[(cc+1)*512 + o];
      float2 k2 = *(const float2*)&Wk[(cc+2)*512 + o];
      float2 k3 = *(const float2*)&Wk[(cc+3)*512 + o];
      #pragma unroll
      for (int nd=0; nd<4; ++nd){
        float4 s4 = *(const float4*)&xs[nd*MC*C + cc];
        aq[nd][0] += s4.x*q0.x + s4.y*q1.x + s4.z*q2.x + s4.w*q3.x;
        aq[nd][1] += s4.x*q0.y + s4.y*q1.y + s4.z*q2.y + s4.w*q3.y;
        ak[nd][0] += s4.x*k0.x + s4.y*k1.x + s4.z*k2.x + s4.w*k3.x;
        ak[nd][1] += s4.x*k0.y + s4.y*k1.y + s4.z*k2.y + s4.w*k3.y;
      }
    }
    #pragma unroll
    for (int nd=0; nd<4; ++nd){
      *(unsigned*)&qb[(size_t)(n0+nd)*512 + o] = pack2(aq[nd][0], aq[nd][1]);
      *(unsigned*)&kb[(size_t)(n0+nd)*512 + o] = pack2(ak[nd][0], ak[nd][1]);
    }
  }
  // V = xs @ Wv
  {
    int c0 = (t&63)*2, g4 = t>>6;
    float acc[4][5][2];
    #pragma unroll
    for (int nd=0; nd<4; ++nd)
      #pragma unroll
      for (int i=0;i<5;i++){ acc[nd][i][0]=0.f; acc[nd][i][1]=0.f; }
    for (int cc=0; cc<C; cc+=4){
      float2 w0 = *(const float2*)&Wv[(cc+0)*C + c0];
      float2 w1 = *(const float2*)&Wv[(cc+1)*C + c0];
      float2 w2 = *(const float2*)&Wv[(cc+2)*C + c0];
      float2 w3 = *(const float2*)&Wv[(cc+3)*C + c0];
      #pragma unroll
      for (int nd=0; nd<4; ++nd){
        #pragma unroll
        for (int i=0;i<5;i++){
          int m = g4 + 4*i;
          if (m < MC){
            float4 a4 = *(const float4*)&xs[nd*MC*C + m*C + cc];
            acc[nd][i][0] += a4.x*w0.x + a4.y*w1.x + a4.z*w2.x + a4.w*w3.x;
            acc[nd][i][1] += a4.x*w0.y + a4.y*w1.y + a4.z*w2.y + a4.w*w3.y;
          }
        }
      }
    }
    #pragma unroll
    for (int nd=0; nd<4; ++nd){
      #pragma unroll
      for (int i=0;i<5;i++){
        int m = g4 + 4*i;
        if (m < MC)
          *(unsigned*)&V[(size_t)(n0+nd)*MC*C + m*C + c0] = pack2(acc[nd][i][0], acc[nd][i][1]);
      }
    }
  }
}

// ---------------- logits: wave per edge; lane owns 8 bf16 (one dwordx4 per operand) ----------------
__global__ __launch_bounds__(256) void k_logits(const unsigned short* __restrict__ qb,
        const unsigned short* __restrict__ kb, const float* __restrict__ alpha,
        const int* __restrict__ srcarr, const int* __restrict__ tgtarr, float* __restrict__ logits){
  int wid = threadIdx.x >> 6; int lane = threadIdx.x & 63;
  int e = blockIdx.x*4 + wid;
  if (e >= N_EDGES) return;
  float al[8];
  {
    float4 a0 = *(const float4*)&alpha[lane*8];
    float4 a1 = *(const float4*)&alpha[lane*8+4];
    al[0]=a0.x; al[1]=a0.y; al[2]=a0.z; al[3]=a0.w;
    al[4]=a1.x; al[5]=a1.y; al[6]=a1.z; al[7]=a1.w;
  }
  int s = srcarr[e], tg = tgtarr[e];
  int4 qv = *(const int4*)&qb[(size_t)tg*512 + lane*8];
  int4 kv = *(const int4*)&kb[(size_t)s*512 + lane*8];
  unsigned qu[4] = {(unsigned)qv.x,(unsigned)qv.y,(unsigned)qv.z,(unsigned)qv.w};
  unsigned ku[4] = {(unsigned)kv.x,(unsigned)kv.y,(unsigned)kv.z,(unsigned)kv.w};
  float acc = 0.f;
  #pragma unroll
  for (int j=0;j<4;j++){
    float2 q2 = bf2f2(qu[j]);
    float2 k2 = bf2f2(ku[j]);
    acc += silu(q2.x+k2.x)*al[2*j]   + silu(q2.y+k2.y)*al[2*j+1];
  }
  #pragma unroll
  for (int d=1; d<8; d<<=1) acc += __shfl_down(acc, d, 64);
  if ((lane&7)==0) logits[e*8 + (lane>>3)] = acc * 0.125f;
}

// one wave per node; lane = (edge-chunk<<3) | h
__global__ __launch_bounds__(256) void k_softmax(const float* logits, const int* rowptr, const int* elist, float* attnb){
  int n = blockIdx.x*4 + (threadIdx.x>>6);
  if (n >= N_NODES) return;
  int lane = threadIdx.x & 63;
  int h = lane & 7, ec = lane >> 3;
  int beg = rowptr[n], end = rowptr[n+1];
  float mx = -1e30f;
  for (int i=beg+ec; i<end; i+=8) mx = fmaxf(mx, logits[elist[i]*8+h]);
  #pragma unroll
  for (int dd=8; dd<64; dd<<=1) mx = fmaxf(mx, __shfl_xor(mx, dd, 64));
  float sum = 0.f;
  for (int i=beg+ec; i<end; i+=8) sum += expf(logits[elist[i]*8+h] - mx);
  #pragma unroll
  for (int dd=8; dd<64; dd<<=1) sum += __shfl_xor(sum, dd, 64);
  float inv = 1.0f/(sum + 1e-9f);
  for (int i=beg+ec; i<end; i+=8){
    int e = elist[i];
    attnb[e*8 + h] = expf(logits[e*8+h]-mx)*inv;
  }
}

// rad: 16 edges/block
__global__ __launch_bounds__(256) void k_rad(const float* efeat, const float* Wrad, float* radb){
  __shared__ float wsh[C*RSTR];
  __shared__ float esh[16][132];
  int t = threadIdx.x;
  for (int q=t; q<C*MC; q+=256){ int cc=q/MC, m=q-cc*MC; wsh[cc*RSTR+m] = Wrad[q]; }
  int e0 = blockIdx.x*16;
  for (int q=t; q<16*C; q+=256) esh[q>>7][q&127] = efeat[(size_t)(e0+(q>>7))*C + (q&127)];
  __syncthreads();
  for (int q=t; q<16*MC; q+=256){
    int el = q/MC, m = q-el*MC;
    float acc = 0.f;
    #pragma unroll 4
    for (int cc=0; cc<C; ++cc) acc += esh[el][cc]*wsh[cc*RSTR+m];
    radb[(size_t)(e0+el)*RSTR + m] = silu(acc);
  }
}

// msum[n,m,d] = sum_e attn[e,h(d)]*rad[e,m]*V[src_e,m,d]  (V bf16)
// wave w handles edges beg+w, beg+w+4, ... with the FULL m range; 4 LDS partials; then Wo epilogue
__global__ __launch_bounds__(256) void k_e1(const unsigned short* __restrict__ V, const float* __restrict__ radb,
        const float* __restrict__ attnb, const float* __restrict__ Wo,
        const int* __restrict__ rowptr, const int* __restrict__ elist, const int* __restrict__ srcarr,
        float* __restrict__ x){
  __shared__ __align__(16) float part[4][MC*C];   // 38912 B; part[0] doubles as msum
  int n = blockIdx.x;
  int t = threadIdx.x;
  int w = t>>6, lane = t&63;
  int c0 = lane*2;
  int h = c0 >> 4;
  float acc[MC][2];
  #pragma unroll
  for (int m=0;m<MC;m++){ acc[m][0]=0.f; acc[m][1]=0.f; }
  int beg = rowptr[n], end = rowptr[n+1];
  for (int idx=beg+w; idx<end; idx+=4){
    int e = elist[idx];
    int s = srcarr[e];
    float a = attnb[e*8 + h];
    const unsigned short* vr = V + (size_t)s*(MC*C) + c0;
    const float* rr = radb + (size_t)e*RSTR;
    float4 r0 = *(const float4*)&rr[0];
    float4 r1 = *(const float4*)&rr[4];
    float4 r2 = *(const float4*)&rr[8];
    float4 r3 = *(const float4*)&rr[12];
    float4 r4 = *(const float4*)&rr[16];
    float rm[20] = {r0.x,r0.y,r0.z,r0.w, r1.x,r1.y,r1.z,r1.w,
                    r2.x,r2.y,r2.z,r2.w, r3.x,r3.y,r3.z,r3.w,
                    r4.x,r4.y,r4.z,r4.w};
    #pragma unroll
    for (int m=0;m<MC;m++){
      float ar = a * rm[m];
      float2 v2 = bf2f2(*(const unsigned*)&vr[m*C]);
      acc[m][0] += ar*v2.x;
      acc[m][1] += ar*v2.y;
    }
  }
  #pragma unroll
  for (int m=0;m<MC;m++){
    part[w][m*C+c0]   = acc[m][0];
    part[w][m*C+c0+1] = acc[m][1];
  }
  __syncthreads();
  for (int q=t; q<MC*C; q+=256)
    part[0][q] = part[0][q] + part[1][q] + part[2][q] + part[3][q];
  __syncthreads();
  // x[n] += part[0] @ Wo
  int c0e = (t&63)*2; int g4 = t>>6;
  float acc2[5][2];
  #pragma unroll
  for (int i=0;i<5;i++){ acc2[i][0]=0.f; acc2[i][1]=0.f; }
  for (int d=0; d<C; d+=4){
    float2 w0 = *(const float2*)&Wo[(d+0)*C + c0e];
    float2 w1 = *(const float2*)&Wo[(d+1)*C + c0e];
    float2 w2 = *(const float2*)&Wo[(d+2)*C + c0e];
    float2 w3 = *(const float2*)&Wo[(d+3)*C + c0e];
    #pragma unroll
    for (int i=0;i<5;i++){
      int m = g4 + 4*i;
      if (m < MC){
        float4 m4 = *(const float4*)&part[0][m*C + d];
        acc2[i][0] += m4.x*w0.x + m4.y*w1.x + m4.z*w2.x + m4.w*w3.x;
        acc2[i][1] += m4.x*w0.y + m4.y*w1.y + m4.z*w2.y + m4.w*w3.y;
      }
    }
  }
  #pragma unroll
  for (int i=0;i<5;i++){
    int m = g4 + 4*i;
    if (m < MC){
      size_t off = (size_t)n*MC*C + m*C + c0e;
      x[off]   += acc2[i][0];
      x[off+1] += acc2[i][1];
    }
  }
}

// ---------------- fused: rmsnorm2 + gated FFN, 2 nodes/block ----------------
// R=4 cols/thread (LDS:VALU balanced at 0.5 B/FLOP); hb reuses xs buffer (LDS ~20.5 KB)
__global__ __launch_bounds__(256) void k_nodeB(float* __restrict__ x, const float* __restrict__ scale,
        const float* __restrict__ W1, const float* __restrict__ W2){
  __shared__ __align__(16) float xs[2*MC*C];   // 19456 B; reused for gated hb
  __shared__ float gate[2*C];
  __shared__ float ssum[2][5];
  int t = threadIdx.x;
  int n0 = blockIdx.x*2;
  int ng = t>>7, c = t&127;
  int n = n0+ng;
  if (t < 10) ssum[t/5][t%5] = 0.f;
  __syncthreads();
  {
    float vals[MC];
    float pl[5]={0.f,0.f,0.f,0.f,0.f};
    #pragma unroll
    for (int m=0;m<MC;m++){
      float v = x[(size_t)n*MC*C + m*C + c];
      vals[m]=v;
      pl[l_of_m(m)] += v*v;
    }
    #pragma unroll
    for (int l=0;l<5;l++){
      float r = pl[l];
      #pragma unroll
      for (int d=32; d>0; d>>=1) r += __shfl_down(r, d, 64);
      if ((t&63)==0) atomicAdd(&ssum[ng][l], r);
    }
    __syncthreads();
    const float dens[5] = {128.f,384.f,640.f,896.f,1152.f};
    float inv[5];
    #pragma unroll
    for (int l=0;l<5;l++) inv[l] = 1.0f/sqrtf(ssum[ng][l]/dens[l] + 1e-8f);
    #pragma unroll
    for (int m=0;m<MC;m++){
      int l = l_of_m(m);
      xs[ng*MC*C + m*C + c] = vals[m]*inv[l]*scale[l*C + c];
    }
  }
  __syncthreads();
  int c4 = (t&31)*4, mg = t>>5;   // mg in 0..7 ; m = mg + 8*i
  // GEMM1: acc = xs @ W1 (registers)
  float acc[2][3][4];
  #pragma unroll
  for (int nd=0; nd<2; ++nd)
    #pragma unroll
    for (int i=0;i<3;i++)
      #pragma unroll
      for (int j=0;j<4;j++) acc[nd][i][j]=0.f;
  for (int cc=0; cc<C; cc+=4){
    float4 w0 = *(const float4*)&W1[(cc+0)*C + c4];
    float4 w1 = *(const float4*)&W1[(cc+1)*C + c4];
    float4 w2 = *(const float4*)&W1[(cc+2)*C + c4];
    float4 w3 = *(const float4*)&W1[(cc+3)*C + c4];
    #pragma unroll
    for (int nd=0; nd<2; ++nd){
      #pragma unroll
      for (int i=0;i<3;i++){
        int m = mg + 8*i;
        if (m < MC){
          float4 a = *(const float4*)&xs[nd*MC*C + m*C + cc];
          acc[nd][i][0] += a.x*w0.x + a.y*w1.x + a.z*w2.x + a.w*w3.x;
          acc[nd][i][1] += a.x*w0.y + a.y*w1.y + a.z*w2.y + a.w*w3.y;
          acc[nd][i][2] += a.x*w0.z + a.y*w1.z + a.z*w2.z + a.w*w3.z;
          acc[nd][i][3] += a.x*w0.w + a.y*w1.w + a.z*w2.w + a.w*w3.w;
        }
      }
    }
  }
  __syncthreads();          // all xs reads complete
  // write hb into xs buffer
  #pragma unroll
  for (int nd=0; nd<2; ++nd)
    #pragma unroll
    for (int i=0;i<3;i++){
      int m = mg + 8*i;
      if (m < MC){
        float4 st; st.x=acc[nd][i][0]; st.y=acc[nd][i][1]; st.z=acc[nd][i][2]; st.w=acc[nd][i][3];
        *(float4*)&xs[nd*MC*C + m*C + c4] = st;
      }
    }
  __syncthreads();
  {
    int nd = t>>7, cg = t&127;
    gate[nd*C+cg] = silu(xs[nd*MC*C + cg]);
  }
  __syncthreads();
  for (int q=t; q<2*MC*C; q+=256){
    int nd2 = (q >= MC*C) ? 1 : 0;
    xs[q] *= gate[nd2*C + (q&127)];
  }
  __syncthreads();
  // GEMM2: x += xs(gated hb) @ W2
  float acc2[2][3][4];
  #pragma unroll
  for (int nd=0; nd<2; ++nd)
    #pragma unroll
    for (int i=0;i<3;i++)
      #pragma unroll
      for (int j=0;j<4;j++) acc2[nd][i][j]=0.f;
  for (int f=0; f<C; f+=4){
    float4 w0 = *(const float4*)&W2[(f+0)*C + c4];
    float4 w1 = *(const float4*)&W2[(f+1)*C + c4];
    float4 w2 = *(const float4*)&W2[(f+2)*C + c4];
    float4 w3 = *(const float4*)&W2[(f+3)*C + c4];
    #pragma unroll
    for (int nd=0; nd<2; ++nd){
      #pragma unroll
      for (int i=0;i<3;i++){
        int m = mg + 8*i;
        if (m < MC){
          float4 a = *(const float4*)&xs[nd*MC*C + m*C + f];
          acc2[nd][i][0] += a.x*w0.x + a.y*w1.x + a.z*w2.x + a.w*w3.x;
          acc2[nd][i][1] += a.x*w0.y + a.y*w1.y + a.z*w2.y + a.w*w3.y;
          acc2[nd][i][2] += a.x*w0.z + a.y*w1.z + a.z*w2.z + a.w*w3.z;
          acc2[nd][i][3] += a.x*w0.w + a.y*w1.w + a.z*w2.w + a.w*w3.w;
        }
      }
    }
  }
  #pragma unroll
  for (int nd=0; nd<2; ++nd)
    #pragma unroll
    for (int i=0;i<3;i++){
      int m = mg + 8*i;
      if (m < MC){
        size_t off = (size_t)(n0+nd)*MC*C + m*C + c4;
        float4 old = *(float4*)&x[off];
        old.x += acc2[nd][i][0];
        old.y += acc2[nd][i][1];
        old.z += acc2[nd][i][2];
        old.w += acc2[nd][i][3];
        *(float4*)&x[off] = old;
      }
    }
}

// ---------------- final head ----------------
__global__ __launch_bounds__(128) void k_final(const float* x, const float* nsf, const float* Wef1,
        const float* Wef2, const int* batch, float* out){
  __shared__ float sl[C];
  __shared__ float red[2];
  __shared__ float red2[2];
  int n = blockIdx.x; int t = threadIdx.x;
  float v = x[(size_t)n*MC*C + t];
  float sq = v*v;
  for (int d=32; d>0; d>>=1) sq += __shfl_down(sq, d, 64);
  if ((t&63)==0) red[t>>6] = sq;
  __syncthreads();
  float ms = (red[0]+red[1]) * (1.0f/128.f);
  float inv = 1.0f/sqrtf(ms + 1e-8f);
  sl[t] = v*inv*nsf[t];
  __syncthreads();
  float acc = 0.f;
  for (int cc=0; cc<C; ++cc) acc += sl[cc]*Wef1[cc*C + t];
  float val = acc*silu(acc)*Wef2[t];
  for (int d=32; d>0; d>>=1) val += __shfl_down(val, d, 64);
  if ((t&63)==0) red2[t>>6] = val;
  __syncthreads();
  if (t==0){
    float ne = red2[0]+red2[1];
    atomicAdd(&out[batch[n]], ne * (1.0f/77.81317f));
  }
}

extern "C" void kernel_launch(void* const* d_in, const int* in_sizes, int n_in,
                              void* d_out, int out_size, void* d_ws, size_t ws_size,
                              hipStream_t stream){
  (void)in_sizes; (void)n_in; (void)ws_size;
  const int*   anum  = (const int*)d_in[0];
  const int*   eidx  = (const int*)d_in[1];
  const float* dist  = (const float*)d_in[2];
  const int*   batch = (const int*)d_in[3];
  const float* emb   = (const float*)d_in[4];
  const float* We1   = (const float*)d_in[5];
  const float* We2   = (const float*)d_in[6];
  const float* Wdeg  = (const float*)d_in[7];
  const float* ns1   = (const float*)d_in[8];
  const float* ns2   = (const float*)d_in[9];
  const float* Wq    = (const float*)d_in[10];
  const float* Wk    = (const float*)d_in[11];
  const float* alpha = (const float*)d_in[12];
  const float* Wv    = (const float*)d_in[13];
  const float* Wrad  = (const float*)d_in[14];
  const float* Wo    = (const float*)d_in[15];
  const float* W1    = (const float*)d_in[16];
  const float* W2    = (const float*)d_in[17];
  const float* nsf   = (const float*)d_in[18];
  const float* Wef1  = (const float*)d_in[19];
  const float* Wef2  = (const float*)d_in[20];
  float* out = (float*)d_out;

  const int* srcarr = eidx;
  const int* tgtarr = eidx + N_EDGES;

  char* wsb = (char*)d_ws;
  float* efeat = (float*)wsb;  wsb += (size_t)N_EDGES*C*4;
  float* efsum = (float*)wsb;  wsb += (size_t)N_NODES*C*4;
  float* x     = (float*)wsb;  wsb += (size_t)N_NODES*MC*C*4;
  unsigned short* Vb = (unsigned short*)wsb; wsb += (size_t)N_NODES*MC*C*2;
  unsigned short* qb = (unsigned short*)wsb; wsb += (size_t)N_NODES*512*2;
  unsigned short* kb = (unsigned short*)wsb; wsb += (size_t)N_NODES*512*2;
  float* logit = (float*)wsb;  wsb += (size_t)N_EDGES*8*4;
  float* attnb = (float*)wsb;  wsb += (size_t)N_EDGES*8*4;
  float* radb  = (float*)wsb;  wsb += (size_t)N_EDGES*RSTR*4;
  int* deg     = (int*)wsb;    wsb += (size_t)N_NODES*4;
  int* rowptr  = (int*)wsb;    wsb += (size_t)(N_NODES+1)*4;
  int* cursor  = (int*)wsb;    wsb += (size_t)N_NODES*4;
  int* elist   = (int*)wsb;    wsb += (size_t)N_EDGES*4;

  (void)hipMemsetAsync(deg, 0, N_NODES*4, stream);
  (void)hipMemsetAsync(cursor, 0, N_NODES*4, stream);
  (void)hipMemsetAsync(d_out, 0, (size_t)out_size*sizeof(float), stream);

  k_count<<<(N_EDGES+255)/256, 256, 0, stream>>>(tgtarr, deg);
  k_scan<<<1, 64, 0, stream>>>(deg, rowptr);
  k_fill<<<(N_EDGES+255)/256, 256, 0, stream>>>(tgtarr, rowptr, cursor, elist);
  k_efeat<<<N_EDGES/16, 256, 0, stream>>>(dist, We1, We2, efeat);
  k_efsum<<<N_NODES, 128, 0, stream>>>(efeat, rowptr, elist, efsum);
  k_deginit<<<(N_NODES+7)/8, 256, 0, stream>>>(efsum, Wdeg, emb, anum, x);

  for (int i=0;i<NL;i++){
    k_nodeA<<<N_NODES/4, 256, 0, stream>>>(x, ns1 + i*5*C, Wq + i*C*512, Wk + i*C*512,
                                           Wv + i*C*C, qb, kb, Vb);
    k_logits<<<(N_EDGES+3)/4, 256, 0, stream>>>(qb, kb, alpha + i*512, srcarr, tgtarr, logit);
    k_softmax<<<(N_NODES+3)/4, 256, 0, stream>>>(logit, rowptr, elist, attnb);
    k_rad<<<N_EDGES/16, 256, 0, stream>>>(efeat, Wrad + i*C*MC, radb);
    k_e1<<<N_NODES, 256, 0, stream>>>(Vb, radb, attnb, Wo + i*C*C,
                                      rowptr, elist, srcarr, x);
    k_nodeB<<<N_NODES/2, 256, 0, stream>>>(x, ns2 + i*5*C, W1 + i*C*C, W2 + i*C*C);
  }
  k_final<<<N_NODES, 128, 0, stream>>>(x, nsf, Wef1, Wef2, batch, out);
}

// Round 11
// 1331.438 us; speedup vs baseline: 3.5049x; 1.0355x over previous
//
#include <hip/hip_runtime.h>
#include <hip/hip_bf16.h>

#define N_NODES 2500
#define N_EDGES 50000
#define C 128
#define MC 19
#define RSTR 20
#define NL 4
#define NB 600
#define GW 12
#define NTAP (2*GW+1)

__device__ __forceinline__ float silu(float v){ return v / (1.f + expf(-v)); }
__device__ __forceinline__ int l_of_m(int m){
  return (m==0)?0 : (m<4)?1 : (m<9)?2 : (m<14)?3 : 4;
}
__device__ __forceinline__ unsigned pack2(float a, float b){
  __hip_bfloat162 h2;
  h2.x = __float2bfloat16(a);
  h2.y = __float2bfloat16(b);
  return *(unsigned*)&h2;
}
__device__ __forceinline__ float2 bf2f2(unsigned u){
  float2 r;
  r.x = __uint_as_float(u << 16);
  r.y = __uint_as_float(u & 0xffff0000u);
  return r;
}

// ---------------- CSR build ----------------
__global__ void k_count(const int* tgt, int* deg){
  int e = blockIdx.x*256 + threadIdx.x;
  if (e < N_EDGES) atomicAdd(&deg[tgt[e]], 1);
}

__global__ void k_scan(const int* deg, int* rowptr){
  int lane = threadIdx.x;               // 64 threads
  const int CH = (N_NODES + 63)/64;     // 40
  int base = lane*CH;
  int s = 0;
  for (int i=0;i<CH;i++){ int idx=base+i; if (idx<N_NODES) s += deg[idx]; }
  int inc = s;
  for (int d=1; d<64; d<<=1){
    int v = __shfl_up(inc, d, 64);
    if (lane >= d) inc += v;
  }
  int run = inc - s;                    // exclusive prefix
  for (int i=0;i<CH;i++){
    int idx = base+i;
    if (idx < N_NODES){ rowptr[idx] = run; run += deg[idx]; }
  }
  if (lane == 63) rowptr[N_NODES] = run;
}

__global__ void k_fill(const int* tgt, const int* rowptr, int* cursor, int* elist){
  int e = blockIdx.x*256 + threadIdx.x;
  if (e < N_EDGES){
    int n = tgt[e];
    int pos = atomicAdd(&cursor[n], 1);
    elist[rowptr[n] + pos] = e;
  }
}

// ---------------- edge features: 16 edges/block; +-12 taps (tail < 2e-8) ----------------
__global__ __launch_bounds__(256) void k_efeat(const float* __restrict__ dist, const float* __restrict__ We1,
                                               const float* __restrict__ We2, float* __restrict__ efeat){
  __shared__ float gbuf[16][NTAP+3];
  __shared__ __align__(16) float t1[16*132];
  __shared__ float dsh[16];
  __shared__ int j0s[16];
  __shared__ int cns[16];
  int t = threadIdx.x;
  int e0 = blockIdx.x*16;
  const float delta = 12.0f/599.0f;
  const float coeff = -0.5f/((2.0f*delta)*(2.0f*delta));
  if (t < 16){
    float d = dist[e0+t];
    int jc = (int)floorf(d/delta + 0.5f);
    int j0 = jc-GW; if (j0<0) j0=0;
    int j1 = jc+GW; if (j1>NB-1) j1=NB-1;
    dsh[t]=d; j0s[t]=j0; cns[t]=j1-j0+1;
  }
  __syncthreads();
  for (int q=t; q<16*NTAP; q+=256){
    int el = q/NTAP, w = q - el*NTAP;
    float g = 0.f;
    if (w < cns[el]){
      float off = (float)(j0s[el]+w)*delta;
      float dd = dsh[el]-off;
      g = expf(coeff*dd*dd);
    }
    gbuf[el][w] = g;
  }
  __syncthreads();
  {
    int elb = t>>5, c4 = (t&31)*4;
    #pragma unroll
    for (int half=0; half<2; ++half){
      int el = elb + 8*half;
      int j0 = j0s[el];
      float a0=0.f,a1=0.f,a2=0.f,a3=0.f;
      for (int w=0; w<NTAP; ++w){
        float g = gbuf[el][w];
        int row = j0+w; if (row > NB-1) row = NB-1;
        float4 wv = *(const float4*)&We1[(size_t)row*C + c4];
        a0 += g*wv.x; a1 += g*wv.y; a2 += g*wv.z; a3 += g*wv.w;
      }
      float4 st; st.x=silu(a0); st.y=silu(a1); st.z=silu(a2); st.w=silu(a3);
      *(float4*)&t1[el*132 + c4] = st;
    }
  }
  __syncthreads();
  {
    int grp = t>>6;
    int c2 = (t&63)*2;
    float acc[4][2];
    #pragma unroll
    for (int i=0;i<4;i++){ acc[i][0]=0.f; acc[i][1]=0.f; }
    for (int cc=0; cc<C; cc+=4){
      float2 w0 = *(const float2*)&We2[(cc+0)*C + c2];
      float2 w1 = *(const float2*)&We2[(cc+1)*C + c2];
      float2 w2 = *(const float2*)&We2[(cc+2)*C + c2];
      float2 w3 = *(const float2*)&We2[(cc+3)*C + c2];
      #pragma unroll
      for (int i=0;i<4;i++){
        int el = grp*4 + i;
        float4 a4 = *(const float4*)&t1[el*132 + cc];
        acc[i][0] += a4.x*w0.x + a4.y*w1.x + a4.z*w2.x + a4.w*w3.x;
        acc[i][1] += a4.x*w0.y + a4.y*w1.y + a4.z*w2.y + a4.w*w3.y;
      }
    }
    #pragma unroll
    for (int i=0;i<4;i++){
      int el = grp*4 + i;
      float2 st; st.x = silu(acc[i][0]); st.y = silu(acc[i][1]);
      *(float2*)&efeat[(size_t)(e0+el)*C + c2] = st;
    }
  }
}

// efsumT[c][n] (transposed for k_deginit's coalesced/conflict-free consumption)
__global__ void k_efsum(const float* efeat, const int* rowptr, const int* elist, float* efsumT){
  int n = blockIdx.x; int t = threadIdx.x; // 128 threads
  float acc = 0.f;
  int beg = rowptr[n], end = rowptr[n+1];
  for (int i=beg;i<end;i++)
    acc += efeat[elist[i]*C + t];
  efsumT[(size_t)t*N_NODES + n] = acc;
}

// ---------------- deg-init: 16 nodes/block x 5 o-groups; x = emb(m=0) + (efsum@Wdeg)/avg ----------------
__global__ __launch_bounds__(256) void k_deginit(const float* __restrict__ efsumT, const float* __restrict__ Wdeg,
        const float* __restrict__ emb, const int* __restrict__ anum, float* __restrict__ x){
  __shared__ __align__(16) float efT[C][16];
  int t = threadIdx.x;
  int n0 = blockIdx.x*16;
  int grp = blockIdx.y;
  for (int q=t; q<16*C; q+=256){
    int cc=q>>4, nd=q&15;
    int n=n0+nd;
    efT[cc][nd] = (n<N_NODES)? efsumT[(size_t)cc*N_NODES + n] : 0.f;
  }
  __syncthreads();
  const float inv_avg = 1.0f/23.395238876342773f;
  int o = grp*512 + t*2;
  if (o < MC*C){
    float a0[16], a1[16];
    #pragma unroll
    for (int i=0;i<16;i++){ a0[i]=0.f; a1[i]=0.f; }
    for (int cc=0; cc<C; ++cc){
      float2 w = *(const float2*)&Wdeg[(size_t)cc*(MC*C)+o];
      float4 e0 = *(const float4*)&efT[cc][0];
      float4 e1 = *(const float4*)&efT[cc][4];
      float4 e2 = *(const float4*)&efT[cc][8];
      float4 e3 = *(const float4*)&efT[cc][12];
      a0[0]+=e0.x*w.x; a1[0]+=e0.x*w.y;
      a0[1]+=e0.y*w.x; a1[1]+=e0.y*w.y;
      a0[2]+=e0.z*w.x; a1[2]+=e0.z*w.y;
      a0[3]+=e0.w*w.x; a1[3]+=e0.w*w.y;
      a0[4]+=e1.x*w.x; a1[4]+=e1.x*w.y;
      a0[5]+=e1.y*w.x; a1[5]+=e1.y*w.y;
      a0[6]+=e1.z*w.x; a1[6]+=e1.z*w.y;
      a0[7]+=e1.w*w.x; a1[7]+=e1.w*w.y;
      a0[8]+=e2.x*w.x; a1[8]+=e2.x*w.y;
      a0[9]+=e2.y*w.x; a1[9]+=e2.y*w.y;
      a0[10]+=e2.z*w.x; a1[10]+=e2.z*w.y;
      a0[11]+=e2.w*w.x; a1[11]+=e2.w*w.y;
      a0[12]+=e3.x*w.x; a1[12]+=e3.x*w.y;
      a0[13]+=e3.y*w.x; a1[13]+=e3.y*w.y;
      a0[14]+=e3.z*w.x; a1[14]+=e3.z*w.y;
      a0[15]+=e3.w*w.x; a1[15]+=e3.w*w.y;
    }
    #pragma unroll
    for (int nd=0; nd<16; ++nd){
      int n = n0+nd;
      if (n < N_NODES){
        float v0 = a0[nd]*inv_avg, v1 = a1[nd]*inv_avg;
        if (o < C){ int an=anum[n]; v0 += emb[an*C+o]; v1 += emb[an*C+o+1]; }
        float2 st; st.x=v0; st.y=v1;
        *(float2*)&x[(size_t)n*MC*C + o] = st;
      }
    }
  }
}

// ---------------- fused: rmsnorm1 + QK + V, 4 nodes/block; qb/kb/V stored bf16 ----------------
__global__ __launch_bounds__(256) void k_nodeA(const float* __restrict__ x, const float* __restrict__ scale,
        const float* __restrict__ Wq, const float* __restrict__ Wk, const float* __restrict__ Wv,
        unsigned short* __restrict__ qb, unsigned short* __restrict__ kb, unsigned short* __restrict__ V){
  __shared__ __align__(16) float xs[4*MC*C];   // 38912 B
  int t = threadIdx.x;
  int n0 = blockIdx.x*4;
  {
    int ng = t>>6, lane = t&63;
    int n = n0+ng;
    float2 xv[MC];
    float pl[5]={0.f,0.f,0.f,0.f,0.f};
    #pragma unroll
    for (int m=0;m<MC;m++){
      float2 v = *(const float2*)&x[(size_t)n*MC*C + m*C + lane*2];
      xv[m]=v;
      pl[l_of_m(m)] += v.x*v.x + v.y*v.y;
    }
    #pragma unroll
    for (int l=0;l<5;l++){
      float r = pl[l];
      #pragma unroll
      for (int d=32; d>0; d>>=1) r += __shfl_xor(r, d, 64);
      pl[l]=r;
    }
    const float dens[5] = {128.f,384.f,640.f,896.f,1152.f};
    float inv[5];
    #pragma unroll
    for (int l=0;l<5;l++) inv[l] = 1.0f/sqrtf(pl[l]/dens[l] + 1e-8f);
    #pragma unroll
    for (int m=0;m<MC;m++){
      int l = l_of_m(m);
      float2 sc = *(const float2*)&scale[l*C + lane*2];
      float2 st; st.x = xv[m].x*inv[l]*sc.x; st.y = xv[m].y*inv[l]*sc.y;
      *(float2*)&xs[ng*MC*C + m*C + lane*2] = st;
    }
  }
  __syncthreads();
  // QK: thread owns o,o+1 for all 4 nodes
  {
    int o = t*2;
    float aq[4][2], ak[4][2];
    #pragma unroll
    for (int nd=0; nd<4; ++nd){ aq[nd][0]=aq[nd][1]=ak[nd][0]=ak[nd][1]=0.f; }
    for (int cc=0; cc<C; cc+=4){
      float2 q0 = *(const float2*)&Wq[(cc+0)*512 + o];
      float2 q1 = *(const float2*)&Wq[(cc+1)*512 + o];
      float2 q2 = *(const float2*)&Wq[(cc+2)*512 + o];
      float2 q3 = *(const float2*)&Wq[(cc+3)*512 + o];
      float2 k0 = *(const float2*)&Wk[(cc+0)*512 + o];
      float2 k1 = *(const float2*)&Wk[(cc+1)*512 + o];
      float2 k2 = *(const float2*)&Wk[(cc+2)*512 + o];
      float2 k3 = *(const float2*)&Wk[(cc+3)*512 + o];
      #pragma unroll
      for (int nd=0; nd<4; ++nd){
        float4 s4 = *(const float4*)&xs[nd*MC*C + cc];
        aq[nd][0] += s4.x*q0.x + s4.y*q1.x + s4.z*q2.x + s4.w*q3.x;
        aq[nd][1] += s4.x*q0.y + s4.y*q1.y + s4.z*q2.y + s4.w*q3.y;
        ak[nd][0] += s4.x*k0.x + s4.y*k1.x + s4.z*k2.x + s4.w*k3.x;
        ak[nd][1] += s4.x*k0.y + s4.y*k1.y + s4.z*k2.y + s4.w*k3.y;
      }
    }
    #pragma unroll
    for (int nd=0; nd<4; ++nd){
      *(unsigned*)&qb[(size_t)(n0+nd)*512 + o] = pack2(aq[nd][0], aq[nd][1]);
      *(unsigned*)&kb[(size_t)(n0+nd)*512 + o] = pack2(ak[nd][0], ak[nd][1]);
    }
  }
  // V = xs @ Wv
  {
    int c0 = (t&63)*2, g4 = t>>6;
    float acc[4][5][2];
    #pragma unroll
    for (int nd=0; nd<4; ++nd)
      #pragma unroll
      for (int i=0;i<5;i++){ acc[nd][i][0]=0.f; acc[nd][i][1]=0.f; }
    for (int cc=0; cc<C; cc+=4){
      float2 w0 = *(const float2*)&Wv[(cc+0)*C + c0];
      float2 w1 = *(const float2*)&Wv[(cc+1)*C + c0];
      float2 w2 = *(const float2*)&Wv[(cc+2)*C + c0];
      float2 w3 = *(const float2*)&Wv[(cc+3)*C + c0];
      #pragma unroll
      for (int nd=0; nd<4; ++nd){
        #pragma unroll
        for (int i=0;i<5;i++){
          int m = g4 + 4*i;
          if (m < MC){
            float4 a4 = *(const float4*)&xs[nd*MC*C + m*C + cc];
            acc[nd][i][0] += a4.x*w0.x + a4.y*w1.x + a4.z*w2.x + a4.w*w3.x;
            acc[nd][i][1] += a4.x*w0.y + a4.y*w1.y + a4.z*w2.y + a4.w*w3.y;
          }
        }
      }
    }
    #pragma unroll
    for (int nd=0; nd<4; ++nd){
      #pragma unroll
      for (int i=0;i<5;i++){
        int m = g4 + 4*i;
        if (m < MC)
          *(unsigned*)&V[(size_t)(n0+nd)*MC*C + m*C + c0] = pack2(acc[nd][i][0], acc[nd][i][1]);
      }
    }
  }
}

// ---------------- logits: wave per edge; lane owns 8 bf16 (one dwordx4 per operand) ----------------
__global__ __launch_bounds__(256) void k_logits(const unsigned short* __restrict__ qb,
        const unsigned short* __restrict__ kb, const float* __restrict__ alpha,
        const int* __restrict__ srcarr, const int* __restrict__ tgtarr, float* __restrict__ logits){
  int wid = threadIdx.x >> 6; int lane = threadIdx.x & 63;
  int e = blockIdx.x*4 + wid;
  if (e >= N_EDGES) return;
  float al[8];
  {
    float4 a0 = *(const float4*)&alpha[lane*8];
    float4 a1 = *(const float4*)&alpha[lane*8+4];
    al[0]=a0.x; al[1]=a0.y; al[2]=a0.z; al[3]=a0.w;
    al[4]=a1.x; al[5]=a1.y; al[6]=a1.z; al[7]=a1.w;
  }
  int s = srcarr[e], tg = tgtarr[e];
  int4 qv = *(const int4*)&qb[(size_t)tg*512 + lane*8];
  int4 kv = *(const int4*)&kb[(size_t)s*512 + lane*8];
  unsigned qu[4] = {(unsigned)qv.x,(unsigned)qv.y,(unsigned)qv.z,(unsigned)qv.w};
  unsigned ku[4] = {(unsigned)kv.x,(unsigned)kv.y,(unsigned)kv.z,(unsigned)kv.w};
  float acc = 0.f;
  #pragma unroll
  for (int j=0;j<4;j++){
    float2 q2 = bf2f2(qu[j]);
    float2 k2 = bf2f2(ku[j]);
    acc += silu(q2.x+k2.x)*al[2*j]   + silu(q2.y+k2.y)*al[2*j+1];
  }
  #pragma unroll
  for (int d=1; d<8; d<<=1) acc += __shfl_down(acc, d, 64);
  if ((lane&7)==0) logits[e*8 + (lane>>3)] = acc * 0.125f;
}

// one wave per node; lane = (edge-chunk<<3) | h
__global__ __launch_bounds__(256) void k_softmax(const float* logits, const int* rowptr, const int* elist, float* attnb){
  int n = blockIdx.x*4 + (threadIdx.x>>6);
  if (n >= N_NODES) return;
  int lane = threadIdx.x & 63;
  int h = lane & 7, ec = lane >> 3;
  int beg = rowptr[n], end = rowptr[n+1];
  float mx = -1e30f;
  for (int i=beg+ec; i<end; i+=8) mx = fmaxf(mx, logits[elist[i]*8+h]);
  #pragma unroll
  for (int dd=8; dd<64; dd<<=1) mx = fmaxf(mx, __shfl_xor(mx, dd, 64));
  float sum = 0.f;
  for (int i=beg+ec; i<end; i+=8) sum += expf(logits[elist[i]*8+h] - mx);
  #pragma unroll
  for (int dd=8; dd<64; dd<<=1) sum += __shfl_xor(sum, dd, 64);
  float inv = 1.0f/(sum + 1e-9f);
  for (int i=beg+ec; i<end; i+=8){
    int e = elist[i];
    attnb[e*8 + h] = expf(logits[e*8+h]-mx)*inv;
  }
}

// rad: 16 edges/block
__global__ __launch_bounds__(256) void k_rad(const float* efeat, const float* Wrad, float* radb){
  __shared__ float wsh[C*RSTR];
  __shared__ float esh[16][132];
  int t = threadIdx.x;
  for (int q=t; q<C*MC; q+=256){ int cc=q/MC, m=q-cc*MC; wsh[cc*RSTR+m] = Wrad[q]; }
  int e0 = blockIdx.x*16;
  for (int q=t; q<16*C; q+=256) esh[q>>7][q&127] = efeat[(size_t)(e0+(q>>7))*C + (q&127)];
  __syncthreads();
  for (int q=t; q<16*MC; q+=256){
    int el = q/MC, m = q-el*MC;
    float acc = 0.f;
    #pragma unroll 4
    for (int cc=0; cc<C; ++cc) acc += esh[el][cc]*wsh[cc*RSTR+m];
    radb[(size_t)(e0+el)*RSTR + m] = silu(acc);
  }
}

// msum[n,m,d] = sum_e attn[e,h(d)]*rad[e,m]*V[src_e,m,d]  (V bf16)
// wave w handles edges beg+w, beg+w+4, ... with the FULL m range; 4 LDS partials; then Wo epilogue
__global__ __launch_bounds__(256) void k_e1(const unsigned short* __restrict__ V, const float* __restrict__ radb,
        const float* __restrict__ attnb, const float* __restrict__ Wo,
        const int* __restrict__ rowptr, const int* __restrict__ elist, const int* __restrict__ srcarr,
        float* __restrict__ x){
  __shared__ __align__(16) float part[4][MC*C];   // 38912 B; part[0] doubles as msum
  int n = blockIdx.x;
  int t = threadIdx.x;
  int w = t>>6, lane = t&63;
  int c0 = lane*2;
  int h = c0 >> 4;
  float acc[MC][2];
  #pragma unroll
  for (int m=0;m<MC;m++){ acc[m][0]=0.f; acc[m][1]=0.f; }
  int beg = rowptr[n], end = rowptr[n+1];
  for (int idx=beg+w; idx<end; idx+=4){
    int e = elist[idx];
    int s = srcarr[e];
    float a = attnb[e*8 + h];
    const unsigned short* vr = V + (size_t)s*(MC*C) + c0;
    const float* rr = radb + (size_t)e*RSTR;
    float4 r0 = *(const float4*)&rr[0];
    float4 r1 = *(const float4*)&rr[4];
    float4 r2 = *(const float4*)&rr[8];
    float4 r3 = *(const float4*)&rr[12];
    float4 r4 = *(const float4*)&rr[16];
    float rm[20] = {r0.x,r0.y,r0.z,r0.w, r1.x,r1.y,r1.z,r1.w,
                    r2.x,r2.y,r2.z,r2.w, r3.x,r3.y,r3.z,r3.w,
                    r4.x,r4.y,r4.z,r4.w};
    #pragma unroll
    for (int m=0;m<MC;m++){
      float ar = a * rm[m];
      float2 v2 = bf2f2(*(const unsigned*)&vr[m*C]);
      acc[m][0] += ar*v2.x;
      acc[m][1] += ar*v2.y;
    }
  }
  #pragma unroll
  for (int m=0;m<MC;m++){
    part[w][m*C+c0]   = acc[m][0];
    part[w][m*C+c0+1] = acc[m][1];
  }
  __syncthreads();
  for (int q=t; q<MC*C; q+=256)
    part[0][q] = part[0][q] + part[1][q] + part[2][q] + part[3][q];
  __syncthreads();
  // x[n] += part[0] @ Wo
  int c0e = (t&63)*2; int g4 = t>>6;
  float acc2[5][2];
  #pragma unroll
  for (int i=0;i<5;i++){ acc2[i][0]=0.f; acc2[i][1]=0.f; }
  for (int d=0; d<C; d+=4){
    float2 w0 = *(const float2*)&Wo[(d+0)*C + c0e];
    float2 w1 = *(const float2*)&Wo[(d+1)*C + c0e];
    float2 w2 = *(const float2*)&Wo[(d+2)*C + c0e];
    float2 w3 = *(const float2*)&Wo[(d+3)*C + c0e];
    #pragma unroll
    for (int i=0;i<5;i++){
      int m = g4 + 4*i;
      if (m < MC){
        float4 m4 = *(const float4*)&part[0][m*C + d];
        acc2[i][0] += m4.x*w0.x + m4.y*w1.x + m4.z*w2.x + m4.w*w3.x;
        acc2[i][1] += m4.x*w0.y + m4.y*w1.y + m4.z*w2.y + m4.w*w3.y;
      }
    }
  }
  #pragma unroll
  for (int i=0;i<5;i++){
    int m = g4 + 4*i;
    if (m < MC){
      size_t off = (size_t)n*MC*C + m*C + c0e;
      x[off]   += acc2[i][0];
      x[off+1] += acc2[i][1];
    }
  }
}

// ---------------- fused: rmsnorm2 + gated FFN, 2 nodes/block ----------------
__global__ __launch_bounds__(256) void k_nodeB(float* __restrict__ x, const float* __restrict__ scale,
        const float* __restrict__ W1, const float* __restrict__ W2){
  __shared__ __align__(16) float xs[2*MC*C];   // 19456 B; reused for gated hb
  __shared__ float gate[2*C];
  __shared__ float ssum[2][5];
  int t = threadIdx.x;
  int n0 = blockIdx.x*2;
  int ng = t>>7, c = t&127;
  int n = n0+ng;
  if (t < 10) ssum[t/5][t%5] = 0.f;
  __syncthreads();
  {
    float vals[MC];
    float pl[5]={0.f,0.f,0.f,0.f,0.f};
    #pragma unroll
    for (int m=0;m<MC;m++){
      float v = x[(size_t)n*MC*C + m*C + c];
      vals[m]=v;
      pl[l_of_m(m)] += v*v;
    }
    #pragma unroll
    for (int l=0;l<5;l++){
      float r = pl[l];
      #pragma unroll
      for (int d=32; d>0; d>>=1) r += __shfl_down(r, d, 64);
      if ((t&63)==0) atomicAdd(&ssum[ng][l], r);
    }
    __syncthreads();
    const float dens[5] = {128.f,384.f,640.f,896.f,1152.f};
    float inv[5];
    #pragma unroll
    for (int l=0;l<5;l++) inv[l] = 1.0f/sqrtf(ssum[ng][l]/dens[l] + 1e-8f);
    #pragma unroll
    for (int m=0;m<MC;m++){
      int l = l_of_m(m);
      xs[ng*MC*C + m*C + c] = vals[m]*inv[l]*scale[l*C + c];
    }
  }
  __syncthreads();
  int c4 = (t&31)*4, mg = t>>5;   // mg in 0..7 ; m = mg + 8*i
  // GEMM1: acc = xs @ W1 (registers)
  float acc[2][3][4];
  #pragma unroll
  for (int nd=0; nd<2; ++nd)
    #pragma unroll
    for (int i=0;i<3;i++)
      #pragma unroll
      for (int j=0;j<4;j++) acc[nd][i][j]=0.f;
  for (int cc=0; cc<C; cc+=4){
    float4 w0 = *(const float4*)&W1[(cc+0)*C + c4];
    float4 w1 = *(const float4*)&W1[(cc+1)*C + c4];
    float4 w2 = *(const float4*)&W1[(cc+2)*C + c4];
    float4 w3 = *(const float4*)&W1[(cc+3)*C + c4];
    #pragma unroll
    for (int nd=0; nd<2; ++nd){
      #pragma unroll
      for (int i=0;i<3;i++){
        int m = mg + 8*i;
        if (m < MC){
          float4 a = *(const float4*)&xs[nd*MC*C + m*C + cc];
          acc[nd][i][0] += a.x*w0.x + a.y*w1.x + a.z*w2.x + a.w*w3.x;
          acc[nd][i][1] += a.x*w0.y + a.y*w1.y + a.z*w2.y + a.w*w3.y;
          acc[nd][i][2] += a.x*w0.z + a.y*w1.z + a.z*w2.z + a.w*w3.z;
          acc[nd][i][3] += a.x*w0.w + a.y*w1.w + a.z*w2.w + a.w*w3.w;
        }
      }
    }
  }
  __syncthreads();          // all xs reads complete
  #pragma unroll
  for (int nd=0; nd<2; ++nd)
    #pragma unroll
    for (int i=0;i<3;i++){
      int m = mg + 8*i;
      if (m < MC){
        float4 st; st.x=acc[nd][i][0]; st.y=acc[nd][i][1]; st.z=acc[nd][i][2]; st.w=acc[nd][i][3];
        *(float4*)&xs[nd*MC*C + m*C + c4] = st;
      }
    }
  __syncthreads();
  {
    int nd = t>>7, cg = t&127;
    gate[nd*C+cg] = silu(xs[nd*MC*C + cg]);
  }
  __syncthreads();
  for (int q=t; q<2*MC*C; q+=256){
    int nd2 = (q >= MC*C) ? 1 : 0;
    xs[q] *= gate[nd2*C + (q&127)];
  }
  __syncthreads();
  // GEMM2: x += xs(gated hb) @ W2
  float acc2[2][3][4];
  #pragma unroll
  for (int nd=0; nd<2; ++nd)
    #pragma unroll
    for (int i=0;i<3;i++)
      #pragma unroll
      for (int j=0;j<4;j++) acc2[nd][i][j]=0.f;
  for (int f=0; f<C; f+=4){
    float4 w0 = *(const float4*)&W2[(f+0)*C + c4];
    float4 w1 = *(const float4*)&W2[(f+1)*C + c4];
    float4 w2 = *(const float4*)&W2[(f+2)*C + c4];
    float4 w3 = *(const float4*)&W2[(f+3)*C + c4];
    #pragma unroll
    for (int nd=0; nd<2; ++nd){
      #pragma unroll
      for (int i=0;i<3;i++){
        int m = mg + 8*i;
        if (m < MC){
          float4 a = *(const float4*)&xs[nd*MC*C + m*C + f];
          acc2[nd][i][0] += a.x*w0.x + a.y*w1.x + a.z*w2.x + a.w*w3.x;
          acc2[nd][i][1] += a.x*w0.y + a.y*w1.y + a.z*w2.y + a.w*w3.y;
          acc2[nd][i][2] += a.x*w0.z + a.y*w1.z + a.z*w2.z + a.w*w3.z;
          acc2[nd][i][3] += a.x*w0.w + a.y*w1.w + a.z*w2.w + a.w*w3.w;
        }
      }
    }
  }
  #pragma unroll
  for (int nd=0; nd<2; ++nd)
    #pragma unroll
    for (int i=0;i<3;i++){
      int m = mg + 8*i;
      if (m < MC){
        size_t off = (size_t)(n0+nd)*MC*C + m*C + c4;
        float4 old = *(float4*)&x[off];
        old.x += acc2[nd][i][0];
        old.y += acc2[nd][i][1];
        old.z += acc2[nd][i][2];
        old.w += acc2[nd][i][3];
        *(float4*)&x[off] = old;
      }
    }
}

// ---------------- final head ----------------
__global__ __launch_bounds__(128) void k_final(const float* x, const float* nsf, const float* Wef1,
        const float* Wef2, const int* batch, float* out){
  __shared__ float sl[C];
  __shared__ float red[2];
  __shared__ float red2[2];
  int n = blockIdx.x; int t = threadIdx.x;
  float v = x[(size_t)n*MC*C + t];
  float sq = v*v;
  for (int d=32; d>0; d>>=1) sq += __shfl_down(sq, d, 64);
  if ((t&63)==0) red[t>>6] = sq;
  __syncthreads();
  float ms = (red[0]+red[1]) * (1.0f/128.f);
  float inv = 1.0f/sqrtf(ms + 1e-8f);
  sl[t] = v*inv*nsf[t];
  __syncthreads();
  float acc = 0.f;
  for (int cc=0; cc<C; ++cc) acc += sl[cc]*Wef1[cc*C + t];
  float val = acc*silu(acc)*Wef2[t];
  for (int d=32; d>0; d>>=1) val += __shfl_down(val, d, 64);
  if ((t&63)==0) red2[t>>6] = val;
  __syncthreads();
  if (t==0){
    float ne = red2[0]+red2[1];
    atomicAdd(&out[batch[n]], ne * (1.0f/77.81317f));
  }
}

extern "C" void kernel_launch(void* const* d_in, const int* in_sizes, int n_in,
                              void* d_out, int out_size, void* d_ws, size_t ws_size,
                              hipStream_t stream){
  (void)in_sizes; (void)n_in; (void)ws_size;
  const int*   anum  = (const int*)d_in[0];
  const int*   eidx  = (const int*)d_in[1];
  const float* dist  = (const float*)d_in[2];
  const int*   batch = (const int*)d_in[3];
  const float* emb   = (const float*)d_in[4];
  const float* We1   = (const float*)d_in[5];
  const float* We2   = (const float*)d_in[6];
  const float* Wdeg  = (const float*)d_in[7];
  const float* ns1   = (const float*)d_in[8];
  const float* ns2   = (const float*)d_in[9];
  const float* Wq    = (const float*)d_in[10];
  const float* Wk    = (const float*)d_in[11];
  const float* alpha = (const float*)d_in[12];
  const float* Wv    = (const float*)d_in[13];
  const float* Wrad  = (const float*)d_in[14];
  const float* Wo    = (const float*)d_in[15];
  const float* W1    = (const float*)d_in[16];
  const float* W2    = (const float*)d_in[17];
  const float* nsf   = (const float*)d_in[18];
  const float* Wef1  = (const float*)d_in[19];
  const float* Wef2  = (const float*)d_in[20];
  float* out = (float*)d_out;

  const int* srcarr = eidx;
  const int* tgtarr = eidx + N_EDGES;

  char* wsb = (char*)d_ws;
  float* efeat = (float*)wsb;  wsb += (size_t)N_EDGES*C*4;
  float* efsumT= (float*)wsb;  wsb += (size_t)N_NODES*C*4;
  float* x     = (float*)wsb;  wsb += (size_t)N_NODES*MC*C*4;
  unsigned short* Vb = (unsigned short*)wsb; wsb += (size_t)N_NODES*MC*C*2;
  unsigned short* qb = (unsigned short*)wsb; wsb += (size_t)N_NODES*512*2;
  unsigned short* kb = (unsigned short*)wsb; wsb += (size_t)N_NODES*512*2;
  float* logit = (float*)wsb;  wsb += (size_t)N_EDGES*8*4;
  float* attnb = (float*)wsb;  wsb += (size_t)N_EDGES*8*4;
  float* radb  = (float*)wsb;  wsb += (size_t)N_EDGES*RSTR*4;
  int* deg     = (int*)wsb;    wsb += (size_t)N_NODES*4;
  int* rowptr  = (int*)wsb;    wsb += (size_t)(N_NODES+1)*4;
  int* cursor  = (int*)wsb;    wsb += (size_t)N_NODES*4;
  int* elist   = (int*)wsb;    wsb += (size_t)N_EDGES*4;

  (void)hipMemsetAsync(deg, 0, N_NODES*4, stream);
  (void)hipMemsetAsync(cursor, 0, N_NODES*4, stream);
  (void)hipMemsetAsync(d_out, 0, (size_t)out_size*sizeof(float), stream);

  k_count<<<(N_EDGES+255)/256, 256, 0, stream>>>(tgtarr, deg);
  k_scan<<<1, 64, 0, stream>>>(deg, rowptr);
  k_fill<<<(N_EDGES+255)/256, 256, 0, stream>>>(tgtarr, rowptr, cursor, elist);
  k_efeat<<<N_EDGES/16, 256, 0, stream>>>(dist, We1, We2, efeat);
  k_efsum<<<N_NODES, 128, 0, stream>>>(efeat, rowptr, elist, efsumT);
  k_deginit<<<dim3((N_NODES+15)/16, 5), 256, 0, stream>>>(efsumT, Wdeg, emb, anum, x);

  for (int i=0;i<NL;i++){
    k_nodeA<<<N_NODES/4, 256, 0, stream>>>(x, ns1 + i*5*C, Wq + i*C*512, Wk + i*C*512,
                                           Wv + i*C*C, qb, kb, Vb);
    k_logits<<<(N_EDGES+3)/4, 256, 0, stream>>>(qb, kb, alpha + i*512, srcarr, tgtarr, logit);
    k_softmax<<<(N_NODES+3)/4, 256, 0, stream>>>(logit, rowptr, elist, attnb);
    k_rad<<<N_EDGES/16, 256, 0, stream>>>(efeat, Wrad + i*C*MC, radb);
    k_e1<<<N_NODES, 256, 0, stream>>>(Vb, radb, attnb, Wo + i*C*C,
                                      rowptr, elist, srcarr, x);
    k_nodeB<<<N_NODES/2, 256, 0, stream>>>(x, ns2 + i*5*C, W1 + i*C*C, W2 + i*C*C);
  }
  k_final<<<N_NODES, 128, 0, stream>>>(x, nsf, Wef1, Wef2, batch, out);
}